// Round 2
// baseline (3482.863 us; speedup 1.0000x reference)
//
#include <hip/hip_runtime.h>
#include <math.h>

#define HH 128
#define WW 128
#define CC 180
#define BB 4
#define IMG (HH*WW)          // 16384 tokens per image
#define NTOK (BB*IMG)        // 65536
#define NHEADS 6
#define HD 30
#define WSZ 16
#define NTOKW (WSZ*WSZ)      // 256
#define HID 720

__device__ __forceinline__ float warp_sum(float v) {
    #pragma unroll
    for (int o = 32; o > 0; o >>= 1) v += __shfl_xor(v, o);
    return v;
}
__device__ __forceinline__ float warp_max(float v) {
    #pragma unroll
    for (int o = 32; o > 0; o >>= 1) v = fmaxf(v, __shfl_xor(v, o));
    return v;
}
__device__ __forceinline__ float gelu_exact(float v) {
    return 0.5f * v * (1.f + erff(v * 0.70710678118654752f));
}

// ---------------- LayerNorm (one wave per token) ----------------
__global__ __launch_bounds__(256) void ln_kernel(
    const float* __restrict__ x, const float* __restrict__ g,
    const float* __restrict__ b, float* __restrict__ out)
{
    int wid = threadIdx.x >> 6, lane = threadIdx.x & 63;
    int t = blockIdx.x * 4 + wid;
    size_t off = (size_t)t * CC;
    bool has2 = lane < (CC - 128);
    float v0 = x[off + lane];
    float v1 = x[off + lane + 64];
    float v2 = has2 ? x[off + lane + 128] : 0.f;
    float s = warp_sum(v0 + v1 + v2);
    float mu = s * (1.f / CC);
    float d0 = v0 - mu, d1 = v1 - mu, d2 = has2 ? v2 - mu : 0.f;
    float var = warp_sum(d0*d0 + d1*d1 + d2*d2) * (1.f / CC);
    float rs = rsqrtf(var + 1e-5f);
    out[off + lane]      = d0 * rs * g[lane]      + b[lane];
    out[off + lane + 64] = d1 * rs * g[lane + 64] + b[lane + 64];
    if (has2) out[off + lane + 128] = d2 * rs * g[lane + 128] + b[lane + 128];
}

// ---------------- relative position bias, transposed [h][j][i] ----------------
__global__ void bias_kernel(const int* __restrict__ rpi, const float* __restrict__ rpb,
                            float* __restrict__ biasT)
{
    int idx = blockIdx.x * blockDim.x + threadIdx.x;
    if (idx >= NTOKW * NTOKW) return;
    int i = idx / NTOKW, j = idx % NTOKW;
    int r = rpi[idx];
    #pragma unroll
    for (int h = 0; h < NHEADS; h++)
        biasT[(size_t)h * NTOKW * NTOKW + (size_t)j * NTOKW + i] = rpb[r * NHEADS + h];
}

// ---------------- generic tiled GEMM:  C[M,N] = A[M,K] @ W[N,K]^T + bias ----------------
__global__ __launch_bounds__(256) void gemm_kernel(
    const float* __restrict__ A, const float* __restrict__ Wt,
    const float* __restrict__ bias, float* __restrict__ C,
    int M, int N, int K, int act,
    const float* __restrict__ rowscale, const float* __restrict__ resid)
{
    __shared__ float sA[16][64];
    __shared__ float sW[16][64];
    int tid = threadIdx.x;
    int ty = tid >> 4, tx = tid & 15;
    int m0 = blockIdx.y * 64;
    int n0 = blockIdx.x * 64;
    int rr = tid >> 2;
    int kp = (tid & 3) << 2;
    bool vec = ((K & 3) == 0);
    int nch = (K + 15) >> 4;
    float acc[4][4] = {};
    for (int ch = 0; ch < nch; ch++) {
        int k0 = ch * 16 + kp;
        {   // A tile
            int row = m0 + rr;
            float4 av = make_float4(0.f, 0.f, 0.f, 0.f);
            if (row < M) {
                if (vec && (k0 + 3) < K) {
                    av = *reinterpret_cast<const float4*>(A + (size_t)row * K + k0);
                } else {
                    float tmp[4];
                    #pragma unroll
                    for (int j = 0; j < 4; j++)
                        tmp[j] = (k0 + j < K) ? A[(size_t)row * K + k0 + j] : 0.f;
                    av = make_float4(tmp[0], tmp[1], tmp[2], tmp[3]);
                }
                if (rowscale) { float sc = rowscale[row]; av.x*=sc; av.y*=sc; av.z*=sc; av.w*=sc; }
            }
            sA[kp+0][rr] = av.x; sA[kp+1][rr] = av.y; sA[kp+2][rr] = av.z; sA[kp+3][rr] = av.w;
        }
        {   // W tile
            int nrow = n0 + rr;
            float4 wv = make_float4(0.f, 0.f, 0.f, 0.f);
            if (nrow < N) {
                if (vec && (k0 + 3) < K) {
                    wv = *reinterpret_cast<const float4*>(Wt + (size_t)nrow * K + k0);
                } else {
                    float tmp[4];
                    #pragma unroll
                    for (int j = 0; j < 4; j++)
                        tmp[j] = (k0 + j < K) ? Wt[(size_t)nrow * K + k0 + j] : 0.f;
                    wv = make_float4(tmp[0], tmp[1], tmp[2], tmp[3]);
                }
            }
            sW[kp+0][rr] = wv.x; sW[kp+1][rr] = wv.y; sW[kp+2][rr] = wv.z; sW[kp+3][rr] = wv.w;
        }
        __syncthreads();
        #pragma unroll
        for (int k = 0; k < 16; k++) {
            float4 a = *reinterpret_cast<const float4*>(&sA[k][ty << 2]);
            float4 w = *reinterpret_cast<const float4*>(&sW[k][tx << 2]);
            acc[0][0] += a.x*w.x; acc[0][1] += a.x*w.y; acc[0][2] += a.x*w.z; acc[0][3] += a.x*w.w;
            acc[1][0] += a.y*w.x; acc[1][1] += a.y*w.y; acc[1][2] += a.y*w.z; acc[1][3] += a.y*w.w;
            acc[2][0] += a.z*w.x; acc[2][1] += a.z*w.y; acc[2][2] += a.z*w.z; acc[2][3] += a.z*w.w;
            acc[3][0] += a.w*w.x; acc[3][1] += a.w*w.y; acc[3][2] += a.w*w.z; acc[3][3] += a.w*w.w;
        }
        __syncthreads();
    }
    #pragma unroll
    for (int i = 0; i < 4; i++) {
        int row = m0 + (ty << 2) + i;
        if (row >= M) continue;
        #pragma unroll
        for (int j = 0; j < 4; j++) {
            int col = n0 + (tx << 2) + j;
            if (col >= N) continue;
            float v = acc[i][j] + bias[col];
            if (act == 1) v = gelu_exact(v);
            else if (act == 2) v = fmaxf(v, 0.f);
            if (resid) v += resid[(size_t)row * N + col];
            C[(size_t)row * N + col] = v;
        }
    }
}

// ---------------- window attention (single image): one block per (window, head) ----------------
__global__ __launch_bounds__(256) void attn_kernel(
    const float* __restrict__ qkv, const float* __restrict__ biasT,
    float* __restrict__ out)
{
    __shared__ float ks[NTOKW][32];
    __shared__ float vs[NTOKW][32];
    int blk = blockIdx.x;
    int h = blk % NHEADS;
    int win = blk / NHEADS;          // 0..63 within image
    int base = (win >> 3) * WSZ * WW + (win & 7) * WSZ;
    int tid = threadIdx.x;
    for (int idx = tid; idx < NTOKW * HD; idx += 256) {
        int j = idx / HD, d = idx - j * HD;
        int g = base + (j >> 4) * WW + (j & 15);
        ks[j][d] = qkv[(size_t)g * 540 + 180 + h * HD + d];
        vs[j][d] = qkv[(size_t)g * 540 + 360 + h * HD + d];
    }
    ks[tid][30] = 0.f; ks[tid][31] = 0.f; vs[tid][30] = 0.f; vs[tid][31] = 0.f;
    int i = tid;
    int gi = base + (i >> 4) * WW + (i & 15);
    float4 q[8];
    {
        const float scale = 0.18257418583505536f;  // 30^-0.5
        float qq[32];
        #pragma unroll
        for (int d = 0; d < HD; d++) qq[d] = qkv[(size_t)gi * 540 + h * HD + d] * scale;
        qq[30] = 0.f; qq[31] = 0.f;
        #pragma unroll
        for (int r = 0; r < 8; r++) q[r] = make_float4(qq[4*r], qq[4*r+1], qq[4*r+2], qq[4*r+3]);
    }
    __syncthreads();
    const float* bT = biasT + (size_t)h * NTOKW * NTOKW + i;
    float4 acc[8];
    #pragma unroll
    for (int r = 0; r < 8; r++) acc[r] = make_float4(0.f, 0.f, 0.f, 0.f);
    float l = 0.f;
    for (int j = 0; j < NTOKW; j++) {
        const float4* kr = reinterpret_cast<const float4*>(&ks[j][0]);
        float s = bT[(size_t)j * NTOKW];
        #pragma unroll
        for (int r = 0; r < 8; r++) {
            float4 kv = kr[r];
            s += q[r].x * kv.x + q[r].y * kv.y + q[r].z * kv.z + q[r].w * kv.w;
        }
        float p = __expf(s);   // |s| small -> safe without max-shift
        l += p;
        const float4* vr = reinterpret_cast<const float4*>(&vs[j][0]);
        #pragma unroll
        for (int r = 0; r < 8; r++) {
            float4 vv = vr[r];
            acc[r].x += p * vv.x; acc[r].y += p * vv.y; acc[r].z += p * vv.z; acc[r].w += p * vv.w;
        }
    }
    float inv = 1.f / l;
    float accs[32];
    #pragma unroll
    for (int r = 0; r < 8; r++) {
        accs[4*r] = acc[r].x; accs[4*r+1] = acc[r].y; accs[4*r+2] = acc[r].z; accs[4*r+3] = acc[r].w;
    }
    float* orow = out + (size_t)gi * CC + h * HD;
    #pragma unroll
    for (int d = 0; d < HD; d++) orow[d] = accs[d] * inv;
}

// ---------------- depthwise 3x3 conv, NHWC, nimg images ----------------
__global__ void dwconv_kernel(const float* __restrict__ in, const float* __restrict__ w,
                              const float* __restrict__ bias, float* __restrict__ out,
                              int Cc, int dil, int act, int nimg)
{
    size_t idx = (size_t)blockIdx.x * blockDim.x + threadIdx.x;
    size_t total = (size_t)nimg * IMG * Cc;
    if (idx >= total) return;
    int c = (int)(idx % Cc);
    size_t pos = idx / Cc;
    int px = (int)(pos % WW);
    int py = (int)((pos / WW) % HH);
    int b  = (int)(pos / (WW * HH));
    float acc = bias[c];
    #pragma unroll
    for (int ky = 0; ky < 3; ky++) {
        int iy = py + (ky - 1) * dil;
        if (iy < 0 || iy >= HH) continue;
        #pragma unroll
        for (int kx = 0; kx < 3; kx++) {
            int ix = px + (kx - 1) * dil;
            if (ix < 0 || ix >= WW) continue;
            acc += in[(((size_t)b * HH + iy) * WW + ix) * Cc + c] * w[c * 9 + ky * 3 + kx];
        }
    }
    if (act == 1) acc = gelu_exact(acc);
    else if (act == 2) acc = fmaxf(acc, 0.f);
    out[idx] = acc;
}

// ---------------- GAP partial sums: part[b][chunk][c] ----------------
__global__ void gap_kernel(const float* __restrict__ y, float* __restrict__ part)
{
    int blk = blockIdx.x;
    int b = blk >> 5, chunk = blk & 31;
    int c = threadIdx.x;
    if (c >= CC) return;
    size_t basep = ((size_t)b * IMG + (size_t)chunk * 512) * CC;
    float s = 0.f;
    for (int p = 0; p < 512; p++) s += y[basep + (size_t)p * CC + c];
    part[((size_t)b * 32 + chunk) * CC + c] = s;
}

// ---------------- channel attention (tiny) ----------------
__global__ void ca_kernel(const float* __restrict__ part,
                          const float* __restrict__ w1, const float* __restrict__ b1,
                          const float* __restrict__ w2, const float* __restrict__ b2,
                          float* __restrict__ ca)
{
    __shared__ float gap[BB * CC];
    __shared__ float s1[BB * 6];
    int tid = threadIdx.x;
    for (int idx = tid; idx < BB * CC; idx += 256) {
        int b = idx / CC, c = idx % CC;
        float s = 0.f;
        for (int ch = 0; ch < 32; ch++) s += part[((size_t)b * 32 + ch) * CC + c];
        gap[idx] = s * (1.f / IMG);
    }
    __syncthreads();
    if (tid < BB * 6) {
        int b = tid / 6, cs = tid % 6;
        float s = 0.f;
        for (int c = 0; c < CC; c++) s += w1[cs * CC + c] * gap[b * CC + c];
        s1[tid] = fmaxf(s + b1[cs], 0.f);
    }
    __syncthreads();
    for (int idx = tid; idx < BB * CC; idx += 256) {
        int b = idx / CC, c = idx % CC;
        float s = b2[c];
        #pragma unroll
        for (int cs = 0; cs < 6; cs++) s += w2[c * 6 + cs] * s1[b * 6 + cs];
        ca[idx] = 1.f / (1.f + __expf(-s));
    }
}

// ---------------- x1 += 0.01*y4*ca  (in place), then LN2 -> xn2 ----------------
__global__ __launch_bounds__(256) void resid_ln_kernel(
    float* __restrict__ x1, const float* __restrict__ y4, const float* __restrict__ ca,
    const float* __restrict__ g, const float* __restrict__ bb,
    float* __restrict__ xn2)
{
    int wid = threadIdx.x >> 6, lane = threadIdx.x & 63;
    int t = blockIdx.x * 4 + wid;
    int b = t >> 14;
    size_t off = (size_t)t * CC;
    bool has2 = lane < (CC - 128);
    float v0 = x1[off+lane]    + 0.01f * y4[off+lane]    * ca[b*CC + lane];
    float v1 = x1[off+lane+64] + 0.01f * y4[off+lane+64] * ca[b*CC + lane+64];
    float v2 = 0.f;
    if (has2) v2 = x1[off+lane+128] + 0.01f * y4[off+lane+128] * ca[b*CC + lane+128];
    x1[off+lane] = v0; x1[off+lane+64] = v1;
    if (has2) x1[off+lane+128] = v2;
    float s = warp_sum(v0 + v1 + v2);
    float mu = s * (1.f / CC);
    float d0 = v0-mu, d1 = v1-mu, d2 = has2 ? v2-mu : 0.f;
    float var = warp_sum(d0*d0 + d1*d1 + d2*d2) * (1.f / CC);
    float rs = rsqrtf(var + 1e-5f);
    xn2[off+lane]      = d0 * rs * g[lane]      + bb[lane];
    xn2[off+lane+64]   = d1 * rs * g[lane+64]   + bb[lane+64];
    if (has2) xn2[off+lane+128] = d2 * rs * g[lane+128] + bb[lane+128];
}

// ---------------- max/mean over channels per pixel (one image) ----------------
__global__ __launch_bounds__(256) void mpap_kernel(
    const float* __restrict__ h, float* __restrict__ mp, float* __restrict__ ap)
{
    int wid = threadIdx.x >> 6, lane = threadIdx.x & 63;
    int p = blockIdx.x * 4 + wid;
    const float* row = h + (size_t)p * HID;
    float mx = -1e30f, s = 0.f;
    for (int j = lane; j < HID; j += 64) { float v = row[j]; mx = fmaxf(mx, v); s += v; }
    mx = warp_max(mx); s = warp_sum(s);
    if (lane == 0) { mp[p] = mx; ap[p] = s * (1.f / HID); }
}

// ---------------- 7x7 spatial-attention conv + sigmoid (one image) ----------------
__global__ void saconv_kernel(const float* __restrict__ mp, const float* __restrict__ ap,
                              const float* __restrict__ w, float* __restrict__ sa)
{
    int p = blockIdx.x * blockDim.x + threadIdx.x;
    if (p >= IMG) return;
    int px = p % WW, py = p / WW;
    float acc = 0.f;
    for (int ky = 0; ky < 7; ky++) {
        int iy = py + ky - 3;
        if (iy < 0 || iy >= HH) continue;
        for (int kx = 0; kx < 7; kx++) {
            int ix = px + kx - 3;
            if (ix < 0 || ix >= WW) continue;
            int pid = iy * WW + ix;
            acc += mp[pid] * w[ky * 7 + kx] + ap[pid] * w[49 + ky * 7 + kx];
        }
    }
    sa[p] = 1.f / (1.f + __expf(-acc));
}

extern "C" void kernel_launch(void* const* d_in, const int* in_sizes, int n_in,
                              void* d_out, int out_size, void* d_ws, size_t ws_size,
                              hipStream_t stream)
{
    const float* x      = (const float*)d_in[0];
    const int*   rpi    = (const int*)d_in[3];
    const float* n1g    = (const float*)d_in[4];
    const float* n1b    = (const float*)d_in[5];
    const float* rpb    = (const float*)d_in[6];
    const float* qkv_w  = (const float*)d_in[7];
    const float* qkv_b  = (const float*)d_in[8];
    const float* proj_w = (const float*)d_in[9];
    const float* proj_b = (const float*)d_in[10];
    const float* cab_w0 = (const float*)d_in[11];
    const float* cab_b0 = (const float*)d_in[12];
    const float* cab_w1 = (const float*)d_in[13];
    const float* cab_b1 = (const float*)d_in[14];
    const float* cab_w2 = (const float*)d_in[15];
    const float* cab_b2 = (const float*)d_in[16];
    const float* cab_w3 = (const float*)d_in[17];
    const float* cab_b3 = (const float*)d_in[18];
    const float* ca_w1  = (const float*)d_in[19];
    const float* ca_b1  = (const float*)d_in[20];
    const float* ca_w2  = (const float*)d_in[21];
    const float* ca_b2  = (const float*)d_in[22];
    const float* n2g    = (const float*)d_in[23];
    const float* n2b    = (const float*)d_in[24];
    const float* fc1_w  = (const float*)d_in[25];
    const float* fc1_b  = (const float*)d_in[26];
    const float* dw_w   = (const float*)d_in[27];
    const float* dw_b   = (const float*)d_in[28];
    const float* pw_w   = (const float*)d_in[29];
    const float* pw_b   = (const float*)d_in[30];
    const float* sa_w   = (const float*)d_in[31];
    const float* fc2_w  = (const float*)d_in[32];
    const float* fc2_b  = (const float*)d_in[33];
    float* outp = (float*)d_out;
    (void)in_sizes; (void)n_in; (void)out_size; (void)ws_size;

    char* ws = (char*)d_ws;
    const size_t TOKC = (size_t)NTOK * CC * sizeof(float);   // 47,185,920 bytes
    // 5 rotating regions of TOKC each (~225 MB total + ~2.5 MB tail):
    float* R1  = (float*)(ws);               // qkvt_b | y1+y2 | y4 | h3_b
    float* RB  = (float*)(ws + TOKC);        // xn -> xn2
    float* RC  = (float*)(ws + 2 * TOKC);    // attnb -> y3 -> h2_b
    float* RD  = (float*)(ws + 3 * TOKC);    // h1_b
    float* RX  = (float*)(ws + 4 * TOKC);    // x1 = x + proj(attn) (+ conv term)
    char*  tail = ws + 5 * TOKC;
    float* biasT = (float*)tail;                                   // 1,572,864 B
    float* part  = (float*)(tail + 1572864);                       // 92,160 B
    float* cabuf = (float*)(tail + 1572864 + 98304);               // 2,880 B
    float* mp    = (float*)(tail + 1572864 + 131072);              // NTOK*4
    float* ap    = (float*)(tail + 1572864 + 131072 + NTOK*4);     // NTOK*4
    float* sab   = (float*)(tail + 1572864 + 131072 + 2*(size_t)NTOK*4);

    float* xn    = RB;
    float* xn2   = RB;
    float* attnb = RC;
    float* x1    = RX;
    float* qkvt  = R1;                                   // 16384*540 floats
    float* y1    = R1;                                   // 16384*... (NTOK*90)
    float* y2    = R1 + (size_t)NTOK * 90;
    float* y3    = RC;
    float* y4    = R1;

    auto gemm = [&](const float* A, const float* Wt, const float* bi, float* Cp,
                    int M, int N, int K, int act, const float* rs, const float* resid) {
        dim3 g((N + 63) / 64, (M + 63) / 64);
        gemm_kernel<<<g, dim3(256), 0, stream>>>(A, Wt, bi, Cp, M, N, K, act, rs, resid);
    };

    // 1) LN1 (full batch)
    ln_kernel<<<dim3(NTOK / 4), dim3(256), 0, stream>>>(x, n1g, n1b, xn);
    // 2) bias table
    bias_kernel<<<dim3((NTOKW * NTOKW) / 256), dim3(256), 0, stream>>>(rpi, rpb, biasT);
    // 3) per-image qkv + window attention (qkvt region reused)
    for (int b = 0; b < BB; b++) {
        gemm(xn + (size_t)b * IMG * CC, qkv_w, qkv_b, qkvt, IMG, 540, CC, 0, nullptr, nullptr);
        attn_kernel<<<dim3(64 * NHEADS), dim3(256), 0, stream>>>(
            qkvt, biasT, attnb + (size_t)b * IMG * CC);
    }
    // 4) proj with residual x fused -> x1
    gemm(attnb, proj_w, proj_b, x1, NTOK, CC, CC, 0, nullptr, x);
    // 5) CAB branch (full batch)
    gemm(xn, cab_w0, cab_b0, y1, NTOK, 90, CC, 0, nullptr, nullptr);
    dwconv_kernel<<<dim3((NTOK * 90 + 255) / 256), dim3(256), 0, stream>>>(y1, cab_w1, cab_b1, y2, 90, 1, 1, BB);
    gemm(y2, cab_w2, cab_b2, y3, NTOK, CC, 90, 0, nullptr, nullptr);
    dwconv_kernel<<<dim3((NTOK * CC + 255) / 256), dim3(256), 0, stream>>>(y3, cab_w3, cab_b3, y4, CC, 2, 0, BB);
    gap_kernel<<<dim3(BB * 32), dim3(192), 0, stream>>>(y4, part);
    ca_kernel<<<dim3(1), dim3(256), 0, stream>>>(part, ca_w1, ca_b1, ca_w2, ca_b2, cabuf);
    // 6) x1 += 0.01*y4*ca; LN2 -> xn2
    resid_ln_kernel<<<dim3(NTOK / 4), dim3(256), 0, stream>>>(x1, y4, cabuf, n2g, n2b, xn2);
    // 7) FFN per image (h regions reused)
    for (int b = 0; b < BB; b++) {
        const float* xn2b = xn2 + (size_t)b * IMG * CC;
        float* h1 = RD;
        float* h2 = RC;
        float* h3 = R1;
        gemm(xn2b, fc1_w, fc1_b, h1, IMG, HID, CC, 1, nullptr, nullptr);
        dwconv_kernel<<<dim3((IMG * HID + 255) / 256), dim3(256), 0, stream>>>(h1, dw_w, dw_b, h2, HID, 1, 2, 1);
        gemm(h2, pw_w, pw_b, h3, IMG, HID, HID, 2, nullptr, nullptr);
        mpap_kernel<<<dim3(IMG / 4), dim3(256), 0, stream>>>(h3, mp + (size_t)b * IMG, ap + (size_t)b * IMG);
        saconv_kernel<<<dim3(IMG / 256), dim3(256), 0, stream>>>(
            mp + (size_t)b * IMG, ap + (size_t)b * IMG, sa_w, sab + (size_t)b * IMG);
        gemm(h3, fc2_w, fc2_b, outp + (size_t)b * IMG * CC, IMG, CC, HID, 0,
             sab + (size_t)b * IMG, x1 + (size_t)b * IMG * CC);
    }
}

// Round 3
// 2375.230 us; speedup vs baseline: 1.4663x; 1.4663x over previous
//
#include <hip/hip_runtime.h>
#include <math.h>

#define HH 128
#define WW 128
#define CC 180
#define BB 4
#define IMG (HH*WW)          // 16384 tokens per image
#define NTOK (BB*IMG)        // 65536
#define NHEADS 6
#define HD 30
#define WSZ 16
#define NTOKW (WSZ*WSZ)      // 256
#define HID 720

typedef __attribute__((ext_vector_type(8))) short short8v;
typedef __attribute__((ext_vector_type(4))) short short4v;
typedef __attribute__((ext_vector_type(4))) float f32x4;

__device__ __forceinline__ float warp_sum(float v) {
    #pragma unroll
    for (int o = 32; o > 0; o >>= 1) v += __shfl_xor(v, o);
    return v;
}
__device__ __forceinline__ float warp_max(float v) {
    #pragma unroll
    for (int o = 32; o > 0; o >>= 1) v = fmaxf(v, __shfl_xor(v, o));
    return v;
}
__device__ __forceinline__ float gelu_exact(float v) {
    return 0.5f * v * (1.f + erff(v * 0.70710678118654752f));
}
__device__ __forceinline__ short f2bf(float f) {
    union { float f; unsigned int u; } c; c.f = f;
    unsigned int r = (c.u + 0x7FFFu + ((c.u >> 16) & 1u)) >> 16;
    return (short)r;
}

// ---------------- LayerNorm (one wave per token) ----------------
__global__ __launch_bounds__(256) void ln_kernel(
    const float* __restrict__ x, const float* __restrict__ g,
    const float* __restrict__ b, float* __restrict__ out)
{
    int wid = threadIdx.x >> 6, lane = threadIdx.x & 63;
    int t = blockIdx.x * 4 + wid;
    size_t off = (size_t)t * CC;
    bool has2 = lane < (CC - 128);
    float v0 = x[off + lane];
    float v1 = x[off + lane + 64];
    float v2 = has2 ? x[off + lane + 128] : 0.f;
    float s = warp_sum(v0 + v1 + v2);
    float mu = s * (1.f / CC);
    float d0 = v0 - mu, d1 = v1 - mu, d2 = has2 ? v2 - mu : 0.f;
    float var = warp_sum(d0*d0 + d1*d1 + d2*d2) * (1.f / CC);
    float rs = rsqrtf(var + 1e-5f);
    out[off + lane]      = d0 * rs * g[lane]      + b[lane];
    out[off + lane + 64] = d1 * rs * g[lane + 64] + b[lane + 64];
    if (has2) out[off + lane + 128] = d2 * rs * g[lane + 128] + b[lane + 128];
}

// ---------------- relative position bias, transposed [h][j][i] ----------------
__global__ void bias_kernel(const int* __restrict__ rpi, const float* __restrict__ rpb,
                            float* __restrict__ biasT)
{
    int idx = blockIdx.x * blockDim.x + threadIdx.x;
    if (idx >= NTOKW * NTOKW) return;
    int i = idx / NTOKW, j = idx % NTOKW;
    int r = rpi[idx];
    #pragma unroll
    for (int h = 0; h < NHEADS; h++)
        biasT[(size_t)h * NTOKW * NTOKW + (size_t)j * NTOKW + i] = rpb[r * NHEADS + h];
}

// ---------------- bf16 MFMA GEMM:  C[M,N] = A[M,K] @ W[N,K]^T (+rowscale,+bias,act,+resid) ----
// 128x128 tile, BK=32, 4 waves (2x2), each wave 64x64 = 4x4 fragments of 16x16x32.
// A,W are fp32 in HBM; converted to bf16 during reg-staged LDS write (XOR-swizzled).
// Requires M % 128 == 0. N,K arbitrary (guarded).
__global__ __launch_bounds__(256) void mgemm_kernel(
    const float* __restrict__ A, const float* __restrict__ Wt,
    const float* __restrict__ bias, float* __restrict__ C,
    int M, int N, int K, int act,
    const float* __restrict__ rowscale, const float* __restrict__ resid)
{
    __shared__ short sA[128 * 32];
    __shared__ short sB[128 * 32];
    int tid = threadIdx.x;
    int m0 = blockIdx.y * 128, n0 = blockIdx.x * 128;
    int lane = tid & 63, wid = tid >> 6;
    int wm = (wid >> 1) << 6;       // 0 or 64
    int wn = (wid & 1) << 6;        // 0 or 64
    int chunk = lane >> 4;          // 0..3 (k-chunk of 8)
    int lrow = lane & 15;

    f32x4 acc[4][4];
    #pragma unroll
    for (int i = 0; i < 4; i++)
        #pragma unroll
        for (int j = 0; j < 4; j++)
            #pragma unroll
            for (int r = 0; r < 4; r++) acc[i][j][r] = 0.f;

    int nk = (K + 31) >> 5;
    for (int t = 0; t < nk; t++) {
        int kk = t << 5;
        // ---- stage A tile (rows m0.., always valid) ----
        #pragma unroll
        for (int i = 0; i < 4; i++) {
            int seg = tid + (i << 8);           // 0..1023
            int r = seg >> 3;                   // 0..127
            int ks4 = (seg & 7) << 2;           // 0,4,..,28
            int gk = kk + ks4;
            float v0 = 0.f, v1 = 0.f, v2 = 0.f, v3 = 0.f;
            const float* p = A + (size_t)(m0 + r) * K + gk;
            if (gk + 3 < K) {
                float4 v = *reinterpret_cast<const float4*>(p);
                v0 = v.x; v1 = v.y; v2 = v.z; v3 = v.w;
            } else {
                if (gk + 0 < K) v0 = p[0];
                if (gk + 1 < K) v1 = p[1];
                if (gk + 2 < K) v2 = p[2];
                if (gk + 3 < K) v3 = p[3];
            }
            int swz = (ks4 >> 3) ^ (r & 3) ^ ((r >> 2) & 3);
            int idx = r * 32 + (swz << 3) + (ks4 & 4);
            short4v sv; sv[0] = f2bf(v0); sv[1] = f2bf(v1); sv[2] = f2bf(v2); sv[3] = f2bf(v3);
            *reinterpret_cast<short4v*>(&sA[idx]) = sv;
        }
        // ---- stage B tile (rows n0.., guard N) ----
        #pragma unroll
        for (int i = 0; i < 4; i++) {
            int seg = tid + (i << 8);
            int r = seg >> 3;
            int ks4 = (seg & 7) << 2;
            int gk = kk + ks4;
            float v0 = 0.f, v1 = 0.f, v2 = 0.f, v3 = 0.f;
            if (n0 + r < N) {
                const float* p = Wt + (size_t)(n0 + r) * K + gk;
                if (gk + 3 < K) {
                    float4 v = *reinterpret_cast<const float4*>(p);
                    v0 = v.x; v1 = v.y; v2 = v.z; v3 = v.w;
                } else {
                    if (gk + 0 < K) v0 = p[0];
                    if (gk + 1 < K) v1 = p[1];
                    if (gk + 2 < K) v2 = p[2];
                    if (gk + 3 < K) v3 = p[3];
                }
            }
            int swz = (ks4 >> 3) ^ (r & 3) ^ ((r >> 2) & 3);
            int idx = r * 32 + (swz << 3) + (ks4 & 4);
            short4v sv; sv[0] = f2bf(v0); sv[1] = f2bf(v1); sv[2] = f2bf(v2); sv[3] = f2bf(v3);
            *reinterpret_cast<short4v*>(&sB[idx]) = sv;
        }
        __syncthreads();
        // ---- fragments + MFMA ----
        short8v a[4], b[4];
        #pragma unroll
        for (int i = 0; i < 4; i++) {
            int r = wm + (i << 4) + lrow;
            int swz = chunk ^ (r & 3) ^ ((r >> 2) & 3);
            a[i] = *reinterpret_cast<const short8v*>(&sA[r * 32 + (swz << 3)]);
        }
        #pragma unroll
        for (int j = 0; j < 4; j++) {
            int r = wn + (j << 4) + lrow;
            int swz = chunk ^ (r & 3) ^ ((r >> 2) & 3);
            b[j] = *reinterpret_cast<const short8v*>(&sB[r * 32 + (swz << 3)]);
        }
        #pragma unroll
        for (int i = 0; i < 4; i++)
            #pragma unroll
            for (int j = 0; j < 4; j++)
                acc[i][j] = __builtin_amdgcn_mfma_f32_16x16x32_bf16(a[i], b[j], acc[i][j], 0, 0, 0);
        __syncthreads();
    }
    // ---- epilogue: C/D layout col=lane&15, row=(lane>>4)*4+reg ----
    #pragma unroll
    for (int i = 0; i < 4; i++) {
        int rowb = m0 + wm + (i << 4) + (chunk << 2);
        #pragma unroll
        for (int j = 0; j < 4; j++) {
            int col = n0 + wn + (j << 4) + lrow;
            if (col >= N) continue;
            float bi = bias[col];
            #pragma unroll
            for (int r = 0; r < 4; r++) {
                int row = rowb + r;
                float v = acc[i][j][r];
                if (rowscale) v *= rowscale[row];
                v += bi;
                if (act == 1) v = gelu_exact(v);
                else if (act == 2) v = fmaxf(v, 0.f);
                if (resid) v += resid[(size_t)row * N + col];
                C[(size_t)row * N + col] = v;
            }
        }
    }
}

// ---------------- window attention (single image): one block per (window, head) ----------------
__global__ __launch_bounds__(256) void attn_kernel(
    const float* __restrict__ qkv, const float* __restrict__ biasT,
    float* __restrict__ out)
{
    __shared__ float ks[NTOKW][32];
    __shared__ float vs[NTOKW][32];
    int blk = blockIdx.x;
    int h = blk % NHEADS;
    int win = blk / NHEADS;          // 0..63 within image
    int base = (win >> 3) * WSZ * WW + (win & 7) * WSZ;
    int tid = threadIdx.x;
    for (int idx = tid; idx < NTOKW * HD; idx += 256) {
        int j = idx / HD, d = idx - j * HD;
        int g = base + (j >> 4) * WW + (j & 15);
        ks[j][d] = qkv[(size_t)g * 540 + 180 + h * HD + d];
        vs[j][d] = qkv[(size_t)g * 540 + 360 + h * HD + d];
    }
    ks[tid][30] = 0.f; ks[tid][31] = 0.f; vs[tid][30] = 0.f; vs[tid][31] = 0.f;
    int i = tid;
    int gi = base + (i >> 4) * WW + (i & 15);
    float4 q[8];
    {
        const float scale = 0.18257418583505536f;  // 30^-0.5
        float qq[32];
        #pragma unroll
        for (int d = 0; d < HD; d++) qq[d] = qkv[(size_t)gi * 540 + h * HD + d] * scale;
        qq[30] = 0.f; qq[31] = 0.f;
        #pragma unroll
        for (int r = 0; r < 8; r++) q[r] = make_float4(qq[4*r], qq[4*r+1], qq[4*r+2], qq[4*r+3]);
    }
    __syncthreads();
    const float* bT = biasT + (size_t)h * NTOKW * NTOKW + i;
    float4 acc[8];
    #pragma unroll
    for (int r = 0; r < 8; r++) acc[r] = make_float4(0.f, 0.f, 0.f, 0.f);
    float l = 0.f;
    for (int j = 0; j < NTOKW; j++) {
        const float4* kr = reinterpret_cast<const float4*>(&ks[j][0]);
        float s = bT[(size_t)j * NTOKW];
        #pragma unroll
        for (int r = 0; r < 8; r++) {
            float4 kv = kr[r];
            s += q[r].x * kv.x + q[r].y * kv.y + q[r].z * kv.z + q[r].w * kv.w;
        }
        float p = __expf(s);   // |s| small -> safe without max-shift
        l += p;
        const float4* vr = reinterpret_cast<const float4*>(&vs[j][0]);
        #pragma unroll
        for (int r = 0; r < 8; r++) {
            float4 vv = vr[r];
            acc[r].x += p * vv.x; acc[r].y += p * vv.y; acc[r].z += p * vv.z; acc[r].w += p * vv.w;
        }
    }
    float inv = 1.f / l;
    float accs[32];
    #pragma unroll
    for (int r = 0; r < 8; r++) {
        accs[4*r] = acc[r].x; accs[4*r+1] = acc[r].y; accs[4*r+2] = acc[r].z; accs[4*r+3] = acc[r].w;
    }
    float* orow = out + (size_t)gi * CC + h * HD;
    #pragma unroll
    for (int d = 0; d < HD; d++) orow[d] = accs[d] * inv;
}

// ---------------- depthwise 3x3 conv, NHWC, nimg images ----------------
__global__ void dwconv_kernel(const float* __restrict__ in, const float* __restrict__ w,
                              const float* __restrict__ bias, float* __restrict__ out,
                              int Cc, int dil, int act, int nimg)
{
    size_t idx = (size_t)blockIdx.x * blockDim.x + threadIdx.x;
    size_t total = (size_t)nimg * IMG * Cc;
    if (idx >= total) return;
    int c = (int)(idx % Cc);
    size_t pos = idx / Cc;
    int px = (int)(pos % WW);
    int py = (int)((pos / WW) % HH);
    int b  = (int)(pos / (WW * HH));
    float acc = bias[c];
    #pragma unroll
    for (int ky = 0; ky < 3; ky++) {
        int iy = py + (ky - 1) * dil;
        if (iy < 0 || iy >= HH) continue;
        #pragma unroll
        for (int kx = 0; kx < 3; kx++) {
            int ix = px + (kx - 1) * dil;
            if (ix < 0 || ix >= WW) continue;
            acc += in[(((size_t)b * HH + iy) * WW + ix) * Cc + c] * w[c * 9 + ky * 3 + kx];
        }
    }
    if (act == 1) acc = gelu_exact(acc);
    else if (act == 2) acc = fmaxf(acc, 0.f);
    out[idx] = acc;
}

// ---------------- GAP partial sums: part[b][chunk][c] ----------------
__global__ void gap_kernel(const float* __restrict__ y, float* __restrict__ part)
{
    int blk = blockIdx.x;
    int b = blk >> 5, chunk = blk & 31;
    int c = threadIdx.x;
    if (c >= CC) return;
    size_t basep = ((size_t)b * IMG + (size_t)chunk * 512) * CC;
    float s = 0.f;
    for (int p = 0; p < 512; p++) s += y[basep + (size_t)p * CC + c];
    part[((size_t)b * 32 + chunk) * CC + c] = s;
}

// ---------------- channel attention (tiny) ----------------
__global__ void ca_kernel(const float* __restrict__ part,
                          const float* __restrict__ w1, const float* __restrict__ b1,
                          const float* __restrict__ w2, const float* __restrict__ b2,
                          float* __restrict__ ca)
{
    __shared__ float gap[BB * CC];
    __shared__ float s1[BB * 6];
    int tid = threadIdx.x;
    for (int idx = tid; idx < BB * CC; idx += 256) {
        int b = idx / CC, c = idx % CC;
        float s = 0.f;
        for (int ch = 0; ch < 32; ch++) s += part[((size_t)b * 32 + ch) * CC + c];
        gap[idx] = s * (1.f / IMG);
    }
    __syncthreads();
    if (tid < BB * 6) {
        int b = tid / 6, cs = tid % 6;
        float s = 0.f;
        for (int c = 0; c < CC; c++) s += w1[cs * CC + c] * gap[b * CC + c];
        s1[tid] = fmaxf(s + b1[cs], 0.f);
    }
    __syncthreads();
    for (int idx = tid; idx < BB * CC; idx += 256) {
        int b = idx / CC, c = idx % CC;
        float s = b2[c];
        #pragma unroll
        for (int cs = 0; cs < 6; cs++) s += w2[c * 6 + cs] * s1[b * 6 + cs];
        ca[idx] = 1.f / (1.f + __expf(-s));
    }
}

// ---------------- x1 += 0.01*y4*ca  (in place), then LN2 -> xn2 ----------------
__global__ __launch_bounds__(256) void resid_ln_kernel(
    float* __restrict__ x1, const float* __restrict__ y4, const float* __restrict__ ca,
    const float* __restrict__ g, const float* __restrict__ bb,
    float* __restrict__ xn2)
{
    int wid = threadIdx.x >> 6, lane = threadIdx.x & 63;
    int t = blockIdx.x * 4 + wid;
    int b = t >> 14;
    size_t off = (size_t)t * CC;
    bool has2 = lane < (CC - 128);
    float v0 = x1[off+lane]    + 0.01f * y4[off+lane]    * ca[b*CC + lane];
    float v1 = x1[off+lane+64] + 0.01f * y4[off+lane+64] * ca[b*CC + lane+64];
    float v2 = 0.f;
    if (has2) v2 = x1[off+lane+128] + 0.01f * y4[off+lane+128] * ca[b*CC + lane+128];
    x1[off+lane] = v0; x1[off+lane+64] = v1;
    if (has2) x1[off+lane+128] = v2;
    float s = warp_sum(v0 + v1 + v2);
    float mu = s * (1.f / CC);
    float d0 = v0-mu, d1 = v1-mu, d2 = has2 ? v2-mu : 0.f;
    float var = warp_sum(d0*d0 + d1*d1 + d2*d2) * (1.f / CC);
    float rs = rsqrtf(var + 1e-5f);
    xn2[off+lane]      = d0 * rs * g[lane]      + bb[lane];
    xn2[off+lane+64]   = d1 * rs * g[lane+64]   + bb[lane+64];
    if (has2) xn2[off+lane+128] = d2 * rs * g[lane+128] + bb[lane+128];
}

// ---------------- max/mean over channels per pixel (one image) ----------------
__global__ __launch_bounds__(256) void mpap_kernel(
    const float* __restrict__ h, float* __restrict__ mp, float* __restrict__ ap)
{
    int wid = threadIdx.x >> 6, lane = threadIdx.x & 63;
    int p = blockIdx.x * 4 + wid;
    const float* row = h + (size_t)p * HID;
    float mx = -1e30f, s = 0.f;
    for (int j = lane; j < HID; j += 64) { float v = row[j]; mx = fmaxf(mx, v); s += v; }
    mx = warp_max(mx); s = warp_sum(s);
    if (lane == 0) { mp[p] = mx; ap[p] = s * (1.f / HID); }
}

// ---------------- 7x7 spatial-attention conv + sigmoid (one image) ----------------
__global__ void saconv_kernel(const float* __restrict__ mp, const float* __restrict__ ap,
                              const float* __restrict__ w, float* __restrict__ sa)
{
    int p = blockIdx.x * blockDim.x + threadIdx.x;
    if (p >= IMG) return;
    int px = p % WW, py = p / WW;
    float acc = 0.f;
    for (int ky = 0; ky < 7; ky++) {
        int iy = py + ky - 3;
        if (iy < 0 || iy >= HH) continue;
        for (int kx = 0; kx < 7; kx++) {
            int ix = px + kx - 3;
            if (ix < 0 || ix >= WW) continue;
            int pid = iy * WW + ix;
            acc += mp[pid] * w[ky * 7 + kx] + ap[pid] * w[49 + ky * 7 + kx];
        }
    }
    sa[p] = 1.f / (1.f + __expf(-acc));
}

extern "C" void kernel_launch(void* const* d_in, const int* in_sizes, int n_in,
                              void* d_out, int out_size, void* d_ws, size_t ws_size,
                              hipStream_t stream)
{
    const float* x      = (const float*)d_in[0];
    const int*   rpi    = (const int*)d_in[3];
    const float* n1g    = (const float*)d_in[4];
    const float* n1b    = (const float*)d_in[5];
    const float* rpb    = (const float*)d_in[6];
    const float* qkv_w  = (const float*)d_in[7];
    const float* qkv_b  = (const float*)d_in[8];
    const float* proj_w = (const float*)d_in[9];
    const float* proj_b = (const float*)d_in[10];
    const float* cab_w0 = (const float*)d_in[11];
    const float* cab_b0 = (const float*)d_in[12];
    const float* cab_w1 = (const float*)d_in[13];
    const float* cab_b1 = (const float*)d_in[14];
    const float* cab_w2 = (const float*)d_in[15];
    const float* cab_b2 = (const float*)d_in[16];
    const float* cab_w3 = (const float*)d_in[17];
    const float* cab_b3 = (const float*)d_in[18];
    const float* ca_w1  = (const float*)d_in[19];
    const float* ca_b1  = (const float*)d_in[20];
    const float* ca_w2  = (const float*)d_in[21];
    const float* ca_b2  = (const float*)d_in[22];
    const float* n2g    = (const float*)d_in[23];
    const float* n2b    = (const float*)d_in[24];
    const float* fc1_w  = (const float*)d_in[25];
    const float* fc1_b  = (const float*)d_in[26];
    const float* dw_w   = (const float*)d_in[27];
    const float* dw_b   = (const float*)d_in[28];
    const float* pw_w   = (const float*)d_in[29];
    const float* pw_b   = (const float*)d_in[30];
    const float* sa_w   = (const float*)d_in[31];
    const float* fc2_w  = (const float*)d_in[32];
    const float* fc2_b  = (const float*)d_in[33];
    float* outp = (float*)d_out;
    (void)in_sizes; (void)n_in; (void)out_size; (void)ws_size;

    char* ws = (char*)d_ws;
    const size_t TOKC = (size_t)NTOK * CC * sizeof(float);   // 47,185,920 bytes
    // 5 rotating regions of TOKC each (~225 MB total + ~2.5 MB tail):
    float* R1  = (float*)(ws);               // qkvt_b | y1+y2 | y4 | h3_b
    float* RB  = (float*)(ws + TOKC);        // xn -> xn2
    float* RC  = (float*)(ws + 2 * TOKC);    // attnb -> y3 -> h2_b
    float* RD  = (float*)(ws + 3 * TOKC);    // h1_b
    float* RX  = (float*)(ws + 4 * TOKC);    // x1 = x + proj(attn) (+ conv term)
    char*  tail = ws + 5 * TOKC;
    float* biasT = (float*)tail;                                   // 1,572,864 B
    float* part  = (float*)(tail + 1572864);                       // 92,160 B
    float* cabuf = (float*)(tail + 1572864 + 98304);               // 2,880 B
    float* mp    = (float*)(tail + 1572864 + 131072);              // NTOK*4
    float* ap    = (float*)(tail + 1572864 + 131072 + NTOK*4);     // NTOK*4
    float* sab   = (float*)(tail + 1572864 + 131072 + 2*(size_t)NTOK*4);

    float* xn    = RB;
    float* xn2   = RB;
    float* attnb = RC;
    float* x1    = RX;
    float* qkvt  = R1;                                   // 16384*540 floats
    float* y1    = R1;                                   // NTOK*90
    float* y2    = R1 + (size_t)NTOK * 90;
    float* y3    = RC;
    float* y4    = R1;

    auto gemm = [&](const float* A, const float* Wt, const float* bi, float* Cp,
                    int M, int N, int K, int act, const float* rs, const float* resid) {
        dim3 g((N + 127) / 128, M / 128);
        mgemm_kernel<<<g, dim3(256), 0, stream>>>(A, Wt, bi, Cp, M, N, K, act, rs, resid);
    };

    // 1) LN1 (full batch)
    ln_kernel<<<dim3(NTOK / 4), dim3(256), 0, stream>>>(x, n1g, n1b, xn);
    // 2) bias table
    bias_kernel<<<dim3((NTOKW * NTOKW) / 256), dim3(256), 0, stream>>>(rpi, rpb, biasT);
    // 3) per-image qkv + window attention (qkvt region reused)
    for (int b = 0; b < BB; b++) {
        gemm(xn + (size_t)b * IMG * CC, qkv_w, qkv_b, qkvt, IMG, 540, CC, 0, nullptr, nullptr);
        attn_kernel<<<dim3(64 * NHEADS), dim3(256), 0, stream>>>(
            qkvt, biasT, attnb + (size_t)b * IMG * CC);
    }
    // 4) proj with residual x fused -> x1
    gemm(attnb, proj_w, proj_b, x1, NTOK, CC, CC, 0, nullptr, x);
    // 5) CAB branch (full batch)
    gemm(xn, cab_w0, cab_b0, y1, NTOK, 90, CC, 0, nullptr, nullptr);
    dwconv_kernel<<<dim3((NTOK * 90 + 255) / 256), dim3(256), 0, stream>>>(y1, cab_w1, cab_b1, y2, 90, 1, 1, BB);
    gemm(y2, cab_w2, cab_b2, y3, NTOK, CC, 90, 0, nullptr, nullptr);
    dwconv_kernel<<<dim3((NTOK * CC + 255) / 256), dim3(256), 0, stream>>>(y3, cab_w3, cab_b3, y4, CC, 2, 0, BB);
    gap_kernel<<<dim3(BB * 32), dim3(192), 0, stream>>>(y4, part);
    ca_kernel<<<dim3(1), dim3(256), 0, stream>>>(part, ca_w1, ca_b1, ca_w2, ca_b2, cabuf);
    // 6) x1 += 0.01*y4*ca; LN2 -> xn2
    resid_ln_kernel<<<dim3(NTOK / 4), dim3(256), 0, stream>>>(x1, y4, cabuf, n2g, n2b, xn2);
    // 7) FFN per image (h regions reused)
    for (int b = 0; b < BB; b++) {
        const float* xn2b = xn2 + (size_t)b * IMG * CC;
        float* h1 = RD;
        float* h2 = RC;
        float* h3 = R1;
        gemm(xn2b, fc1_w, fc1_b, h1, IMG, HID, CC, 1, nullptr, nullptr);
        dwconv_kernel<<<dim3((IMG * HID + 255) / 256), dim3(256), 0, stream>>>(h1, dw_w, dw_b, h2, HID, 1, 2, 1);
        gemm(h2, pw_w, pw_b, h3, IMG, HID, HID, 2, nullptr, nullptr);
        mpap_kernel<<<dim3(IMG / 4), dim3(256), 0, stream>>>(h3, mp + (size_t)b * IMG, ap + (size_t)b * IMG);
        saconv_kernel<<<dim3(IMG / 256), dim3(256), 0, stream>>>(
            mp + (size_t)b * IMG, ap + (size_t)b * IMG, sa_w, sab + (size_t)b * IMG);
        gemm(h3, fc2_w, fc2_b, outp + (size_t)b * IMG * CC, IMG, CC, HID, 0,
             sab + (size_t)b * IMG, x1 + (size_t)b * IMG * CC);
    }
}

// Round 4
// 1863.982 us; speedup vs baseline: 1.8685x; 1.2743x over previous
//
#include <hip/hip_runtime.h>
#include <math.h>

#define HH 128
#define WW 128
#define CC 180
#define BB 4
#define IMG (HH*WW)          // 16384 tokens per image
#define NTOK (BB*IMG)        // 65536
#define NHEADS 6
#define HD 30
#define WSZ 16
#define NTOKW (WSZ*WSZ)      // 256
#define HID 720

typedef __attribute__((ext_vector_type(8))) short short8v;
typedef __attribute__((ext_vector_type(4))) float f32x4;
typedef unsigned short ushortw;

__device__ __forceinline__ float warp_sum(float v) {
    #pragma unroll
    for (int o = 32; o > 0; o >>= 1) v += __shfl_xor(v, o);
    return v;
}
__device__ __forceinline__ float warp_max(float v) {
    #pragma unroll
    for (int o = 32; o > 0; o >>= 1) v = fmaxf(v, __shfl_xor(v, o));
    return v;
}
__device__ __forceinline__ float gelu_exact(float v) {
    return 0.5f * v * (1.f + erff(v * 0.70710678118654752f));
}
__device__ __forceinline__ ushortw f2bf(float f) {
    union { float f; unsigned int u; } c; c.f = f;
    unsigned int r = (c.u + 0x7FFFu + ((c.u >> 16) & 1u)) >> 16;
    return (ushortw)r;
}
__device__ __forceinline__ float bf2f(ushortw u) {
    union { unsigned int u; float f; } c; c.u = ((unsigned int)u) << 16; return c.f;
}

// ---------------- weight fp32 -> bf16 with N/K padding (zeros) ----------------
__global__ void wconv_kernel(const float* __restrict__ src, ushortw* __restrict__ dst,
                             int N, int K, int Npad, int Kpad)
{
    int idx = blockIdx.x * blockDim.x + threadIdx.x;
    if (idx >= Npad * Kpad) return;
    int r = idx / Kpad, k = idx % Kpad;
    float v = (r < N && k < K) ? src[r * K + k] : 0.f;
    dst[idx] = f2bf(v);
}

// ---------------- LayerNorm -> bf16 out, stride 192 (cols 180..191 zero) ----------------
__global__ __launch_bounds__(256) void ln_kernel(
    const float* __restrict__ x, const float* __restrict__ g,
    const float* __restrict__ b, ushortw* __restrict__ out)
{
    int wid = threadIdx.x >> 6, lane = threadIdx.x & 63;
    int t = blockIdx.x * 4 + wid;
    size_t off = (size_t)t * CC;
    size_t off2 = (size_t)t * 192;
    bool has2 = lane < (CC - 128);
    float v0 = x[off + lane];
    float v1 = x[off + lane + 64];
    float v2 = has2 ? x[off + lane + 128] : 0.f;
    float s = warp_sum(v0 + v1 + v2);
    float mu = s * (1.f / CC);
    float d0 = v0 - mu, d1 = v1 - mu, d2 = has2 ? v2 - mu : 0.f;
    float var = warp_sum(d0*d0 + d1*d1 + d2*d2) * (1.f / CC);
    float rs = rsqrtf(var + 1e-5f);
    out[off2 + lane]      = f2bf(d0 * rs * g[lane]      + b[lane]);
    out[off2 + lane + 64] = f2bf(d1 * rs * g[lane + 64] + b[lane + 64]);
    out[off2 + lane + 128] = has2 ? f2bf(d2 * rs * g[lane + 128] + b[lane + 128]) : (ushortw)0;
}

// ---------------- relative position bias, transposed [h][j][i] ----------------
__global__ void bias_kernel(const int* __restrict__ rpi, const float* __restrict__ rpb,
                            float* __restrict__ biasT)
{
    int idx = blockIdx.x * blockDim.x + threadIdx.x;
    if (idx >= NTOKW * NTOKW) return;
    int i = idx / NTOKW, j = idx % NTOKW;
    int r = rpi[idx];
    #pragma unroll
    for (int h = 0; h < NHEADS; h++)
        biasT[(size_t)h * NTOKW * NTOKW + (size_t)j * NTOKW + i] = rpb[r * NHEADS + h];
}

// ---------------- bf16 MFMA GEMM, m97 structure ----------------
// C[M,N] = A[M,Kp] @ W[Npad,Kp]^T. A,W bf16 (K padded w/ zeros, W rows padded).
// 128x128 tile, BK=64, 4 waves, global_load_lds(16B) staging, XOR chunk swizzle
// (applied to global src AND ds_read -> conflict-free, rule both-sides).
// M%128==0 required. Epilogue: rowscale, +bias, act, +resid, out fp32/bf16, zfill to ldc.
__global__ __launch_bounds__(256) void mgemm_kernel(
    const ushortw* __restrict__ A, const ushortw* __restrict__ Wt,
    const float* __restrict__ bias, void* __restrict__ Cout,
    int M, int N, int Kp, int ldc, int outbf, int zfill, int act,
    const float* __restrict__ rowscale, const float* __restrict__ resid)
{
    __shared__ ushortw sA[128 * 64];
    __shared__ ushortw sB[128 * 64];
    int tid = threadIdx.x, lane = tid & 63, wid = tid >> 6;
    int m0 = blockIdx.y << 7, n0 = blockIdx.x << 7;
    int wm = (wid >> 1) << 6, wn = (wid & 1) << 6;
    int lrow = lane & 15, kgrp = lane >> 4;

    f32x4 acc[4][4];
    #pragma unroll
    for (int i = 0; i < 4; i++)
        #pragma unroll
        for (int j = 0; j < 4; j++)
            #pragma unroll
            for (int r = 0; r < 4; r++) acc[i][j][r] = 0.f;

    int nk = Kp >> 6;
    for (int t = 0; t < nk; t++) {
        int kk = t << 6;
        #pragma unroll
        for (int q = 0; q < 4; q++) {
            int seg = (wid << 2) + q;                 // 0..15
            int row = (seg << 3) + (lane >> 3);       // 0..127
            int cg = (lane & 7) ^ (row & 7);          // swizzled global chunk
            const ushortw* ga = A + (size_t)(m0 + row) * Kp + kk + (cg << 3);
            __builtin_amdgcn_global_load_lds(
                (const __attribute__((address_space(1))) void*)ga,
                (__attribute__((address_space(3))) void*)&sA[seg << 9], 16, 0, 0);
            const ushortw* gb = Wt + (size_t)(n0 + row) * Kp + kk + (cg << 3);
            __builtin_amdgcn_global_load_lds(
                (const __attribute__((address_space(1))) void*)gb,
                (__attribute__((address_space(3))) void*)&sB[seg << 9], 16, 0, 0);
        }
        __syncthreads();
        short8v a[4][2], b[4][2];
        #pragma unroll
        for (int i = 0; i < 4; i++) {
            int r = wm + (i << 4) + lrow;
            #pragma unroll
            for (int s = 0; s < 2; s++) {
                int slot = ((s << 2) + kgrp) ^ (r & 7);
                a[i][s] = *reinterpret_cast<const short8v*>(&sA[(r << 6) + (slot << 3)]);
            }
        }
        #pragma unroll
        for (int j = 0; j < 4; j++) {
            int r = wn + (j << 4) + lrow;
            #pragma unroll
            for (int s = 0; s < 2; s++) {
                int slot = ((s << 2) + kgrp) ^ (r & 7);
                b[j][s] = *reinterpret_cast<const short8v*>(&sB[(r << 6) + (slot << 3)]);
            }
        }
        #pragma unroll
        for (int i = 0; i < 4; i++)
            #pragma unroll
            for (int j = 0; j < 4; j++) {
                acc[i][j] = __builtin_amdgcn_mfma_f32_16x16x32_bf16(a[i][0], b[j][0], acc[i][j], 0, 0, 0);
                acc[i][j] = __builtin_amdgcn_mfma_f32_16x16x32_bf16(a[i][1], b[j][1], acc[i][j], 0, 0, 0);
            }
        __syncthreads();
    }
    // epilogue: C/D layout col=lane&15, row=(lane>>4)*4+reg (verified r2)
    #pragma unroll
    for (int i = 0; i < 4; i++) {
        int rowb = m0 + wm + (i << 4) + (kgrp << 2);
        #pragma unroll
        for (int j = 0; j < 4; j++) {
            int col = n0 + wn + (j << 4) + lrow;
            if (col < N) {
                float bi = bias[col];
                #pragma unroll
                for (int r = 0; r < 4; r++) {
                    int row = rowb + r;
                    float v = acc[i][j][r];
                    if (rowscale) v *= rowscale[row];
                    v += bi;
                    if (act == 1) v = gelu_exact(v);
                    else if (act == 2) v = fmaxf(v, 0.f);
                    if (resid) v += resid[(size_t)row * N + col];
                    if (outbf) ((ushortw*)Cout)[(size_t)row * ldc + col] = f2bf(v);
                    else       ((float*)Cout)[(size_t)row * ldc + col] = v;
                }
            } else if (zfill && col < ldc) {
                #pragma unroll
                for (int r = 0; r < 4; r++) {
                    int row = rowb + r;
                    if (outbf) ((ushortw*)Cout)[(size_t)row * ldc + col] = 0;
                    else       ((float*)Cout)[(size_t)row * ldc + col] = 0.f;
                }
            }
        }
    }
}

// ---------------- window attention (single image), bf16 qkv in, bf16 out (stride 192) ----------------
__global__ __launch_bounds__(256) void attn_kernel(
    const ushortw* __restrict__ qkv, const float* __restrict__ biasT,
    ushortw* __restrict__ out)
{
    __shared__ float ks[NTOKW][32];
    __shared__ float vs[NTOKW][32];
    int blk = blockIdx.x;
    int h = blk % NHEADS;
    int win = blk / NHEADS;          // 0..63 within image
    int base = (win >> 3) * WSZ * WW + (win & 7) * WSZ;
    int tid = threadIdx.x;
    for (int idx = tid; idx < NTOKW * HD; idx += 256) {
        int j = idx / HD, d = idx - j * HD;
        int g = base + (j >> 4) * WW + (j & 15);
        ks[j][d] = bf2f(qkv[(size_t)g * 540 + 180 + h * HD + d]);
        vs[j][d] = bf2f(qkv[(size_t)g * 540 + 360 + h * HD + d]);
    }
    ks[tid][30] = 0.f; ks[tid][31] = 0.f; vs[tid][30] = 0.f; vs[tid][31] = 0.f;
    int i = tid;
    int gi = base + (i >> 4) * WW + (i & 15);
    float4 q[8];
    {
        const float scale = 0.18257418583505536f;  // 30^-0.5
        float qq[32];
        #pragma unroll
        for (int d = 0; d < HD; d++) qq[d] = bf2f(qkv[(size_t)gi * 540 + h * HD + d]) * scale;
        qq[30] = 0.f; qq[31] = 0.f;
        #pragma unroll
        for (int r = 0; r < 8; r++) q[r] = make_float4(qq[4*r], qq[4*r+1], qq[4*r+2], qq[4*r+3]);
    }
    __syncthreads();
    const float* bT = biasT + (size_t)h * NTOKW * NTOKW + i;
    float4 acc[8];
    #pragma unroll
    for (int r = 0; r < 8; r++) acc[r] = make_float4(0.f, 0.f, 0.f, 0.f);
    float l = 0.f;
    for (int j = 0; j < NTOKW; j++) {
        const float4* kr = reinterpret_cast<const float4*>(&ks[j][0]);
        float s = bT[(size_t)j * NTOKW];
        #pragma unroll
        for (int r = 0; r < 8; r++) {
            float4 kv = kr[r];
            s += q[r].x * kv.x + q[r].y * kv.y + q[r].z * kv.z + q[r].w * kv.w;
        }
        float p = __expf(s);
        l += p;
        const float4* vr = reinterpret_cast<const float4*>(&vs[j][0]);
        #pragma unroll
        for (int r = 0; r < 8; r++) {
            float4 vv = vr[r];
            acc[r].x += p * vv.x; acc[r].y += p * vv.y; acc[r].z += p * vv.z; acc[r].w += p * vv.w;
        }
    }
    float inv = 1.f / l;
    float accs[32];
    #pragma unroll
    for (int r = 0; r < 8; r++) {
        accs[4*r] = acc[r].x; accs[4*r+1] = acc[r].y; accs[4*r+2] = acc[r].z; accs[4*r+3] = acc[r].w;
    }
    ushortw* orow = out + (size_t)gi * 192 + h * HD;
    #pragma unroll
    for (int d = 0; d < HD; d++) orow[d] = f2bf(accs[d] * inv);
    if (h == 0) {   // zero pad cols 180..191
        for (int idx2 = tid; idx2 < NTOKW * 12; idx2 += 256) {
            int j = idx2 / 12, d = idx2 % 12;
            int gj = base + (j >> 4) * WW + (j & 15);
            out[(size_t)gj * 192 + 180 + d] = 0;
        }
    }
}

// ---------------- depthwise 3x3 conv, bf16 in, bf16/fp32 out, padded out stride ----------------
template<int OUTBF>
__global__ void dwconv_kernel(const ushortw* __restrict__ in, const float* __restrict__ w,
                              const float* __restrict__ bias, void* __restrict__ out,
                              int Cc, int Cop, int dil, int act, int nimg)
{
    size_t idx = (size_t)blockIdx.x * blockDim.x + threadIdx.x;
    size_t total = (size_t)nimg * IMG * Cop;
    if (idx >= total) return;
    int c = (int)(idx % Cop);
    size_t pos = idx / Cop;
    if (c >= Cc) {
        if (OUTBF) ((ushortw*)out)[idx] = 0; else ((float*)out)[idx] = 0.f;
        return;
    }
    int px = (int)(pos % WW);
    int py = (int)((pos / WW) % HH);
    int b  = (int)(pos / (WW * HH));
    float acc = bias[c];
    #pragma unroll
    for (int ky = 0; ky < 3; ky++) {
        int iy = py + (ky - 1) * dil;
        if (iy < 0 || iy >= HH) continue;
        #pragma unroll
        for (int kx = 0; kx < 3; kx++) {
            int ix = px + (kx - 1) * dil;
            if (ix < 0 || ix >= WW) continue;
            acc += bf2f(in[(((size_t)b * HH + iy) * WW + ix) * Cc + c]) * w[c * 9 + ky * 3 + kx];
        }
    }
    if (act == 1) acc = gelu_exact(acc);
    else if (act == 2) acc = fmaxf(acc, 0.f);
    if (OUTBF) ((ushortw*)out)[idx] = f2bf(acc); else ((float*)out)[idx] = acc;
}

// ---------------- GAP partial sums over fp32 y4 ----------------
__global__ void gap_kernel(const float* __restrict__ y, float* __restrict__ part)
{
    int blk = blockIdx.x;
    int b = blk >> 5, chunk = blk & 31;
    int c = threadIdx.x;
    if (c >= CC) return;
    size_t basep = ((size_t)b * IMG + (size_t)chunk * 512) * CC;
    float s = 0.f;
    for (int p = 0; p < 512; p++) s += y[basep + (size_t)p * CC + c];
    part[((size_t)b * 32 + chunk) * CC + c] = s;
}

// ---------------- channel attention (tiny) ----------------
__global__ void ca_kernel(const float* __restrict__ part,
                          const float* __restrict__ w1, const float* __restrict__ b1,
                          const float* __restrict__ w2, const float* __restrict__ b2,
                          float* __restrict__ ca)
{
    __shared__ float gap[BB * CC];
    __shared__ float s1[BB * 6];
    int tid = threadIdx.x;
    for (int idx = tid; idx < BB * CC; idx += 256) {
        int b = idx / CC, c = idx % CC;
        float s = 0.f;
        for (int ch = 0; ch < 32; ch++) s += part[((size_t)b * 32 + ch) * CC + c];
        gap[idx] = s * (1.f / IMG);
    }
    __syncthreads();
    if (tid < BB * 6) {
        int b = tid / 6, cs = tid % 6;
        float s = 0.f;
        for (int c = 0; c < CC; c++) s += w1[cs * CC + c] * gap[b * CC + c];
        s1[tid] = fmaxf(s + b1[cs], 0.f);
    }
    __syncthreads();
    for (int idx = tid; idx < BB * CC; idx += 256) {
        int b = idx / CC, c = idx % CC;
        float s = b2[c];
        #pragma unroll
        for (int cs = 0; cs < 6; cs++) s += w2[c * 6 + cs] * s1[b * 6 + cs];
        ca[idx] = 1.f / (1.f + __expf(-s));
    }
}

// ---------------- x1 += 0.01*y4*ca (fp32, in place); LN2 -> bf16 xn2 (stride 192) ----------------
__global__ __launch_bounds__(256) void resid_ln_kernel(
    float* __restrict__ x1, const float* __restrict__ y4, const float* __restrict__ ca,
    const float* __restrict__ g, const float* __restrict__ bb,
    ushortw* __restrict__ xn2)
{
    int wid = threadIdx.x >> 6, lane = threadIdx.x & 63;
    int t = blockIdx.x * 4 + wid;
    int b = t >> 14;
    size_t off = (size_t)t * CC;
    size_t off2 = (size_t)t * 192;
    bool has2 = lane < (CC - 128);
    float v0 = x1[off+lane]    + 0.01f * y4[off+lane]    * ca[b*CC + lane];
    float v1 = x1[off+lane+64] + 0.01f * y4[off+lane+64] * ca[b*CC + lane+64];
    float v2 = 0.f;
    if (has2) v2 = x1[off+lane+128] + 0.01f * y4[off+lane+128] * ca[b*CC + lane+128];
    x1[off+lane] = v0; x1[off+lane+64] = v1;
    if (has2) x1[off+lane+128] = v2;
    float s = warp_sum(v0 + v1 + v2);
    float mu = s * (1.f / CC);
    float d0 = v0-mu, d1 = v1-mu, d2 = has2 ? v2-mu : 0.f;
    float var = warp_sum(d0*d0 + d1*d1 + d2*d2) * (1.f / CC);
    float rs = rsqrtf(var + 1e-5f);
    xn2[off2+lane]      = f2bf(d0 * rs * g[lane]      + bb[lane]);
    xn2[off2+lane+64]   = f2bf(d1 * rs * g[lane+64]   + bb[lane+64]);
    xn2[off2+lane+128]  = has2 ? f2bf(d2 * rs * g[lane+128] + bb[lane+128]) : (ushortw)0;
}

// ---------------- max/mean over channels per pixel (bf16 h3, stride 768, 720 cols) ----------------
__global__ __launch_bounds__(256) void mpap_kernel(
    const ushortw* __restrict__ h, float* __restrict__ mp, float* __restrict__ ap)
{
    int wid = threadIdx.x >> 6, lane = threadIdx.x & 63;
    int p = blockIdx.x * 4 + wid;
    const ushortw* row = h + (size_t)p * 768;
    float mx = -1e30f, s = 0.f;
    for (int j = lane; j < HID; j += 64) { float v = bf2f(row[j]); mx = fmaxf(mx, v); s += v; }
    mx = warp_max(mx); s = warp_sum(s);
    if (lane == 0) { mp[p] = mx; ap[p] = s * (1.f / HID); }
}

// ---------------- 7x7 spatial-attention conv + sigmoid (one image) ----------------
__global__ void saconv_kernel(const float* __restrict__ mp, const float* __restrict__ ap,
                              const float* __restrict__ w, float* __restrict__ sa)
{
    int p = blockIdx.x * blockDim.x + threadIdx.x;
    if (p >= IMG) return;
    int px = p % WW, py = p / WW;
    float acc = 0.f;
    for (int ky = 0; ky < 7; ky++) {
        int iy = py + ky - 3;
        if (iy < 0 || iy >= HH) continue;
        for (int kx = 0; kx < 7; kx++) {
            int ix = px + kx - 3;
            if (ix < 0 || ix >= WW) continue;
            int pid = iy * WW + ix;
            acc += mp[pid] * w[ky * 7 + kx] + ap[pid] * w[49 + ky * 7 + kx];
        }
    }
    sa[p] = 1.f / (1.f + __expf(-acc));
}

extern "C" void kernel_launch(void* const* d_in, const int* in_sizes, int n_in,
                              void* d_out, int out_size, void* d_ws, size_t ws_size,
                              hipStream_t stream)
{
    const float* x      = (const float*)d_in[0];
    const int*   rpi    = (const int*)d_in[3];
    const float* n1g    = (const float*)d_in[4];
    const float* n1b    = (const float*)d_in[5];
    const float* rpb    = (const float*)d_in[6];
    const float* qkv_w  = (const float*)d_in[7];
    const float* qkv_b  = (const float*)d_in[8];
    const float* proj_w = (const float*)d_in[9];
    const float* proj_b = (const float*)d_in[10];
    const float* cab_w0 = (const float*)d_in[11];
    const float* cab_b0 = (const float*)d_in[12];
    const float* cab_w1 = (const float*)d_in[13];
    const float* cab_b1 = (const float*)d_in[14];
    const float* cab_w2 = (const float*)d_in[15];
    const float* cab_b2 = (const float*)d_in[16];
    const float* cab_w3 = (const float*)d_in[17];
    const float* cab_b3 = (const float*)d_in[18];
    const float* ca_w1  = (const float*)d_in[19];
    const float* ca_b1  = (const float*)d_in[20];
    const float* ca_w2  = (const float*)d_in[21];
    const float* ca_b2  = (const float*)d_in[22];
    const float* n2g    = (const float*)d_in[23];
    const float* n2b    = (const float*)d_in[24];
    const float* fc1_w  = (const float*)d_in[25];
    const float* fc1_b  = (const float*)d_in[26];
    const float* dw_w   = (const float*)d_in[27];
    const float* dw_b   = (const float*)d_in[28];
    const float* pw_w   = (const float*)d_in[29];
    const float* pw_b   = (const float*)d_in[30];
    const float* sa_w   = (const float*)d_in[31];
    const float* fc2_w  = (const float*)d_in[32];
    const float* fc2_b  = (const float*)d_in[33];
    float* outp = (float*)d_out;
    (void)in_sizes; (void)n_in; (void)out_size; (void)ws_size;

    char* ws = (char*)d_ws;
    // regions (bytes)
    const size_t S0 = (size_t)NTOK * 192 * 2;      // 25,165,824  xnb -> xn2b
    const size_t S1 = (size_t)IMG * 540 * 2;       // 17,694,720  qkvtb -> y1b
    const size_t S2 = (size_t)NTOK * 192 * 2;      // 25,165,824  attnbb -> y3b -> h2b
    const size_t S3 = (size_t)NTOK * 180 * 4;      // 47,185,920  x1 (fp32, persistent)
    const size_t S4 = (size_t)NTOK * 128 * 2;      // 16,777,216  y2b
    const size_t S5 = (size_t)IMG * 720 * 2 + (size_t)IMG * 768 * 2; // 48,758,784  y4 / h1b+h3b
    char* pA0 = ws;
    char* pA1 = pA0 + S0;
    char* pA2 = pA1 + S1;
    char* pA3 = pA2 + S2;
    char* pA4 = pA3 + S3;
    char* pA5 = pA4 + S4;
    char* tail = pA5 + S5;

    ushortw* xnb    = (ushortw*)pA0;           // [NTOK][192]
    ushortw* xn2b   = (ushortw*)pA0;
    ushortw* qkvtb  = (ushortw*)pA1;           // [IMG][540]
    ushortw* y1b    = (ushortw*)pA1;           // [NTOK][90]
    ushortw* attnbb = (ushortw*)pA2;           // [NTOK][192]
    ushortw* y3b    = (ushortw*)pA2;           // [NTOK][180]
    ushortw* h2b    = (ushortw*)pA2;           // [IMG][768]
    float*   x1     = (float*)pA3;             // [NTOK][180]
    ushortw* y2b    = (ushortw*)pA4;           // [NTOK][128]
    float*   y4     = (float*)pA5;             // [NTOK][180]
    ushortw* h1b    = (ushortw*)pA5;           // [IMG][720]
    ushortw* h3b    = (ushortw*)(pA5 + (size_t)IMG * 720 * 2); // [IMG][768]

    // bf16 weights (padded): sizes in elements
    ushortw* wqkv  = (ushortw*)tail;                        // 640 x 192
    ushortw* wproj = wqkv  + 640 * 192;                     // 256 x 192
    ushortw* wcab0 = wproj + 256 * 192;                     // 128 x 192
    ushortw* wcab2 = wcab0 + 128 * 192;                     // 256 x 128
    ushortw* wfc1  = wcab2 + 256 * 128;                     // 768 x 192
    ushortw* wpw   = wfc1  + 768 * 192;                     // 768 x 768
    ushortw* wfc2  = wpw   + 768 * 768;                     // 256 x 768
    char* tail2 = (char*)(wfc2 + 256 * 768);
    float* biasT = (float*)tail2;                           // 6*256*256
    float* part  = (float*)(tail2 + 1572864);
    float* cabuf = (float*)(tail2 + 1572864 + 98304);
    float* mp    = (float*)(tail2 + 1572864 + 131072);
    float* ap    = (float*)(tail2 + 1572864 + 131072 + (size_t)NTOK * 4);
    float* sab   = (float*)(tail2 + 1572864 + 131072 + 2 * (size_t)NTOK * 4);

    auto wc = [&](const float* src, ushortw* dst, int N, int K, int Np, int Kp) {
        wconv_kernel<<<dim3((Np * Kp + 255) / 256), dim3(256), 0, stream>>>(src, dst, N, K, Np, Kp);
    };
    auto gemm = [&](const ushortw* A, const ushortw* Wt, const float* bi, void* Cp,
                    int M, int N, int Kp, int ldc, int outbf, int zfill, int act,
                    const float* rs, const float* resid) {
        dim3 g((N + 127) / 128, M / 128);
        mgemm_kernel<<<g, dim3(256), 0, stream>>>(A, Wt, bi, Cp, M, N, Kp, ldc, outbf, zfill, act, rs, resid);
    };

    // 0) weights -> bf16 padded
    wc(qkv_w, wqkv, 540, 180, 640, 192);
    wc(proj_w, wproj, 180, 180, 256, 192);
    wc(cab_w0, wcab0, 90, 180, 128, 192);
    wc(cab_w2, wcab2, 180, 90, 256, 128);
    wc(fc1_w, wfc1, 720, 180, 768, 192);
    wc(pw_w, wpw, 720, 720, 768, 768);
    wc(fc2_w, wfc2, 180, 720, 256, 768);

    // 1) LN1 -> bf16 xnb
    ln_kernel<<<dim3(NTOK / 4), dim3(256), 0, stream>>>(x, n1g, n1b, xnb);
    // 2) bias table
    bias_kernel<<<dim3((NTOKW * NTOKW) / 256), dim3(256), 0, stream>>>(rpi, rpb, biasT);
    // 3) per-image qkv + window attention
    for (int b = 0; b < BB; b++) {
        gemm(xnb + (size_t)b * IMG * 192, wqkv, qkv_b, qkvtb, IMG, 540, 192, 540, 1, 0, 0, nullptr, nullptr);
        attn_kernel<<<dim3(64 * NHEADS), dim3(256), 0, stream>>>(
            qkvtb, biasT, attnbb + (size_t)b * IMG * 192);
    }
    // 4) CAB part 1 (uses xnb; then xnb dead)
    gemm(xnb, wcab0, cab_b0, y1b, NTOK, 90, 192, 90, 1, 0, 0, nullptr, nullptr);
    dwconv_kernel<1><<<dim3((NTOK * 128 + 255) / 256), dim3(256), 0, stream>>>(
        y1b, cab_w1, cab_b1, y2b, 90, 128, 1, 1, BB);
    // 5) proj with residual x -> x1 (attnbb dead after)
    gemm(attnbb, wproj, proj_b, x1, NTOK, 180, 192, 180, 0, 0, 0, nullptr, x);
    // 6) CAB part 2
    gemm(y2b, wcab2, cab_b2, y3b, NTOK, 180, 128, 180, 1, 0, 0, nullptr, nullptr);
    dwconv_kernel<0><<<dim3((NTOK * 180 + 255) / 256), dim3(256), 0, stream>>>(
        y3b, cab_w3, cab_b3, y4, 180, 180, 2, 0, BB);
    gap_kernel<<<dim3(BB * 32), dim3(192), 0, stream>>>(y4, part);
    ca_kernel<<<dim3(1), dim3(256), 0, stream>>>(part, ca_w1, ca_b1, ca_w2, ca_b2, cabuf);
    // 7) x1 += 0.01*y4*ca; LN2 -> bf16 xn2b
    resid_ln_kernel<<<dim3(NTOK / 4), dim3(256), 0, stream>>>(x1, y4, cabuf, n2g, n2b, xn2b);
    // 8) FFN per image
    for (int b = 0; b < BB; b++) {
        gemm(xn2b + (size_t)b * IMG * 192, wfc1, fc1_b, h1b, IMG, 720, 192, 720, 1, 0, 1, nullptr, nullptr);
        dwconv_kernel<1><<<dim3((IMG * 768 + 255) / 256), dim3(256), 0, stream>>>(
            h1b, dw_w, dw_b, h2b, 720, 768, 1, 2, 1);
        gemm(h2b, wpw, pw_b, h3b, IMG, 720, 768, 768, 1, 1, 2, nullptr, nullptr);
        mpap_kernel<<<dim3(IMG / 4), dim3(256), 0, stream>>>(h3b, mp + (size_t)b * IMG, ap + (size_t)b * IMG);
        saconv_kernel<<<dim3(IMG / 256), dim3(256), 0, stream>>>(
            mp + (size_t)b * IMG, ap + (size_t)b * IMG, sa_w, sab + (size_t)b * IMG);
        gemm(h3b, wfc2, fc2_b, outp + (size_t)b * IMG * 180, IMG, 180, 768, 180, 0, 0, 0,
             sab + (size_t)b * IMG, x1 + (size_t)b * IMG * 180);
    }
}

// Round 5
// 1441.454 us; speedup vs baseline: 2.4162x; 1.2931x over previous
//
#include <hip/hip_runtime.h>
#include <math.h>

#define HH 128
#define WW 128
#define CC 180
#define BB 4
#define IMG (HH*WW)          // 16384 tokens per image
#define NTOK (BB*IMG)        // 65536
#define HALFTOK (2*IMG)      // 32768
#define NHEADS 6
#define HD 30
#define WSZ 16
#define NTOKW (WSZ*WSZ)      // 256
#define HID 720

typedef __attribute__((ext_vector_type(8))) short short8v;
typedef __attribute__((ext_vector_type(4))) float f32x4;
typedef unsigned short ushortw;

__device__ __forceinline__ float warp_sum(float v) {
    #pragma unroll
    for (int o = 32; o > 0; o >>= 1) v += __shfl_xor(v, o);
    return v;
}
__device__ __forceinline__ float warp_max(float v) {
    #pragma unroll
    for (int o = 32; o > 0; o >>= 1) v = fmaxf(v, __shfl_xor(v, o));
    return v;
}
__device__ __forceinline__ float gelu_exact(float v) {
    return 0.5f * v * (1.f + erff(v * 0.70710678118654752f));
}
__device__ __forceinline__ ushortw f2bf(float f) {
    union { float f; unsigned int u; } c; c.f = f;
    unsigned int r = (c.u + 0x7FFFu + ((c.u >> 16) & 1u)) >> 16;
    return (ushortw)r;
}
__device__ __forceinline__ float bf2f(ushortw u) {
    union { unsigned int u; float f; } c; c.u = ((unsigned int)u) << 16; return c.f;
}

// ---------------- weight fp32 -> bf16 with N/K padding (zeros) ----------------
__global__ void wconv_kernel(const float* __restrict__ src, ushortw* __restrict__ dst,
                             int N, int K, int Npad, int Kpad)
{
    int idx = blockIdx.x * blockDim.x + threadIdx.x;
    if (idx >= Npad * Kpad) return;
    int r = idx / Kpad, k = idx % Kpad;
    float v = (r < N && k < K) ? src[r * K + k] : 0.f;
    dst[idx] = f2bf(v);
}

// ---------------- dw weight transpose [C][9] -> [9][COP] (+ padded bias) ----------------
__global__ void dwt_kernel(const float* __restrict__ src, const float* __restrict__ bsrc,
                           float* __restrict__ dst, float* __restrict__ bdst,
                           int C, int COP)
{
    int idx = blockIdx.x * blockDim.x + threadIdx.x;
    if (idx >= COP * 9) return;
    int c = idx / 9, k = idx - c * 9;
    dst[k * COP + c] = (c < C) ? src[c * 9 + k] : 0.f;
    if (k == 0) bdst[c] = (c < C) ? bsrc[c] : 0.f;
}

// ---------------- LayerNorm -> bf16 out, stride 192 (cols 180..191 zero) ----------------
__global__ __launch_bounds__(256) void ln_kernel(
    const float* __restrict__ x, const float* __restrict__ g,
    const float* __restrict__ b, ushortw* __restrict__ out)
{
    int wid = threadIdx.x >> 6, lane = threadIdx.x & 63;
    int t = blockIdx.x * 4 + wid;
    size_t off = (size_t)t * CC;
    size_t off2 = (size_t)t * 192;
    bool has2 = lane < (CC - 128);
    float v0 = x[off + lane];
    float v1 = x[off + lane + 64];
    float v2 = has2 ? x[off + lane + 128] : 0.f;
    float s = warp_sum(v0 + v1 + v2);
    float mu = s * (1.f / CC);
    float d0 = v0 - mu, d1 = v1 - mu, d2 = has2 ? v2 - mu : 0.f;
    float var = warp_sum(d0*d0 + d1*d1 + d2*d2) * (1.f / CC);
    float rs = rsqrtf(var + 1e-5f);
    out[off2 + lane]      = f2bf(d0 * rs * g[lane]      + b[lane]);
    out[off2 + lane + 64] = f2bf(d1 * rs * g[lane + 64] + b[lane + 64]);
    out[off2 + lane + 128] = has2 ? f2bf(d2 * rs * g[lane + 128] + b[lane + 128]) : (ushortw)0;
}

// ---------------- relative position bias, transposed [h][j][i] ----------------
__global__ void bias_kernel(const int* __restrict__ rpi, const float* __restrict__ rpb,
                            float* __restrict__ biasT)
{
    int idx = blockIdx.x * blockDim.x + threadIdx.x;
    if (idx >= NTOKW * NTOKW) return;
    int i = idx / NTOKW, j = idx % NTOKW;
    int r = rpi[idx];
    #pragma unroll
    for (int h = 0; h < NHEADS; h++)
        biasT[(size_t)h * NTOKW * NTOKW + (size_t)j * NTOKW + i] = rpb[r * NHEADS + h];
}

// ---------------- bf16 MFMA GEMM, m97 structure (verified r4) ----------------
__global__ __launch_bounds__(256) void mgemm_kernel(
    const ushortw* __restrict__ A, const ushortw* __restrict__ Wt,
    const float* __restrict__ bias, void* __restrict__ Cout,
    int M, int N, int Kp, int ldc, int outbf, int zfill, int act,
    const float* __restrict__ rowscale, const float* __restrict__ resid)
{
    __shared__ ushortw sA[128 * 64];
    __shared__ ushortw sB[128 * 64];
    int tid = threadIdx.x, lane = tid & 63, wid = tid >> 6;
    int m0 = blockIdx.y << 7, n0 = blockIdx.x << 7;
    int wm = (wid >> 1) << 6, wn = (wid & 1) << 6;
    int lrow = lane & 15, kgrp = lane >> 4;

    f32x4 acc[4][4];
    #pragma unroll
    for (int i = 0; i < 4; i++)
        #pragma unroll
        for (int j = 0; j < 4; j++)
            #pragma unroll
            for (int r = 0; r < 4; r++) acc[i][j][r] = 0.f;

    int nk = Kp >> 6;
    for (int t = 0; t < nk; t++) {
        int kk = t << 6;
        #pragma unroll
        for (int q = 0; q < 4; q++) {
            int seg = (wid << 2) + q;                 // 0..15
            int row = (seg << 3) + (lane >> 3);       // 0..127
            int cg = (lane & 7) ^ (row & 7);          // swizzled global chunk
            const ushortw* ga = A + (size_t)(m0 + row) * Kp + kk + (cg << 3);
            __builtin_amdgcn_global_load_lds(
                (const __attribute__((address_space(1))) void*)ga,
                (__attribute__((address_space(3))) void*)&sA[seg << 9], 16, 0, 0);
            const ushortw* gb = Wt + (size_t)(n0 + row) * Kp + kk + (cg << 3);
            __builtin_amdgcn_global_load_lds(
                (const __attribute__((address_space(1))) void*)gb,
                (__attribute__((address_space(3))) void*)&sB[seg << 9], 16, 0, 0);
        }
        __syncthreads();
        short8v a[4][2], b[4][2];
        #pragma unroll
        for (int i = 0; i < 4; i++) {
            int r = wm + (i << 4) + lrow;
            #pragma unroll
            for (int s = 0; s < 2; s++) {
                int slot = ((s << 2) + kgrp) ^ (r & 7);
                a[i][s] = *reinterpret_cast<const short8v*>(&sA[(r << 6) + (slot << 3)]);
            }
        }
        #pragma unroll
        for (int j = 0; j < 4; j++) {
            int r = wn + (j << 4) + lrow;
            #pragma unroll
            for (int s = 0; s < 2; s++) {
                int slot = ((s << 2) + kgrp) ^ (r & 7);
                b[j][s] = *reinterpret_cast<const short8v*>(&sB[(r << 6) + (slot << 3)]);
            }
        }
        #pragma unroll
        for (int i = 0; i < 4; i++)
            #pragma unroll
            for (int j = 0; j < 4; j++) {
                acc[i][j] = __builtin_amdgcn_mfma_f32_16x16x32_bf16(a[i][0], b[j][0], acc[i][j], 0, 0, 0);
                acc[i][j] = __builtin_amdgcn_mfma_f32_16x16x32_bf16(a[i][1], b[j][1], acc[i][j], 0, 0, 0);
            }
        __syncthreads();
    }
    #pragma unroll
    for (int i = 0; i < 4; i++) {
        int rowb = m0 + wm + (i << 4) + (kgrp << 2);
        #pragma unroll
        for (int j = 0; j < 4; j++) {
            int col = n0 + wn + (j << 4) + lrow;
            if (col < N) {
                float bi = bias[col];
                #pragma unroll
                for (int r = 0; r < 4; r++) {
                    int row = rowb + r;
                    float v = acc[i][j][r];
                    if (rowscale) v *= rowscale[row];
                    v += bi;
                    if (act == 1) v = gelu_exact(v);
                    else if (act == 2) v = fmaxf(v, 0.f);
                    if (resid) v += resid[(size_t)row * N + col];
                    if (outbf) ((ushortw*)Cout)[(size_t)row * ldc + col] = f2bf(v);
                    else       ((float*)Cout)[(size_t)row * ldc + col] = v;
                }
            } else if (zfill && col < ldc) {
                #pragma unroll
                for (int r = 0; r < 4; r++) {
                    int row = rowb + r;
                    if (outbf) ((ushortw*)Cout)[(size_t)row * ldc + col] = 0;
                    else       ((float*)Cout)[(size_t)row * ldc + col] = 0.f;
                }
            }
        }
    }
}

// ---------------- window attention, full batch: block = (img, win, head) ----------------
__global__ __launch_bounds__(256) void attn_kernel(
    const ushortw* __restrict__ qkvall, const float* __restrict__ biasT,
    ushortw* __restrict__ out)
{
    __shared__ float ks[NTOKW][32];
    __shared__ float vs[NTOKW][32];
    int blk = blockIdx.x;
    int img = blk / 384;
    int rem = blk - img * 384;
    int h = rem % NHEADS;
    int win = rem / NHEADS;          // 0..63 within image
    const ushortw* qkv = qkvall + (size_t)img * IMG * 540;
    int base = (win >> 3) * WSZ * WW + (win & 7) * WSZ;
    int tid = threadIdx.x;
    for (int idx = tid; idx < NTOKW * HD; idx += 256) {
        int j = idx / HD, d = idx - j * HD;
        int g = base + (j >> 4) * WW + (j & 15);
        ks[j][d] = bf2f(qkv[(size_t)g * 540 + 180 + h * HD + d]);
        vs[j][d] = bf2f(qkv[(size_t)g * 540 + 360 + h * HD + d]);
    }
    ks[tid][30] = 0.f; ks[tid][31] = 0.f; vs[tid][30] = 0.f; vs[tid][31] = 0.f;
    int i = tid;
    int gi = base + (i >> 4) * WW + (i & 15);
    float4 q[8];
    {
        const float scale = 0.18257418583505536f;  // 30^-0.5
        float qq[32];
        #pragma unroll
        for (int d = 0; d < HD; d++) qq[d] = bf2f(qkv[(size_t)gi * 540 + h * HD + d]) * scale;
        qq[30] = 0.f; qq[31] = 0.f;
        #pragma unroll
        for (int r = 0; r < 8; r++) q[r] = make_float4(qq[4*r], qq[4*r+1], qq[4*r+2], qq[4*r+3]);
    }
    __syncthreads();
    const float* bT = biasT + (size_t)h * NTOKW * NTOKW + i;
    float4 acc[8];
    #pragma unroll
    for (int r = 0; r < 8; r++) acc[r] = make_float4(0.f, 0.f, 0.f, 0.f);
    float l = 0.f;
    for (int j = 0; j < NTOKW; j++) {
        const float4* kr = reinterpret_cast<const float4*>(&ks[j][0]);
        float s = bT[(size_t)j * NTOKW];
        #pragma unroll
        for (int r = 0; r < 8; r++) {
            float4 kv = kr[r];
            s += q[r].x * kv.x + q[r].y * kv.y + q[r].z * kv.z + q[r].w * kv.w;
        }
        float p = __expf(s);
        l += p;
        const float4* vr = reinterpret_cast<const float4*>(&vs[j][0]);
        #pragma unroll
        for (int r = 0; r < 8; r++) {
            float4 vv = vr[r];
            acc[r].x += p * vv.x; acc[r].y += p * vv.y; acc[r].z += p * vv.z; acc[r].w += p * vv.w;
        }
    }
    float inv = 1.f / l;
    float accs[32];
    #pragma unroll
    for (int r = 0; r < 8; r++) {
        accs[4*r] = acc[r].x; accs[4*r+1] = acc[r].y; accs[4*r+2] = acc[r].z; accs[4*r+3] = acc[r].w;
    }
    ushortw* orow = out + ((size_t)img * IMG + gi) * 192 + h * HD;
    #pragma unroll
    for (int d = 0; d < HD; d++) orow[d] = f2bf(accs[d] * inv);
    if (h == 0) {   // zero pad cols 180..191
        for (int idx2 = tid; idx2 < NTOKW * 12; idx2 += 256) {
            int j = idx2 / 12, d = idx2 % 12;
            int gj = base + (j >> 4) * WW + (j & 15);
            out[((size_t)img * IMG + gj) * 192 + 180 + d] = 0;
        }
    }
}

// ---------------- templated depthwise 3x3 conv, NHWC ----------------
// grid: (npix/4, COP/64), block 256 = 4 pixels x 64 channels.
// wt is [9][COP] (padded with zeros), bias padded to COP.
template<int CIN_S, int COP, int OSTR, int DIL, int ACT, int OUTBF>
__global__ __launch_bounds__(256) void dwconv_kernel(
    const ushortw* __restrict__ in, const float* __restrict__ wt,
    const float* __restrict__ bias, void* __restrict__ out)
{
    int tid = threadIdx.x;
    int pix = (blockIdx.x << 2) + (tid >> 6);
    int c = (blockIdx.y << 6) + (tid & 63);
    int p = pix & (IMG - 1);
    int base = pix - p;
    int px = p & (WW - 1), py = p >> 7;
    float acc = bias[c];
    #pragma unroll
    for (int ky = 0; ky < 3; ky++) {
        int iy = py + (ky - 1) * DIL;
        if (iy < 0 || iy >= HH) continue;
        #pragma unroll
        for (int kx = 0; kx < 3; kx++) {
            int ix = px + (kx - 1) * DIL;
            if (ix < 0 || ix >= WW) continue;
            int nbr = base + (iy << 7) + ix;
            acc += bf2f(in[(size_t)nbr * CIN_S + c]) * wt[(ky * 3 + kx) * COP + c];
        }
    }
    if (ACT == 1) acc = gelu_exact(acc);
    else if (ACT == 2) acc = fmaxf(acc, 0.f);
    if (c < OSTR) {
        if (OUTBF) ((ushortw*)out)[(size_t)pix * OSTR + c] = f2bf(acc);
        else       ((float*)out)[(size_t)pix * OSTR + c] = acc;
    }
}

// ---------------- GAP partial sums over fp32 y4 ----------------
__global__ void gap_kernel(const float* __restrict__ y, float* __restrict__ part)
{
    int blk = blockIdx.x;
    int b = blk >> 5, chunk = blk & 31;
    int c = threadIdx.x;
    if (c >= CC) return;
    size_t basep = ((size_t)b * IMG + (size_t)chunk * 512) * CC;
    float s = 0.f;
    for (int p = 0; p < 512; p++) s += y[basep + (size_t)p * CC + c];
    part[((size_t)b * 32 + chunk) * CC + c] = s;
}

// ---------------- channel attention (tiny) ----------------
__global__ void ca_kernel(const float* __restrict__ part,
                          const float* __restrict__ w1, const float* __restrict__ b1,
                          const float* __restrict__ w2, const float* __restrict__ b2,
                          float* __restrict__ ca)
{
    __shared__ float gap[BB * CC];
    __shared__ float s1[BB * 6];
    int tid = threadIdx.x;
    for (int idx = tid; idx < BB * CC; idx += 256) {
        int b = idx / CC, c = idx % CC;
        float s = 0.f;
        for (int ch = 0; ch < 32; ch++) s += part[((size_t)b * 32 + ch) * CC + c];
        gap[idx] = s * (1.f / IMG);
    }
    __syncthreads();
    if (tid < BB * 6) {
        int b = tid / 6, cs = tid % 6;
        float s = 0.f;
        for (int c = 0; c < CC; c++) s += w1[cs * CC + c] * gap[b * CC + c];
        s1[tid] = fmaxf(s + b1[cs], 0.f);
    }
    __syncthreads();
    for (int idx = tid; idx < BB * CC; idx += 256) {
        int b = idx / CC, c = idx % CC;
        float s = b2[c];
        #pragma unroll
        for (int cs = 0; cs < 6; cs++) s += w2[c * 6 + cs] * s1[b * 6 + cs];
        ca[idx] = 1.f / (1.f + __expf(-s));
    }
}

// ---------------- x1 += 0.01*y4*ca (fp32, in place); LN2 -> bf16 xn2 (stride 192) ----------------
__global__ __launch_bounds__(256) void resid_ln_kernel(
    float* __restrict__ x1, const float* __restrict__ y4, const float* __restrict__ ca,
    const float* __restrict__ g, const float* __restrict__ bb,
    ushortw* __restrict__ xn2)
{
    int wid = threadIdx.x >> 6, lane = threadIdx.x & 63;
    int t = blockIdx.x * 4 + wid;
    int b = t >> 14;
    size_t off = (size_t)t * CC;
    size_t off2 = (size_t)t * 192;
    bool has2 = lane < (CC - 128);
    float v0 = x1[off+lane]    + 0.01f * y4[off+lane]    * ca[b*CC + lane];
    float v1 = x1[off+lane+64] + 0.01f * y4[off+lane+64] * ca[b*CC + lane+64];
    float v2 = 0.f;
    if (has2) v2 = x1[off+lane+128] + 0.01f * y4[off+lane+128] * ca[b*CC + lane+128];
    x1[off+lane] = v0; x1[off+lane+64] = v1;
    if (has2) x1[off+lane+128] = v2;
    float s = warp_sum(v0 + v1 + v2);
    float mu = s * (1.f / CC);
    float d0 = v0-mu, d1 = v1-mu, d2 = has2 ? v2-mu : 0.f;
    float var = warp_sum(d0*d0 + d1*d1 + d2*d2) * (1.f / CC);
    float rs = rsqrtf(var + 1e-5f);
    xn2[off2+lane]      = f2bf(d0 * rs * g[lane]      + bb[lane]);
    xn2[off2+lane+64]   = f2bf(d1 * rs * g[lane+64]   + bb[lane+64]);
    xn2[off2+lane+128]  = has2 ? f2bf(d2 * rs * g[lane+128] + bb[lane+128]) : (ushortw)0;
}

// ---------------- max/mean over channels per pixel (bf16 h3, stride 768, 720 cols) ----------------
__global__ __launch_bounds__(256) void mpap_kernel(
    const ushortw* __restrict__ h, float* __restrict__ mp, float* __restrict__ ap)
{
    int wid = threadIdx.x >> 6, lane = threadIdx.x & 63;
    int p = blockIdx.x * 4 + wid;
    const ushortw* row = h + (size_t)p * 768;
    float mx = -1e30f, s = 0.f;
    for (int j = lane; j < HID; j += 64) { float v = bf2f(row[j]); mx = fmaxf(mx, v); s += v; }
    mx = warp_max(mx); s = warp_sum(s);
    if (lane == 0) { mp[p] = mx; ap[p] = s * (1.f / HID); }
}

// ---------------- 7x7 spatial-attention conv + sigmoid (half batch = 2 images) ----------------
__global__ void saconv_kernel(const float* __restrict__ mp, const float* __restrict__ ap,
                              const float* __restrict__ w, float* __restrict__ sa)
{
    int p = blockIdx.x * blockDim.x + threadIdx.x;   // 0..HALFTOK-1
    int lp = p & (IMG - 1);
    int base = p - lp;
    int px = lp & (WW - 1), py = lp >> 7;
    float acc = 0.f;
    for (int ky = 0; ky < 7; ky++) {
        int iy = py + ky - 3;
        if (iy < 0 || iy >= HH) continue;
        for (int kx = 0; kx < 7; kx++) {
            int ix = px + kx - 3;
            if (ix < 0 || ix >= WW) continue;
            int pid = base + iy * WW + ix;
            acc += mp[pid] * w[ky * 7 + kx] + ap[pid] * w[49 + ky * 7 + kx];
        }
    }
    sa[p] = 1.f / (1.f + __expf(-acc));
}

extern "C" void kernel_launch(void* const* d_in, const int* in_sizes, int n_in,
                              void* d_out, int out_size, void* d_ws, size_t ws_size,
                              hipStream_t stream)
{
    const float* x      = (const float*)d_in[0];
    const int*   rpi    = (const int*)d_in[3];
    const float* n1g    = (const float*)d_in[4];
    const float* n1b    = (const float*)d_in[5];
    const float* rpb    = (const float*)d_in[6];
    const float* qkv_w  = (const float*)d_in[7];
    const float* qkv_b  = (const float*)d_in[8];
    const float* proj_w = (const float*)d_in[9];
    const float* proj_b = (const float*)d_in[10];
    const float* cab_w0 = (const float*)d_in[11];
    const float* cab_b0 = (const float*)d_in[12];
    const float* cab_w1 = (const float*)d_in[13];
    const float* cab_b1 = (const float*)d_in[14];
    const float* cab_w2 = (const float*)d_in[15];
    const float* cab_b2 = (const float*)d_in[16];
    const float* cab_w3 = (const float*)d_in[17];
    const float* cab_b3 = (const float*)d_in[18];
    const float* ca_w1  = (const float*)d_in[19];
    const float* ca_b1  = (const float*)d_in[20];
    const float* ca_w2  = (const float*)d_in[21];
    const float* ca_b2  = (const float*)d_in[22];
    const float* n2g    = (const float*)d_in[23];
    const float* n2b    = (const float*)d_in[24];
    const float* fc1_w  = (const float*)d_in[25];
    const float* fc1_b  = (const float*)d_in[26];
    const float* dw_w   = (const float*)d_in[27];
    const float* dw_b   = (const float*)d_in[28];
    const float* pw_w   = (const float*)d_in[29];
    const float* pw_b   = (const float*)d_in[30];
    const float* sa_w   = (const float*)d_in[31];
    const float* fc2_w  = (const float*)d_in[32];
    const float* fc2_b  = (const float*)d_in[33];
    float* outp = (float*)d_out;
    (void)in_sizes; (void)n_in; (void)out_size; (void)ws_size;

    char* ws = (char*)d_ws;
    const size_t S0 = (size_t)NTOK * 192 * 2;   // xnb -> xn2b
    const size_t S1 = (size_t)NTOK * 540 * 2;   // qkvF -> y1b -> h1(half) -> h3(half)
    const size_t S2 = (size_t)NTOK * 192 * 2;   // attnbb -> y3b
    const size_t S3 = (size_t)NTOK * 180 * 4;   // x1 fp32 persistent
    const size_t S4 = (size_t)NTOK * 128 * 2;   // y2b ; h2(half) spans S4+S5
    const size_t S5 = (size_t)NTOK * 180 * 4;   // y4 fp32
    char* pA0 = ws;
    char* pA1 = pA0 + S0;
    char* pA2 = pA1 + S1;
    char* pA3 = pA2 + S2;
    char* pA4 = pA3 + S3;
    char* pA5 = pA4 + S4;
    char* tail = pA5 + S5;

    ushortw* xnb    = (ushortw*)pA0;           // [NTOK][192]
    ushortw* xn2b   = (ushortw*)pA0;
    ushortw* qkvF   = (ushortw*)pA1;           // [NTOK][540]
    ushortw* y1b    = (ushortw*)pA1;           // [NTOK][96]
    ushortw* h1     = (ushortw*)pA1;           // [HALFTOK][720]
    ushortw* h3     = (ushortw*)pA1;           // [HALFTOK][768]
    ushortw* attnbb = (ushortw*)pA2;           // [NTOK][192]
    ushortw* y3b    = (ushortw*)pA2;           // [NTOK][192]
    float*   x1     = (float*)pA3;             // [NTOK][180]
    ushortw* y2b    = (ushortw*)pA4;           // [NTOK][128]
    ushortw* h2     = (ushortw*)pA4;           // [HALFTOK][768] spans S4+S5
    float*   y4     = (float*)pA5;             // [NTOK][180]

    // bf16 gemm weights (padded)
    ushortw* wqkv  = (ushortw*)tail;                        // 640 x 192
    ushortw* wproj = wqkv  + 640 * 192;                     // 256 x 192
    ushortw* wcab0 = wproj + 256 * 192;                     // 128 x 192
    ushortw* wcab2 = wcab0 + 128 * 192;                     // 256 x 128
    ushortw* wfc1  = wcab2 + 256 * 128;                     // 768 x 192
    ushortw* wpw   = wfc1  + 768 * 192;                     // 768 x 768
    ushortw* wfc2  = wpw   + 768 * 768;                     // 256 x 768
    char* tail2 = (char*)(wfc2 + 256 * 768);
    float* dwt1 = (float*)tail2;                 float* db1 = dwt1 + 9*128;   // [9][128]+[128]
    float* dwt2 = db1 + 128;                     float* db2 = dwt2 + 9*192;   // [9][192]+[192]
    float* dwt3 = db2 + 192;                     float* db3 = dwt3 + 9*768;   // [9][768]+[768]
    char* tail3 = (char*)(db3 + 768);
    float* biasT = (float*)tail3;                           // 6*256*256
    float* part  = (float*)(tail3 + 1572864);
    float* cabuf = (float*)(tail3 + 1572864 + 98304);
    float* mp    = (float*)(tail3 + 1572864 + 131072);                          // [HALFTOK]
    float* ap    = (float*)(tail3 + 1572864 + 131072 + (size_t)HALFTOK * 4);    // [HALFTOK]
    float* sab   = (float*)(tail3 + 1572864 + 131072 + 2*(size_t)HALFTOK * 4);  // [HALFTOK]

    auto wc = [&](const float* src, ushortw* dst, int N, int K, int Np, int Kp) {
        wconv_kernel<<<dim3((Np * Kp + 255) / 256), dim3(256), 0, stream>>>(src, dst, N, K, Np, Kp);
    };
    auto gemm = [&](const ushortw* A, const ushortw* Wt, const float* bi, void* Cp,
                    int M, int N, int Kp, int ldc, int outbf, int zfill, int act,
                    const float* rs, const float* resid) {
        dim3 g((N + 127) / 128, M / 128);
        mgemm_kernel<<<g, dim3(256), 0, stream>>>(A, Wt, bi, Cp, M, N, Kp, ldc, outbf, zfill, act, rs, resid);
    };

    // 0) weight prep
    wc(qkv_w, wqkv, 540, 180, 640, 192);
    wc(proj_w, wproj, 180, 180, 256, 192);
    wc(cab_w0, wcab0, 90, 180, 128, 192);
    wc(cab_w2, wcab2, 180, 90, 256, 128);
    wc(fc1_w, wfc1, 720, 180, 768, 192);
    wc(pw_w, wpw, 720, 720, 768, 768);
    wc(fc2_w, wfc2, 180, 720, 256, 768);
    dwt_kernel<<<dim3((128*9 + 255)/256), dim3(256), 0, stream>>>(cab_w1, cab_b1, dwt1, db1, 90, 128);
    dwt_kernel<<<dim3((192*9 + 255)/256), dim3(256), 0, stream>>>(cab_w3, cab_b3, dwt2, db2, 180, 192);
    dwt_kernel<<<dim3((768*9 + 255)/256), dim3(256), 0, stream>>>(dw_w, dw_b, dwt3, db3, 720, 768);

    // 1) LN1 -> bf16 xnb ; bias table
    ln_kernel<<<dim3(NTOK / 4), dim3(256), 0, stream>>>(x, n1g, n1b, xnb);
    bias_kernel<<<dim3((NTOKW * NTOKW) / 256), dim3(256), 0, stream>>>(rpi, rpb, biasT);
    // 2) full-batch qkv + attention
    gemm(xnb, wqkv, qkv_b, qkvF, NTOK, 540, 192, 540, 1, 0, 0, nullptr, nullptr);
    attn_kernel<<<dim3(BB * 64 * NHEADS), dim3(256), 0, stream>>>(qkvF, biasT, attnbb);
    // 3) CAB part 1 (xnb consumed; qkvF dead -> y1b reuses S1)
    gemm(xnb, wcab0, cab_b0, y1b, NTOK, 90, 192, 96, 1, 1, 0, nullptr, nullptr);
    dwconv_kernel<96, 128, 128, 1, 1, 1><<<dim3(NTOK / 4, 2), dim3(256), 0, stream>>>(
        y1b, dwt1, db1, y2b);
    // 4) proj with residual x -> x1 (attnbb dead after)
    gemm(attnbb, wproj, proj_b, x1, NTOK, 180, 192, 180, 0, 0, 0, nullptr, x);
    // 5) CAB part 2
    gemm(y2b, wcab2, cab_b2, y3b, NTOK, 180, 128, 192, 1, 1, 0, nullptr, nullptr);
    dwconv_kernel<192, 192, 180, 2, 0, 0><<<dim3(NTOK / 4, 3), dim3(256), 0, stream>>>(
        y3b, dwt2, db2, y4);
    gap_kernel<<<dim3(BB * 32), dim3(192), 0, stream>>>(y4, part);
    ca_kernel<<<dim3(1), dim3(256), 0, stream>>>(part, ca_w1, ca_b1, ca_w2, ca_b2, cabuf);
    // 6) x1 += 0.01*y4*ca; LN2 -> bf16 xn2b
    resid_ln_kernel<<<dim3(NTOK / 4), dim3(256), 0, stream>>>(x1, y4, cabuf, n2g, n2b, xn2b);
    // 7) FFN in two half-batches (2 images each)
    for (int half = 0; half < 2; half++) {
        size_t toff = (size_t)half * HALFTOK;
        gemm(xn2b + toff * 192, wfc1, fc1_b, h1, HALFTOK, 720, 192, 720, 1, 0, 1, nullptr, nullptr);
        dwconv_kernel<720, 768, 768, 1, 2, 1><<<dim3(HALFTOK / 4, 12), dim3(256), 0, stream>>>(
            h1, dwt3, db3, h2);
        gemm(h2, wpw, pw_b, h3, HALFTOK, 720, 768, 768, 1, 1, 2, nullptr, nullptr);
        mpap_kernel<<<dim3(HALFTOK / 4), dim3(256), 0, stream>>>(h3, mp, ap);
        saconv_kernel<<<dim3(HALFTOK / 256), dim3(256), 0, stream>>>(mp, ap, sa_w, sab);
        gemm(h3, wfc2, fc2_b, outp + toff * 180, HALFTOK, 180, 768, 180, 0, 0, 0,
             sab, x1 + toff * 180);
    }
}

// Round 6
// 1347.262 us; speedup vs baseline: 2.5851x; 1.0699x over previous
//
#include <hip/hip_runtime.h>
#include <math.h>

#define HH 128
#define WW 128
#define CC 180
#define BB 4
#define IMG (HH*WW)          // 16384 tokens per image
#define NTOK (BB*IMG)        // 65536
#define HALFTOK (2*IMG)      // 32768
#define NHEADS 6
#define HD 30
#define WSZ 16
#define NTOKW (WSZ*WSZ)      // 256
#define HID 720
#define QKVSTR 576           // padded qkv row: 3 sections x 6 heads x 32

typedef __attribute__((ext_vector_type(8))) short short8v;
typedef __attribute__((ext_vector_type(4))) float f32x4;
typedef unsigned short ushortw;

__device__ __forceinline__ float warp_sum(float v) {
    #pragma unroll
    for (int o = 32; o > 0; o >>= 1) v += __shfl_xor(v, o);
    return v;
}
__device__ __forceinline__ float warp_max(float v) {
    #pragma unroll
    for (int o = 32; o > 0; o >>= 1) v = fmaxf(v, __shfl_xor(v, o));
    return v;
}
__device__ __forceinline__ float gelu_exact(float v) {
    return 0.5f * v * (1.f + erff(v * 0.70710678118654752f));
}
__device__ __forceinline__ ushortw f2bf(float f) {
    union { float f; unsigned int u; } c; c.f = f;
    unsigned int r = (c.u + 0x7FFFu + ((c.u >> 16) & 1u)) >> 16;
    return (ushortw)r;
}
__device__ __forceinline__ float bf2f(ushortw u) {
    union { unsigned int u; float f; } c; c.u = ((unsigned int)u) << 16; return c.f;
}

// ---------------- weight fp32 -> bf16 with N/K padding (zeros) ----------------
__global__ void wconv_kernel(const float* __restrict__ src, ushortw* __restrict__ dst,
                             int N, int K, int Npad, int Kpad)
{
    int idx = blockIdx.x * blockDim.x + threadIdx.x;
    if (idx >= Npad * Kpad) return;
    int r = idx / Kpad, k = idx % Kpad;
    float v = (r < N && k < K) ? src[r * K + k] : 0.f;
    dst[idx] = f2bf(v);
}

// ---------------- dw weight transpose [C][9] -> [9][COP] (+ padded bias) ----------------
__global__ void dwt_kernel(const float* __restrict__ src, const float* __restrict__ bsrc,
                           float* __restrict__ dst, float* __restrict__ bdst,
                           int C, int COP)
{
    int idx = blockIdx.x * blockDim.x + threadIdx.x;
    if (idx >= COP * 9) return;
    int c = idx / 9, k = idx - c * 9;
    dst[k * COP + c] = (c < C) ? src[c * 9 + k] : 0.f;
    if (k == 0) bdst[c] = (c < C) ? bsrc[c] : 0.f;
}

// ---------------- LayerNorm -> bf16 out, stride 192 (cols 180..191 zero) ----------------
__global__ __launch_bounds__(256) void ln_kernel(
    const float* __restrict__ x, const float* __restrict__ g,
    const float* __restrict__ b, ushortw* __restrict__ out)
{
    int wid = threadIdx.x >> 6, lane = threadIdx.x & 63;
    int t = blockIdx.x * 4 + wid;
    size_t off = (size_t)t * CC;
    size_t off2 = (size_t)t * 192;
    bool has2 = lane < (CC - 128);
    float v0 = x[off + lane];
    float v1 = x[off + lane + 64];
    float v2 = has2 ? x[off + lane + 128] : 0.f;
    float s = warp_sum(v0 + v1 + v2);
    float mu = s * (1.f / CC);
    float d0 = v0 - mu, d1 = v1 - mu, d2 = has2 ? v2 - mu : 0.f;
    float var = warp_sum(d0*d0 + d1*d1 + d2*d2) * (1.f / CC);
    float rs = rsqrtf(var + 1e-5f);
    out[off2 + lane]      = f2bf(d0 * rs * g[lane]      + b[lane]);
    out[off2 + lane + 64] = f2bf(d1 * rs * g[lane + 64] + b[lane + 64]);
    out[off2 + lane + 128] = has2 ? f2bf(d2 * rs * g[lane + 128] + b[lane + 128]) : (ushortw)0;
}

// ---------------- relative position bias, natural [h][i*256+j] ----------------
__global__ void bias_kernel(const int* __restrict__ rpi, const float* __restrict__ rpb,
                            float* __restrict__ biasN)
{
    int idx = blockIdx.x * blockDim.x + threadIdx.x;
    if (idx >= NTOKW * NTOKW) return;
    int r = rpi[idx];
    #pragma unroll
    for (int h = 0; h < NHEADS; h++)
        biasN[((size_t)h << 16) + idx] = rpb[r * NHEADS + h];
}

// ---------------- bf16 MFMA GEMM, m97 structure ----------------
// qkvmode: epilogue remaps col n (0..539) -> section(q/k/v)*192 + head*32 + d, bf16.
__global__ __launch_bounds__(256) void mgemm_kernel(
    const ushortw* __restrict__ A, const ushortw* __restrict__ Wt,
    const float* __restrict__ bias, void* __restrict__ Cout,
    int M, int N, int Kp, int ldc, int outbf, int zfill, int act, int qkvmode,
    const float* __restrict__ rowscale, const float* __restrict__ resid)
{
    __shared__ ushortw sA[128 * 64];
    __shared__ ushortw sB[128 * 64];
    int tid = threadIdx.x, lane = tid & 63, wid = tid >> 6;
    int m0 = blockIdx.y << 7, n0 = blockIdx.x << 7;
    int wm = (wid >> 1) << 6, wn = (wid & 1) << 6;
    int lrow = lane & 15, kgrp = lane >> 4;

    f32x4 acc[4][4];
    #pragma unroll
    for (int i = 0; i < 4; i++)
        #pragma unroll
        for (int j = 0; j < 4; j++)
            #pragma unroll
            for (int r = 0; r < 4; r++) acc[i][j][r] = 0.f;

    int nk = Kp >> 6;
    for (int t = 0; t < nk; t++) {
        int kk = t << 6;
        #pragma unroll
        for (int q = 0; q < 4; q++) {
            int seg = (wid << 2) + q;                 // 0..15
            int row = (seg << 3) + (lane >> 3);       // 0..127
            int cg = (lane & 7) ^ (row & 7);          // swizzled global chunk
            const ushortw* ga = A + (size_t)(m0 + row) * Kp + kk + (cg << 3);
            __builtin_amdgcn_global_load_lds(
                (const __attribute__((address_space(1))) void*)ga,
                (__attribute__((address_space(3))) void*)&sA[seg << 9], 16, 0, 0);
            const ushortw* gb = Wt + (size_t)(n0 + row) * Kp + kk + (cg << 3);
            __builtin_amdgcn_global_load_lds(
                (const __attribute__((address_space(1))) void*)gb,
                (__attribute__((address_space(3))) void*)&sB[seg << 9], 16, 0, 0);
        }
        __syncthreads();
        short8v a[4][2], b[4][2];
        #pragma unroll
        for (int i = 0; i < 4; i++) {
            int r = wm + (i << 4) + lrow;
            #pragma unroll
            for (int s = 0; s < 2; s++) {
                int slot = ((s << 2) + kgrp) ^ (r & 7);
                a[i][s] = *reinterpret_cast<const short8v*>(&sA[(r << 6) + (slot << 3)]);
            }
        }
        #pragma unroll
        for (int j = 0; j < 4; j++) {
            int r = wn + (j << 4) + lrow;
            #pragma unroll
            for (int s = 0; s < 2; s++) {
                int slot = ((s << 2) + kgrp) ^ (r & 7);
                b[j][s] = *reinterpret_cast<const short8v*>(&sB[(r << 6) + (slot << 3)]);
            }
        }
        #pragma unroll
        for (int i = 0; i < 4; i++)
            #pragma unroll
            for (int j = 0; j < 4; j++) {
                acc[i][j] = __builtin_amdgcn_mfma_f32_16x16x32_bf16(a[i][0], b[j][0], acc[i][j], 0, 0, 0);
                acc[i][j] = __builtin_amdgcn_mfma_f32_16x16x32_bf16(a[i][1], b[j][1], acc[i][j], 0, 0, 0);
            }
        __syncthreads();
    }
    #pragma unroll
    for (int i = 0; i < 4; i++) {
        int rowb = m0 + wm + (i << 4) + (kgrp << 2);
        #pragma unroll
        for (int j = 0; j < 4; j++) {
            int col = n0 + wn + (j << 4) + lrow;
            if (qkvmode) {
                if (col < N) {
                    int sub = (col >= 360) ? 2 : (col >= 180 ? 1 : 0);
                    int rem = col - sub * 180;
                    int hh = rem / 30;
                    int dd = rem - hh * 30;
                    int col2 = sub * 192 + hh * 32 + dd;
                    float bi = bias[col];
                    #pragma unroll
                    for (int r = 0; r < 4; r++) {
                        int row = rowb + r;
                        ((ushortw*)Cout)[(size_t)row * QKVSTR + col2] = f2bf(acc[i][j][r] + bi);
                    }
                }
                continue;
            }
            if (col < N) {
                float bi = bias[col];
                #pragma unroll
                for (int r = 0; r < 4; r++) {
                    int row = rowb + r;
                    float v = acc[i][j][r];
                    if (rowscale) v *= rowscale[row];
                    v += bi;
                    if (act == 1) v = gelu_exact(v);
                    else if (act == 2) v = fmaxf(v, 0.f);
                    if (resid) v += resid[(size_t)row * N + col];
                    if (outbf) ((ushortw*)Cout)[(size_t)row * ldc + col] = f2bf(v);
                    else       ((float*)Cout)[(size_t)row * ldc + col] = v;
                }
            } else if (zfill && col < ldc) {
                #pragma unroll
                for (int r = 0; r < 4; r++) {
                    int row = rowb + r;
                    if (outbf) ((ushortw*)Cout)[(size_t)row * ldc + col] = 0;
                    else       ((float*)Cout)[(size_t)row * ldc + col] = 0.f;
                }
            }
        }
    }
}

// ---------------- MFMA window attention: block = (img, win, head), 4 waves ----------------
// qkvP: [NTOK][576] bf16 padded (q at h*32, k at 192+h*32, v at 384+h*32; d=30,31 garbage)
// biasN: [6][256][256] fp32. out: [NTOK][192] bf16 (cols 180..191 zeroed by h==0 blocks).
__global__ __launch_bounds__(256) void attn_mfma_kernel(
    const ushortw* __restrict__ qkvP, const float* __restrict__ biasN,
    ushortw* __restrict__ out)
{
    __shared__ ushortw Vc[32 * 33 * 8];      // [kc][33 d-slots][8] : 16896 B
    __shared__ ushortw Pl[4][4096];          // per-wave 16x256 bf16, XOR-swizzled: 32768 B
    const float SCALE = 0.18257418583505536f;   // 30^-0.5
    int blk = blockIdx.x;
    int img = blk / 384;
    int rem = blk - img * 384;
    int win = rem / NHEADS;
    int h = rem - win * NHEADS;
    int base = img * IMG + (win >> 3) * WSZ * WW + (win & 7) * WSZ;
    int tid = threadIdx.x;
    int lane = tid & 63, w = tid >> 6;
    int a15 = lane & 15, kg = lane >> 4;

    // ---- stage V transposed-chunked: Vc[kc= j>>3][d][e= j&7] ----
    {
        int j = tid;
        int g = base + (j >> 4) * WW + (j & 15);
        const ushortw* vp = qkvP + (size_t)g * QKVSTR + 384 + h * 32;
        short8v c0 = *reinterpret_cast<const short8v*>(vp);
        short8v c1 = *reinterpret_cast<const short8v*>(vp + 8);
        short8v c2 = *reinterpret_cast<const short8v*>(vp + 16);
        short8v c3 = *reinterpret_cast<const short8v*>(vp + 24);
        int bo = (j >> 3) * 264 + (j & 7);
        #pragma unroll
        for (int e = 0; e < 8; e++)  Vc[bo + (e) * 8]      = (ushortw)c0[e];
        #pragma unroll
        for (int e = 0; e < 8; e++)  Vc[bo + (8 + e) * 8]  = (ushortw)c1[e];
        #pragma unroll
        for (int e = 0; e < 8; e++)  Vc[bo + (16 + e) * 8] = (ushortw)c2[e];
        #pragma unroll
        for (int e = 0; e < 6; e++)  Vc[bo + (24 + e) * 8] = (ushortw)c3[e];
    }
    // ---- K fragments for all 16 col tiles (regs) ----
    short8v kf[16];
    #pragma unroll
    for (int jt = 0; jt < 16; jt++) {
        int g = base + jt * WW + a15;
        kf[jt] = *reinterpret_cast<const short8v*>(qkvP + (size_t)g * QKVSTR + 192 + h * 32 + (kg << 3));
        if (kg == 3) { kf[jt][6] = 0; kf[jt][7] = 0; }
    }
    __syncthreads();

    ushortw* Pw = &Pl[w][0];
    f32x4 zf = {0.f, 0.f, 0.f, 0.f};
    #pragma unroll 1
    for (int si = 0; si < 4; si++) {
        int strip = (w << 2) + si;
        short8v qf = *reinterpret_cast<const short8v*>(
            qkvP + (size_t)(base + strip * WW + a15) * QKVSTR + h * 32 + (kg << 3));
        if (kg == 3) { qf[6] = 0; qf[7] = 0; }
        f32x4 s[16];
        #pragma unroll
        for (int jt = 0; jt < 16; jt++)
            s[jt] = __builtin_amdgcn_mfma_f32_16x16x32_bf16(qf, kf[jt], zf, 0, 0, 0);
        // softmax rows: i = strip*16 + kg*4 + r ; cols: j = jt*16 + a15
        const float* bp = biasN + ((size_t)h << 16) + (size_t)((strip << 4) + (kg << 2)) * 256 + a15;
        float psum[4] = {0.f, 0.f, 0.f, 0.f};
        #pragma unroll
        for (int jt = 0; jt < 16; jt++) {
            #pragma unroll
            for (int r = 0; r < 4; r++) {
                int irow = (kg << 2) + r;
                float p = __expf(fmaf(s[jt][r], SCALE, bp[r * 256 + jt * 16]));
                psum[r] += p;
                int sidx = (irow * 256 + jt * 16 + a15) ^ ((irow & 7) << 3);
                Pw[sidx] = f2bf(p);
            }
        }
        #pragma unroll
        for (int o = 1; o < 16; o <<= 1) {
            #pragma unroll
            for (int r = 0; r < 4; r++) psum[r] += __shfl_xor(psum[r], o);
        }
        // PV: A from Pw (row=a15), B from Vc
        f32x4 o0 = zf, o1 = zf;
        #pragma unroll
        for (int ks = 0; ks < 8; ks++) {
            int pidx = (a15 * 256 + ks * 32 + (kg << 3)) ^ ((a15 & 7) << 3);
            short8v pa = *reinterpret_cast<const short8v*>(&Pw[pidx]);
            int kc = ks * 4 + kg;
            short8v v0 = *reinterpret_cast<const short8v*>(&Vc[(kc * 33 + a15) * 8]);
            short8v v1 = *reinterpret_cast<const short8v*>(&Vc[(kc * 33 + 16 + a15) * 8]);
            o0 = __builtin_amdgcn_mfma_f32_16x16x32_bf16(pa, v0, o0, 0, 0, 0);
            o1 = __builtin_amdgcn_mfma_f32_16x16x32_bf16(pa, v1, o1, 0, 0, 0);
        }
        #pragma unroll
        for (int r = 0; r < 4; r++) {
            float inv = 1.f / psum[r];
            int g = base + strip * WW + (kg << 2) + r;
            ushortw* orow = out + (size_t)g * 192 + h * HD;
            orow[a15] = f2bf(o0[r] * inv);
            if (a15 < 14) orow[16 + a15] = f2bf(o1[r] * inv);
        }
    }
    if (h == 0) {   // zero pad cols 180..191
        for (int idx2 = tid; idx2 < NTOKW * 12; idx2 += 256) {
            int j = idx2 / 12, d = idx2 - (idx2 / 12) * 12;
            int gj = base + (j >> 4) * WW + (j & 15);
            out[(size_t)gj * 192 + 180 + d] = 0;
        }
    }
}

// ---------------- templated depthwise 3x3 conv, NHWC ----------------
template<int CIN_S, int COP, int OSTR, int DIL, int ACT, int OUTBF>
__global__ __launch_bounds__(256) void dwconv_kernel(
    const ushortw* __restrict__ in, const float* __restrict__ wt,
    const float* __restrict__ bias, void* __restrict__ out)
{
    int tid = threadIdx.x;
    int pix = (blockIdx.x << 2) + (tid >> 6);
    int c = (blockIdx.y << 6) + (tid & 63);
    int p = pix & (IMG - 1);
    int base = pix - p;
    int px = p & (WW - 1), py = p >> 7;
    float acc = bias[c];
    #pragma unroll
    for (int ky = 0; ky < 3; ky++) {
        int iy = py + (ky - 1) * DIL;
        if (iy < 0 || iy >= HH) continue;
        #pragma unroll
        for (int kx = 0; kx < 3; kx++) {
            int ix = px + (kx - 1) * DIL;
            if (ix < 0 || ix >= WW) continue;
            int nbr = base + (iy << 7) + ix;
            acc += bf2f(in[(size_t)nbr * CIN_S + c]) * wt[(ky * 3 + kx) * COP + c];
        }
    }
    if (ACT == 1) acc = gelu_exact(acc);
    else if (ACT == 2) acc = fmaxf(acc, 0.f);
    if (c < OSTR) {
        if (OUTBF) ((ushortw*)out)[(size_t)pix * OSTR + c] = f2bf(acc);
        else       ((float*)out)[(size_t)pix * OSTR + c] = acc;
    }
}

// ---------------- GAP partial sums over fp32 y4 ----------------
__global__ void gap_kernel(const float* __restrict__ y, float* __restrict__ part)
{
    int blk = blockIdx.x;
    int b = blk >> 5, chunk = blk & 31;
    int c = threadIdx.x;
    if (c >= CC) return;
    size_t basep = ((size_t)b * IMG + (size_t)chunk * 512) * CC;
    float s = 0.f;
    for (int p = 0; p < 512; p++) s += y[basep + (size_t)p * CC + c];
    part[((size_t)b * 32 + chunk) * CC + c] = s;
}

// ---------------- channel attention (tiny) ----------------
__global__ void ca_kernel(const float* __restrict__ part,
                          const float* __restrict__ w1, const float* __restrict__ b1,
                          const float* __restrict__ w2, const float* __restrict__ b2,
                          float* __restrict__ ca)
{
    __shared__ float gap[BB * CC];
    __shared__ float s1[BB * 6];
    int tid = threadIdx.x;
    for (int idx = tid; idx < BB * CC; idx += 256) {
        int b = idx / CC, c = idx % CC;
        float s = 0.f;
        for (int ch = 0; ch < 32; ch++) s += part[((size_t)b * 32 + ch) * CC + c];
        gap[idx] = s * (1.f / IMG);
    }
    __syncthreads();
    if (tid < BB * 6) {
        int b = tid / 6, cs = tid % 6;
        float s = 0.f;
        for (int c = 0; c < CC; c++) s += w1[cs * CC + c] * gap[b * CC + c];
        s1[tid] = fmaxf(s + b1[cs], 0.f);
    }
    __syncthreads();
    for (int idx = tid; idx < BB * CC; idx += 256) {
        int b = idx / CC, c = idx % CC;
        float s = b2[c];
        #pragma unroll
        for (int cs = 0; cs < 6; cs++) s += w2[c * 6 + cs] * s1[b * 6 + cs];
        ca[idx] = 1.f / (1.f + __expf(-s));
    }
}

// ---------------- x1 += 0.01*y4*ca (fp32, in place); LN2 -> bf16 xn2 (stride 192) ----------------
__global__ __launch_bounds__(256) void resid_ln_kernel(
    float* __restrict__ x1, const float* __restrict__ y4, const float* __restrict__ ca,
    const float* __restrict__ g, const float* __restrict__ bb,
    ushortw* __restrict__ xn2)
{
    int wid = threadIdx.x >> 6, lane = threadIdx.x & 63;
    int t = blockIdx.x * 4 + wid;
    int b = t >> 14;
    size_t off = (size_t)t * CC;
    size_t off2 = (size_t)t * 192;
    bool has2 = lane < (CC - 128);
    float v0 = x1[off+lane]    + 0.01f * y4[off+lane]    * ca[b*CC + lane];
    float v1 = x1[off+lane+64] + 0.01f * y4[off+lane+64] * ca[b*CC + lane+64];
    float v2 = 0.f;
    if (has2) v2 = x1[off+lane+128] + 0.01f * y4[off+lane+128] * ca[b*CC + lane+128];
    x1[off+lane] = v0; x1[off+lane+64] = v1;
    if (has2) x1[off+lane+128] = v2;
    float s = warp_sum(v0 + v1 + v2);
    float mu = s * (1.f / CC);
    float d0 = v0-mu, d1 = v1-mu, d2 = has2 ? v2-mu : 0.f;
    float var = warp_sum(d0*d0 + d1*d1 + d2*d2) * (1.f / CC);
    float rs = rsqrtf(var + 1e-5f);
    xn2[off2+lane]      = f2bf(d0 * rs * g[lane]      + bb[lane]);
    xn2[off2+lane+64]   = f2bf(d1 * rs * g[lane+64]   + bb[lane+64]);
    xn2[off2+lane+128]  = has2 ? f2bf(d2 * rs * g[lane+128] + bb[lane+128]) : (ushortw)0;
}

// ---------------- max/mean over channels per pixel (bf16 h3, stride 768, 720 cols) ----------------
__global__ __launch_bounds__(256) void mpap_kernel(
    const ushortw* __restrict__ h, float* __restrict__ mp, float* __restrict__ ap)
{
    int wid = threadIdx.x >> 6, lane = threadIdx.x & 63;
    int p = blockIdx.x * 4 + wid;
    const ushortw* row = h + (size_t)p * 768;
    float mx = -1e30f, s = 0.f;
    for (int j = lane; j < HID; j += 64) { float v = bf2f(row[j]); mx = fmaxf(mx, v); s += v; }
    mx = warp_max(mx); s = warp_sum(s);
    if (lane == 0) { mp[p] = mx; ap[p] = s * (1.f / HID); }
}

// ---------------- 7x7 spatial-attention conv + sigmoid (half batch = 2 images) ----------------
__global__ void saconv_kernel(const float* __restrict__ mp, const float* __restrict__ ap,
                              const float* __restrict__ w, float* __restrict__ sa)
{
    int p = blockIdx.x * blockDim.x + threadIdx.x;   // 0..HALFTOK-1
    int lp = p & (IMG - 1);
    int base = p - lp;
    int px = lp & (WW - 1), py = lp >> 7;
    float acc = 0.f;
    for (int ky = 0; ky < 7; ky++) {
        int iy = py + ky - 3;
        if (iy < 0 || iy >= HH) continue;
        for (int kx = 0; kx < 7; kx++) {
            int ix = px + kx - 3;
            if (ix < 0 || ix >= WW) continue;
            int pid = base + iy * WW + ix;
            acc += mp[pid] * w[ky * 7 + kx] + ap[pid] * w[49 + ky * 7 + kx];
        }
    }
    sa[p] = 1.f / (1.f + __expf(-acc));
}

extern "C" void kernel_launch(void* const* d_in, const int* in_sizes, int n_in,
                              void* d_out, int out_size, void* d_ws, size_t ws_size,
                              hipStream_t stream)
{
    const float* x      = (const float*)d_in[0];
    const int*   rpi    = (const int*)d_in[3];
    const float* n1g    = (const float*)d_in[4];
    const float* n1b    = (const float*)d_in[5];
    const float* rpb    = (const float*)d_in[6];
    const float* qkv_w  = (const float*)d_in[7];
    const float* qkv_b  = (const float*)d_in[8];
    const float* proj_w = (const float*)d_in[9];
    const float* proj_b = (const float*)d_in[10];
    const float* cab_w0 = (const float*)d_in[11];
    const float* cab_b0 = (const float*)d_in[12];
    const float* cab_w1 = (const float*)d_in[13];
    const float* cab_b1 = (const float*)d_in[14];
    const float* cab_w2 = (const float*)d_in[15];
    const float* cab_b2 = (const float*)d_in[16];
    const float* cab_w3 = (const float*)d_in[17];
    const float* cab_b3 = (const float*)d_in[18];
    const float* ca_w1  = (const float*)d_in[19];
    const float* ca_b1  = (const float*)d_in[20];
    const float* ca_w2  = (const float*)d_in[21];
    const float* ca_b2  = (const float*)d_in[22];
    const float* n2g    = (const float*)d_in[23];
    const float* n2b    = (const float*)d_in[24];
    const float* fc1_w  = (const float*)d_in[25];
    const float* fc1_b  = (const float*)d_in[26];
    const float* dw_w   = (const float*)d_in[27];
    const float* dw_b   = (const float*)d_in[28];
    const float* pw_w   = (const float*)d_in[29];
    const float* pw_b   = (const float*)d_in[30];
    const float* sa_w   = (const float*)d_in[31];
    const float* fc2_w  = (const float*)d_in[32];
    const float* fc2_b  = (const float*)d_in[33];
    float* outp = (float*)d_out;
    (void)in_sizes; (void)n_in; (void)out_size; (void)ws_size;

    char* ws = (char*)d_ws;
    const size_t S0 = (size_t)NTOK * 192 * 2;      // xnb -> xn2b
    const size_t S1 = (size_t)NTOK * QKVSTR * 2;   // qkvP -> y1b -> h1(half) -> h3(half)
    const size_t S2 = (size_t)NTOK * 192 * 2;      // attnbb -> y3b
    const size_t S3 = (size_t)NTOK * 180 * 4;      // x1 fp32 persistent
    const size_t S4 = (size_t)NTOK * 128 * 2;      // y2b ; h2(half) spans S4+S5
    const size_t S5 = (size_t)NTOK * 180 * 4;      // y4 fp32
    char* pA0 = ws;
    char* pA1 = pA0 + S0;
    char* pA2 = pA1 + S1;
    char* pA3 = pA2 + S2;
    char* pA4 = pA3 + S3;
    char* pA5 = pA4 + S4;
    char* tail = pA5 + S5;

    ushortw* xnb    = (ushortw*)pA0;           // [NTOK][192]
    ushortw* xn2b   = (ushortw*)pA0;
    ushortw* qkvP   = (ushortw*)pA1;           // [NTOK][576]
    ushortw* y1b    = (ushortw*)pA1;           // [NTOK][96]
    ushortw* h1     = (ushortw*)pA1;           // [HALFTOK][720]
    ushortw* h3     = (ushortw*)pA1;           // [HALFTOK][768]
    ushortw* attnbb = (ushortw*)pA2;           // [NTOK][192]
    ushortw* y3b    = (ushortw*)pA2;           // [NTOK][192]
    float*   x1     = (float*)pA3;             // [NTOK][180]
    ushortw* y2b    = (ushortw*)pA4;           // [NTOK][128]
    ushortw* h2     = (ushortw*)pA4;           // [HALFTOK][768] spans S4+S5
    float*   y4     = (float*)pA5;             // [NTOK][180]

    // bf16 gemm weights (padded)
    ushortw* wqkv  = (ushortw*)tail;                        // 640 x 192
    ushortw* wproj = wqkv  + 640 * 192;                     // 256 x 192
    ushortw* wcab0 = wproj + 256 * 192;                     // 128 x 192
    ushortw* wcab2 = wcab0 + 128 * 192;                     // 256 x 128
    ushortw* wfc1  = wcab2 + 256 * 128;                     // 768 x 192
    ushortw* wpw   = wfc1  + 768 * 192;                     // 768 x 768
    ushortw* wfc2  = wpw   + 768 * 768;                     // 256 x 768
    char* tail2 = (char*)(wfc2 + 256 * 768);
    float* dwt1 = (float*)tail2;                 float* db1 = dwt1 + 9*128;   // [9][128]+[128]
    float* dwt2 = db1 + 128;                     float* db2 = dwt2 + 9*192;   // [9][192]+[192]
    float* dwt3 = db2 + 192;                     float* db3 = dwt3 + 9*768;   // [9][768]+[768]
    char* tail3 = (char*)(db3 + 768);
    float* biasN = (float*)tail3;                           // 6*256*256
    float* part  = (float*)(tail3 + 1572864);
    float* cabuf = (float*)(tail3 + 1572864 + 98304);
    float* mp    = (float*)(tail3 + 1572864 + 131072);                          // [HALFTOK]
    float* ap    = (float*)(tail3 + 1572864 + 131072 + (size_t)HALFTOK * 4);    // [HALFTOK]
    float* sab   = (float*)(tail3 + 1572864 + 131072 + 2*(size_t)HALFTOK * 4);  // [HALFTOK]

    auto wc = [&](const float* src, ushortw* dst, int N, int K, int Np, int Kp) {
        wconv_kernel<<<dim3((Np * Kp + 255) / 256), dim3(256), 0, stream>>>(src, dst, N, K, Np, Kp);
    };
    auto gemm = [&](const ushortw* A, const ushortw* Wt, const float* bi, void* Cp,
                    int M, int N, int Kp, int ldc, int outbf, int zfill, int act, int qm,
                    const float* rs, const float* resid) {
        dim3 g((N + 127) / 128, M / 128);
        mgemm_kernel<<<g, dim3(256), 0, stream>>>(A, Wt, bi, Cp, M, N, Kp, ldc, outbf, zfill, act, qm, rs, resid);
    };

    // 0) weight prep
    wc(qkv_w, wqkv, 540, 180, 640, 192);
    wc(proj_w, wproj, 180, 180, 256, 192);
    wc(cab_w0, wcab0, 90, 180, 128, 192);
    wc(cab_w2, wcab2, 180, 90, 256, 128);
    wc(fc1_w, wfc1, 720, 180, 768, 192);
    wc(pw_w, wpw, 720, 720, 768, 768);
    wc(fc2_w, wfc2, 180, 720, 256, 768);
    dwt_kernel<<<dim3((128*9 + 255)/256), dim3(256), 0, stream>>>(cab_w1, cab_b1, dwt1, db1, 90, 128);
    dwt_kernel<<<dim3((192*9 + 255)/256), dim3(256), 0, stream>>>(cab_w3, cab_b3, dwt2, db2, 180, 192);
    dwt_kernel<<<dim3((768*9 + 255)/256), dim3(256), 0, stream>>>(dw_w, dw_b, dwt3, db3, 720, 768);

    // 1) LN1 -> bf16 xnb ; bias table (natural orientation)
    ln_kernel<<<dim3(NTOK / 4), dim3(256), 0, stream>>>(x, n1g, n1b, xnb);
    bias_kernel<<<dim3((NTOKW * NTOKW) / 256), dim3(256), 0, stream>>>(rpi, rpb, biasN);
    // 2) full-batch qkv (padded layout) + MFMA attention
    gemm(xnb, wqkv, qkv_b, qkvP, NTOK, 540, 192, QKVSTR, 1, 0, 0, 1, nullptr, nullptr);
    attn_mfma_kernel<<<dim3(BB * 64 * NHEADS), dim3(256), 0, stream>>>(qkvP, biasN, attnbb);
    // 3) CAB part 1 (xnb consumed)
    gemm(xnb, wcab0, cab_b0, y1b, NTOK, 90, 192, 96, 1, 1, 0, 0, nullptr, nullptr);
    dwconv_kernel<96, 128, 128, 1, 1, 1><<<dim3(NTOK / 4, 2), dim3(256), 0, stream>>>(
        y1b, dwt1, db1, y2b);
    // 4) proj with residual x -> x1
    gemm(attnbb, wproj, proj_b, x1, NTOK, 180, 192, 180, 0, 0, 0, 0, nullptr, x);
    // 5) CAB part 2
    gemm(y2b, wcab2, cab_b2, y3b, NTOK, 180, 128, 192, 1, 1, 0, 0, nullptr, nullptr);
    dwconv_kernel<192, 192, 180, 2, 0, 0><<<dim3(NTOK / 4, 3), dim3(256), 0, stream>>>(
        y3b, dwt2, db2, y4);
    gap_kernel<<<dim3(BB * 32), dim3(192), 0, stream>>>(y4, part);
    ca_kernel<<<dim3(1), dim3(256), 0, stream>>>(part, ca_w1, ca_b1, ca_w2, ca_b2, cabuf);
    // 6) x1 += 0.01*y4*ca; LN2 -> bf16 xn2b
    resid_ln_kernel<<<dim3(NTOK / 4), dim3(256), 0, stream>>>(x1, y4, cabuf, n2g, n2b, xn2b);
    // 7) FFN in two half-batches (2 images each)
    for (int half = 0; half < 2; half++) {
        size_t toff = (size_t)half * HALFTOK;
        gemm(xn2b + toff * 192, wfc1, fc1_b, h1, HALFTOK, 720, 192, 720, 1, 0, 1, 0, nullptr, nullptr);
        dwconv_kernel<720, 768, 768, 1, 2, 1><<<dim3(HALFTOK / 4, 12), dim3(256), 0, stream>>>(
            h1, dwt3, db3, h2);
        gemm(h2, wpw, pw_b, h3, HALFTOK, 720, 768, 768, 1, 1, 2, 0, nullptr, nullptr);
        mpap_kernel<<<dim3(HALFTOK / 4), dim3(256), 0, stream>>>(h3, mp, ap);
        saconv_kernel<<<dim3(HALFTOK / 256), dim3(256), 0, stream>>>(mp, ap, sa_w, sab);
        gemm(h3, wfc2, fc2_b, outp + toff * 180, HALFTOK, 180, 768, 180, 0, 0, 0, 0,
             sab, x1 + toff * 180);
    }
}

// Round 7
// 1239.695 us; speedup vs baseline: 2.8095x; 1.0868x over previous
//
#include <hip/hip_runtime.h>
#include <math.h>

#define HH 128
#define WW 128
#define CC 180
#define BB 4
#define IMG (HH*WW)          // 16384 tokens per image
#define NTOK (BB*IMG)        // 65536
#define HALFTOK (2*IMG)      // 32768
#define NHEADS 6
#define HD 30
#define WSZ 16
#define NTOKW (WSZ*WSZ)      // 256
#define HID 720
#define QKVSTR 576           // padded qkv row: 3 sections x 6 heads x 32

typedef __attribute__((ext_vector_type(8))) short short8v;
typedef __attribute__((ext_vector_type(4))) float f32x4;
typedef unsigned short ushortw;

__device__ __forceinline__ float warp_sum(float v) {
    #pragma unroll
    for (int o = 32; o > 0; o >>= 1) v += __shfl_xor(v, o);
    return v;
}
__device__ __forceinline__ float warp_max(float v) {
    #pragma unroll
    for (int o = 32; o > 0; o >>= 1) v = fmaxf(v, __shfl_xor(v, o));
    return v;
}
__device__ __forceinline__ float gelu_exact(float v) {
    return 0.5f * v * (1.f + erff(v * 0.70710678118654752f));
}
__device__ __forceinline__ ushortw f2bf(float f) {
    union { float f; unsigned int u; } c; c.f = f;
    unsigned int r = (c.u + 0x7FFFu + ((c.u >> 16) & 1u)) >> 16;
    return (ushortw)r;
}
__device__ __forceinline__ float bf2f(ushortw u) {
    union { unsigned int u; float f; } c; c.u = ((unsigned int)u) << 16; return c.f;
}

// ---------------- weight fp32 -> bf16 with N/K padding (zeros) ----------------
__global__ void wconv_kernel(const float* __restrict__ src, ushortw* __restrict__ dst,
                             int N, int K, int Npad, int Kpad)
{
    int idx = blockIdx.x * blockDim.x + threadIdx.x;
    if (idx >= Npad * Kpad) return;
    int r = idx / Kpad, k = idx % Kpad;
    float v = (r < N && k < K) ? src[r * K + k] : 0.f;
    dst[idx] = f2bf(v);
}

// ---------------- dw weight transpose [C][9] -> [9][COP] (+ padded bias) ----------------
__global__ void dwt_kernel(const float* __restrict__ src, const float* __restrict__ bsrc,
                           float* __restrict__ dst, float* __restrict__ bdst,
                           int C, int COP)
{
    int idx = blockIdx.x * blockDim.x + threadIdx.x;
    if (idx >= COP * 9) return;
    int c = idx / 9, k = idx - c * 9;
    dst[k * COP + c] = (c < C) ? src[c * 9 + k] : 0.f;
    if (k == 0) bdst[c] = (c < C) ? bsrc[c] : 0.f;
}

// ---------------- LayerNorm -> bf16 out, stride 192 (cols 180..191 zero) ----------------
__global__ __launch_bounds__(256) void ln_kernel(
    const float* __restrict__ x, const float* __restrict__ g,
    const float* __restrict__ b, ushortw* __restrict__ out)
{
    int wid = threadIdx.x >> 6, lane = threadIdx.x & 63;
    int t = blockIdx.x * 4 + wid;
    size_t off = (size_t)t * CC;
    size_t off2 = (size_t)t * 192;
    bool has2 = lane < (CC - 128);
    float v0 = x[off + lane];
    float v1 = x[off + lane + 64];
    float v2 = has2 ? x[off + lane + 128] : 0.f;
    float s = warp_sum(v0 + v1 + v2);
    float mu = s * (1.f / CC);
    float d0 = v0 - mu, d1 = v1 - mu, d2 = has2 ? v2 - mu : 0.f;
    float var = warp_sum(d0*d0 + d1*d1 + d2*d2) * (1.f / CC);
    float rs = rsqrtf(var + 1e-5f);
    out[off2 + lane]      = f2bf(d0 * rs * g[lane]      + b[lane]);
    out[off2 + lane + 64] = f2bf(d1 * rs * g[lane + 64] + b[lane + 64]);
    out[off2 + lane + 128] = has2 ? f2bf(d2 * rs * g[lane + 128] + b[lane + 128]) : (ushortw)0;
}

// ---------------- relative position bias, natural [h][i*256+j] ----------------
__global__ void bias_kernel(const int* __restrict__ rpi, const float* __restrict__ rpb,
                            float* __restrict__ biasN)
{
    int idx = blockIdx.x * blockDim.x + threadIdx.x;
    if (idx >= NTOKW * NTOKW) return;
    int r = rpi[idx];
    #pragma unroll
    for (int h = 0; h < NHEADS; h++)
        biasN[((size_t)h << 16) + idx] = rpb[r * NHEADS + h];
}

// ---------------- bf16 MFMA GEMM, m97 structure ----------------
// qkvmode: epilogue remaps col n (0..539) -> section(q/k/v)*192 + head*32 + d, bf16.
__global__ __launch_bounds__(256) void mgemm_kernel(
    const ushortw* __restrict__ A, const ushortw* __restrict__ Wt,
    const float* __restrict__ bias, void* __restrict__ Cout,
    int M, int N, int Kp, int ldc, int outbf, int zfill, int act, int qkvmode,
    const float* __restrict__ rowscale, const float* __restrict__ resid)
{
    __shared__ ushortw sA[128 * 64];
    __shared__ ushortw sB[128 * 64];
    int tid = threadIdx.x, lane = tid & 63, wid = tid >> 6;
    int m0 = blockIdx.y << 7, n0 = blockIdx.x << 7;
    int wm = (wid >> 1) << 6, wn = (wid & 1) << 6;
    int lrow = lane & 15, kgrp = lane >> 4;

    f32x4 acc[4][4];
    #pragma unroll
    for (int i = 0; i < 4; i++)
        #pragma unroll
        for (int j = 0; j < 4; j++)
            #pragma unroll
            for (int r = 0; r < 4; r++) acc[i][j][r] = 0.f;

    int nk = Kp >> 6;
    for (int t = 0; t < nk; t++) {
        int kk = t << 6;
        #pragma unroll
        for (int q = 0; q < 4; q++) {
            int seg = (wid << 2) + q;                 // 0..15
            int row = (seg << 3) + (lane >> 3);       // 0..127
            int cg = (lane & 7) ^ (row & 7);          // swizzled global chunk
            const ushortw* ga = A + (size_t)(m0 + row) * Kp + kk + (cg << 3);
            __builtin_amdgcn_global_load_lds(
                (const __attribute__((address_space(1))) void*)ga,
                (__attribute__((address_space(3))) void*)&sA[seg << 9], 16, 0, 0);
            const ushortw* gb = Wt + (size_t)(n0 + row) * Kp + kk + (cg << 3);
            __builtin_amdgcn_global_load_lds(
                (const __attribute__((address_space(1))) void*)gb,
                (__attribute__((address_space(3))) void*)&sB[seg << 9], 16, 0, 0);
        }
        __syncthreads();
        short8v a[4][2], b[4][2];
        #pragma unroll
        for (int i = 0; i < 4; i++) {
            int r = wm + (i << 4) + lrow;
            #pragma unroll
            for (int s = 0; s < 2; s++) {
                int slot = ((s << 2) + kgrp) ^ (r & 7);
                a[i][s] = *reinterpret_cast<const short8v*>(&sA[(r << 6) + (slot << 3)]);
            }
        }
        #pragma unroll
        for (int j = 0; j < 4; j++) {
            int r = wn + (j << 4) + lrow;
            #pragma unroll
            for (int s = 0; s < 2; s++) {
                int slot = ((s << 2) + kgrp) ^ (r & 7);
                b[j][s] = *reinterpret_cast<const short8v*>(&sB[(r << 6) + (slot << 3)]);
            }
        }
        #pragma unroll
        for (int i = 0; i < 4; i++)
            #pragma unroll
            for (int j = 0; j < 4; j++) {
                acc[i][j] = __builtin_amdgcn_mfma_f32_16x16x32_bf16(a[i][0], b[j][0], acc[i][j], 0, 0, 0);
                acc[i][j] = __builtin_amdgcn_mfma_f32_16x16x32_bf16(a[i][1], b[j][1], acc[i][j], 0, 0, 0);
            }
        __syncthreads();
    }
    #pragma unroll
    for (int i = 0; i < 4; i++) {
        int rowb = m0 + wm + (i << 4) + (kgrp << 2);
        #pragma unroll
        for (int j = 0; j < 4; j++) {
            int col = n0 + wn + (j << 4) + lrow;
            if (qkvmode) {
                if (col < N) {
                    int sub = (col >= 360) ? 2 : (col >= 180 ? 1 : 0);
                    int rem = col - sub * 180;
                    int hh = rem / 30;
                    int dd = rem - hh * 30;
                    int col2 = sub * 192 + hh * 32 + dd;
                    float bi = bias[col];
                    #pragma unroll
                    for (int r = 0; r < 4; r++) {
                        int row = rowb + r;
                        ((ushortw*)Cout)[(size_t)row * QKVSTR + col2] = f2bf(acc[i][j][r] + bi);
                    }
                }
                continue;
            }
            if (col < N) {
                float bi = bias[col];
                #pragma unroll
                for (int r = 0; r < 4; r++) {
                    int row = rowb + r;
                    float v = acc[i][j][r];
                    if (rowscale) v *= rowscale[row];
                    v += bi;
                    if (act == 1) v = gelu_exact(v);
                    else if (act == 2) v = fmaxf(v, 0.f);
                    if (resid) v += resid[(size_t)row * N + col];
                    if (outbf) ((ushortw*)Cout)[(size_t)row * ldc + col] = f2bf(v);
                    else       ((float*)Cout)[(size_t)row * ldc + col] = v;
                }
            } else if (zfill && col < ldc) {
                #pragma unroll
                for (int r = 0; r < 4; r++) {
                    int row = rowb + r;
                    if (outbf) ((ushortw*)Cout)[(size_t)row * ldc + col] = 0;
                    else       ((float*)Cout)[(size_t)row * ldc + col] = 0.f;
                }
            }
        }
    }
}

// ---------------- MFMA window attention (swapped QK^T): block = (img, win, head) ----------------
// Lane-local softmax rows: s = mfma(K, Q) puts P^T[k][q=a15] in regs.
// K in XOR-swizzled LDS, P half-tiles (k=128) per wave in XOR-swizzled LDS.
__global__ __launch_bounds__(256, 3) void attn_mfma_kernel(
    const ushortw* __restrict__ qkvP, const float* __restrict__ biasN,
    ushortw* __restrict__ out)
{
    __shared__ ushortw Vc[32 * 33 * 8];      // [kc][33 d-slots][8] : 16896 B
    __shared__ ushortw Kc[256 * 32];         // [k-row][32 d], chunk-XOR swizzled : 16384 B
    __shared__ ushortw Pl[4][2048];          // per-wave [16 q][128 k] bf16, XOR-swizzled : 16384 B
    const float SCALE = 0.18257418583505536f;   // 30^-0.5
    int blk = blockIdx.x;
    int img = blk / 384;
    int rem = blk - img * 384;
    int win = rem / NHEADS;
    int h = rem - win * NHEADS;
    int base = img * IMG + (win >> 3) * WSZ * WW + (win & 7) * WSZ;
    int tid = threadIdx.x;
    int lane = tid & 63, w = tid >> 6;
    int a15 = lane & 15, kg = lane >> 4;

    // ---- stage V (k-chunked B-operand layout) and K (row-major, chunk-XOR) ----
    {
        int j = tid;
        int g = base + (j >> 4) * WW + (j & 15);
        const ushortw* vp = qkvP + (size_t)g * QKVSTR + 384 + h * 32;
        short8v c0 = *reinterpret_cast<const short8v*>(vp);
        short8v c1 = *reinterpret_cast<const short8v*>(vp + 8);
        short8v c2 = *reinterpret_cast<const short8v*>(vp + 16);
        short8v c3 = *reinterpret_cast<const short8v*>(vp + 24);
        int bo = (j >> 3) * 264 + (j & 7);
        #pragma unroll
        for (int e = 0; e < 8; e++)  Vc[bo + (e) * 8]      = (ushortw)c0[e];
        #pragma unroll
        for (int e = 0; e < 8; e++)  Vc[bo + (8 + e) * 8]  = (ushortw)c1[e];
        #pragma unroll
        for (int e = 0; e < 8; e++)  Vc[bo + (16 + e) * 8] = (ushortw)c2[e];
        #pragma unroll
        for (int e = 0; e < 6; e++)  Vc[bo + (24 + e) * 8] = (ushortw)c3[e];
        // K row j
        const ushortw* kp = qkvP + (size_t)g * QKVSTR + 192 + h * 32;
        short8v k0 = *reinterpret_cast<const short8v*>(kp);
        short8v k1 = *reinterpret_cast<const short8v*>(kp + 8);
        short8v k2 = *reinterpret_cast<const short8v*>(kp + 16);
        short8v k3 = *reinterpret_cast<const short8v*>(kp + 24);
        k3[6] = 0; k3[7] = 0;
        short8v* krow = reinterpret_cast<short8v*>(&Kc[j * 32]);
        int jsw = j & 3;
        krow[0 ^ jsw] = k0; krow[1 ^ jsw] = k1; krow[2 ^ jsw] = k2; krow[3 ^ jsw] = k3;
    }
    __syncthreads();

    ushortw* Pw = &Pl[w][0];
    int xsw = (a15 & 7) << 2;                // P dword-XOR per q-row
    f32x4 zf = {0.f, 0.f, 0.f, 0.f};
    #pragma unroll 1
    for (int si = 0; si < 4; si++) {
        int strip = (w << 2) + si;
        short8v qf = *reinterpret_cast<const short8v*>(
            qkvP + (size_t)(base + strip * WW + a15) * QKVSTR + h * 32 + (kg << 3));
        if (kg == 3) { qf[6] = 0; qf[7] = 0; }
        float psum = 0.f;
        f32x4 o0 = zf, o1 = zf;
        const float* brow = biasN + ((size_t)h << 16) + (size_t)((strip << 4) + a15) * 256;
        #pragma unroll 1
        for (int half = 0; half < 2; half++) {
            f32x4 s[8];
            #pragma unroll
            for (int j8 = 0; j8 < 8; j8++) {
                int jt = (half << 3) + j8;
                int row = (jt << 4) + a15;
                short8v ka = reinterpret_cast<const short8v*>(&Kc[row * 32])[kg ^ (row & 3)];
                s[j8] = __builtin_amdgcn_mfma_f32_16x16x32_bf16(ka, qf, zf, 0, 0, 0);
            }
            #pragma unroll
            for (int j8 = 0; j8 < 8; j8++) {
                int jt = (half << 3) + j8;
                float4 b4 = *reinterpret_cast<const float4*>(brow + (jt << 4) + (kg << 2));
                float p0 = __expf(fmaf(s[j8][0], SCALE, b4.x));
                float p1 = __expf(fmaf(s[j8][1], SCALE, b4.y));
                float p2 = __expf(fmaf(s[j8][2], SCALE, b4.z));
                float p3 = __expf(fmaf(s[j8][3], SCALE, b4.w));
                psum += (p0 + p1) + (p2 + p3);
                unsigned int u0, u1;
                asm("v_cvt_pk_bf16_f32 %0, %1, %2" : "=v"(u0) : "v"(p0), "v"(p1));
                asm("v_cvt_pk_bf16_f32 %0, %1, %2" : "=v"(u1) : "v"(p2), "v"(p3));
                int dw0 = ((j8 << 3) + (kg << 1)) ^ xsw;
                unsigned long long pk64 = (unsigned long long)u0 | ((unsigned long long)u1 << 32);
                *reinterpret_cast<unsigned long long*>(&Pw[(a15 << 7) + (dw0 << 1)]) = pk64;
            }
            __builtin_amdgcn_sched_barrier(0);
            #pragma unroll
            for (int ks4 = 0; ks4 < 4; ks4++) {
                int dwr = ((ks4 << 4) + (kg << 2)) ^ xsw;
                short8v pa = *reinterpret_cast<const short8v*>(&Pw[(a15 << 7) + (dwr << 1)]);
                int kc = (((half << 2) + ks4) << 2) + kg;
                short8v v0 = *reinterpret_cast<const short8v*>(&Vc[(kc * 33 + a15) * 8]);
                short8v v1 = *reinterpret_cast<const short8v*>(&Vc[(kc * 33 + 16 + a15) * 8]);
                o0 = __builtin_amdgcn_mfma_f32_16x16x32_bf16(pa, v0, o0, 0, 0, 0);
                o1 = __builtin_amdgcn_mfma_f32_16x16x32_bf16(pa, v1, o1, 0, 0, 0);
            }
            __builtin_amdgcn_sched_barrier(0);
        }
        // row sums: reduce over kg lanes (k partitions); lane a15 holds q=a15 total
        psum += __shfl_xor(psum, 16);
        psum += __shfl_xor(psum, 32);
        #pragma unroll
        for (int r = 0; r < 4; r++) {
            float pt = __shfl(psum, (kg << 2) + r);
            float inv = 1.f / pt;
            int g = base + strip * WW + (kg << 2) + r;
            ushortw* orow = out + (size_t)g * 192 + h * HD;
            orow[a15] = f2bf(o0[r] * inv);
            if (a15 < 14) orow[16 + a15] = f2bf(o1[r] * inv);
        }
    }
    if (h == 0) {   // zero pad cols 180..191
        for (int idx2 = tid; idx2 < NTOKW * 12; idx2 += 256) {
            int j = idx2 / 12, d = idx2 - (idx2 / 12) * 12;
            int gj = base + (j >> 4) * WW + (j & 15);
            out[(size_t)gj * 192 + 180 + d] = 0;
        }
    }
}

// ---------------- templated depthwise 3x3 conv, NHWC ----------------
template<int CIN_S, int COP, int OSTR, int DIL, int ACT, int OUTBF>
__global__ __launch_bounds__(256) void dwconv_kernel(
    const ushortw* __restrict__ in, const float* __restrict__ wt,
    const float* __restrict__ bias, void* __restrict__ out)
{
    int tid = threadIdx.x;
    int pix = (blockIdx.x << 2) + (tid >> 6);
    int c = (blockIdx.y << 6) + (tid & 63);
    int p = pix & (IMG - 1);
    int base = pix - p;
    int px = p & (WW - 1), py = p >> 7;
    float acc = bias[c];
    #pragma unroll
    for (int ky = 0; ky < 3; ky++) {
        int iy = py + (ky - 1) * DIL;
        if (iy < 0 || iy >= HH) continue;
        #pragma unroll
        for (int kx = 0; kx < 3; kx++) {
            int ix = px + (kx - 1) * DIL;
            if (ix < 0 || ix >= WW) continue;
            int nbr = base + (iy << 7) + ix;
            acc += bf2f(in[(size_t)nbr * CIN_S + c]) * wt[(ky * 3 + kx) * COP + c];
        }
    }
    if (ACT == 1) acc = gelu_exact(acc);
    else if (ACT == 2) acc = fmaxf(acc, 0.f);
    if (c < OSTR) {
        if (OUTBF) ((ushortw*)out)[(size_t)pix * OSTR + c] = f2bf(acc);
        else       ((float*)out)[(size_t)pix * OSTR + c] = acc;
    }
}

// ---------------- GAP partial sums over fp32 y4 ----------------
__global__ void gap_kernel(const float* __restrict__ y, float* __restrict__ part)
{
    int blk = blockIdx.x;
    int b = blk >> 5, chunk = blk & 31;
    int c = threadIdx.x;
    if (c >= CC) return;
    size_t basep = ((size_t)b * IMG + (size_t)chunk * 512) * CC;
    float s = 0.f;
    for (int p = 0; p < 512; p++) s += y[basep + (size_t)p * CC + c];
    part[((size_t)b * 32 + chunk) * CC + c] = s;
}

// ---------------- channel attention (tiny) ----------------
__global__ void ca_kernel(const float* __restrict__ part,
                          const float* __restrict__ w1, const float* __restrict__ b1,
                          const float* __restrict__ w2, const float* __restrict__ b2,
                          float* __restrict__ ca)
{
    __shared__ float gap[BB * CC];
    __shared__ float s1[BB * 6];
    int tid = threadIdx.x;
    for (int idx = tid; idx < BB * CC; idx += 256) {
        int b = idx / CC, c = idx % CC;
        float s = 0.f;
        for (int ch = 0; ch < 32; ch++) s += part[((size_t)b * 32 + ch) * CC + c];
        gap[idx] = s * (1.f / IMG);
    }
    __syncthreads();
    if (tid < BB * 6) {
        int b = tid / 6, cs = tid % 6;
        float s = 0.f;
        for (int c = 0; c < CC; c++) s += w1[cs * CC + c] * gap[b * CC + c];
        s1[tid] = fmaxf(s + b1[cs], 0.f);
    }
    __syncthreads();
    for (int idx = tid; idx < BB * CC; idx += 256) {
        int b = idx / CC, c = idx % CC;
        float s = b2[c];
        #pragma unroll
        for (int cs = 0; cs < 6; cs++) s += w2[c * 6 + cs] * s1[b * 6 + cs];
        ca[idx] = 1.f / (1.f + __expf(-s));
    }
}

// ---------------- x1 += 0.01*y4*ca (fp32, in place); LN2 -> bf16 xn2 (stride 192) ----------------
__global__ __launch_bounds__(256) void resid_ln_kernel(
    float* __restrict__ x1, const float* __restrict__ y4, const float* __restrict__ ca,
    const float* __restrict__ g, const float* __restrict__ bb,
    ushortw* __restrict__ xn2)
{
    int wid = threadIdx.x >> 6, lane = threadIdx.x & 63;
    int t = blockIdx.x * 4 + wid;
    int b = t >> 14;
    size_t off = (size_t)t * CC;
    size_t off2 = (size_t)t * 192;
    bool has2 = lane < (CC - 128);
    float v0 = x1[off+lane]    + 0.01f * y4[off+lane]    * ca[b*CC + lane];
    float v1 = x1[off+lane+64] + 0.01f * y4[off+lane+64] * ca[b*CC + lane+64];
    float v2 = 0.f;
    if (has2) v2 = x1[off+lane+128] + 0.01f * y4[off+lane+128] * ca[b*CC + lane+128];
    x1[off+lane] = v0; x1[off+lane+64] = v1;
    if (has2) x1[off+lane+128] = v2;
    float s = warp_sum(v0 + v1 + v2);
    float mu = s * (1.f / CC);
    float d0 = v0-mu, d1 = v1-mu, d2 = has2 ? v2-mu : 0.f;
    float var = warp_sum(d0*d0 + d1*d1 + d2*d2) * (1.f / CC);
    float rs = rsqrtf(var + 1e-5f);
    xn2[off2+lane]      = f2bf(d0 * rs * g[lane]      + bb[lane]);
    xn2[off2+lane+64]   = f2bf(d1 * rs * g[lane+64]   + bb[lane+64]);
    xn2[off2+lane+128]  = has2 ? f2bf(d2 * rs * g[lane+128] + bb[lane+128]) : (ushortw)0;
}

// ---------------- max/mean over channels per pixel (bf16 h3, stride 768, 720 cols) ----------------
__global__ __launch_bounds__(256) void mpap_kernel(
    const ushortw* __restrict__ h, float* __restrict__ mp, float* __restrict__ ap)
{
    int wid = threadIdx.x >> 6, lane = threadIdx.x & 63;
    int p = blockIdx.x * 4 + wid;
    const ushortw* row = h + (size_t)p * 768;
    float mx = -1e30f, s = 0.f;
    for (int j = lane; j < HID; j += 64) { float v = bf2f(row[j]); mx = fmaxf(mx, v); s += v; }
    mx = warp_max(mx); s = warp_sum(s);
    if (lane == 0) { mp[p] = mx; ap[p] = s * (1.f / HID); }
}

// ---------------- 7x7 spatial-attention conv + sigmoid (half batch = 2 images) ----------------
__global__ void saconv_kernel(const float* __restrict__ mp, const float* __restrict__ ap,
                              const float* __restrict__ w, float* __restrict__ sa)
{
    int p = blockIdx.x * blockDim.x + threadIdx.x;   // 0..HALFTOK-1
    int lp = p & (IMG - 1);
    int base = p - lp;
    int px = lp & (WW - 1), py = lp >> 7;
    float acc = 0.f;
    for (int ky = 0; ky < 7; ky++) {
        int iy = py + ky - 3;
        if (iy < 0 || iy >= HH) continue;
        for (int kx = 0; kx < 7; kx++) {
            int ix = px + kx - 3;
            if (ix < 0 || ix >= WW) continue;
            int pid = base + iy * WW + ix;
            acc += mp[pid] * w[ky * 7 + kx] + ap[pid] * w[49 + ky * 7 + kx];
        }
    }
    sa[p] = 1.f / (1.f + __expf(-acc));
}

extern "C" void kernel_launch(void* const* d_in, const int* in_sizes, int n_in,
                              void* d_out, int out_size, void* d_ws, size_t ws_size,
                              hipStream_t stream)
{
    const float* x      = (const float*)d_in[0];
    const int*   rpi    = (const int*)d_in[3];
    const float* n1g    = (const float*)d_in[4];
    const float* n1b    = (const float*)d_in[5];
    const float* rpb    = (const float*)d_in[6];
    const float* qkv_w  = (const float*)d_in[7];
    const float* qkv_b  = (const float*)d_in[8];
    const float* proj_w = (const float*)d_in[9];
    const float* proj_b = (const float*)d_in[10];
    const float* cab_w0 = (const float*)d_in[11];
    const float* cab_b0 = (const float*)d_in[12];
    const float* cab_w1 = (const float*)d_in[13];
    const float* cab_b1 = (const float*)d_in[14];
    const float* cab_w2 = (const float*)d_in[15];
    const float* cab_b2 = (const float*)d_in[16];
    const float* cab_w3 = (const float*)d_in[17];
    const float* cab_b3 = (const float*)d_in[18];
    const float* ca_w1  = (const float*)d_in[19];
    const float* ca_b1  = (const float*)d_in[20];
    const float* ca_w2  = (const float*)d_in[21];
    const float* ca_b2  = (const float*)d_in[22];
    const float* n2g    = (const float*)d_in[23];
    const float* n2b    = (const float*)d_in[24];
    const float* fc1_w  = (const float*)d_in[25];
    const float* fc1_b  = (const float*)d_in[26];
    const float* dw_w   = (const float*)d_in[27];
    const float* dw_b   = (const float*)d_in[28];
    const float* pw_w   = (const float*)d_in[29];
    const float* pw_b   = (const float*)d_in[30];
    const float* sa_w   = (const float*)d_in[31];
    const float* fc2_w  = (const float*)d_in[32];
    const float* fc2_b  = (const float*)d_in[33];
    float* outp = (float*)d_out;
    (void)in_sizes; (void)n_in; (void)out_size; (void)ws_size;

    char* ws = (char*)d_ws;
    const size_t S0 = (size_t)NTOK * 192 * 2;      // xnb -> xn2b
    const size_t S1 = (size_t)NTOK * QKVSTR * 2;   // qkvP -> y1b -> h1(half) -> h3(half)
    const size_t S2 = (size_t)NTOK * 192 * 2;      // attnbb -> y3b
    const size_t S3 = (size_t)NTOK * 180 * 4;      // x1 fp32 persistent
    const size_t S4 = (size_t)NTOK * 128 * 2;      // y2b ; h2(half) spans S4+S5
    const size_t S5 = (size_t)NTOK * 180 * 4;      // y4 fp32
    char* pA0 = ws;
    char* pA1 = pA0 + S0;
    char* pA2 = pA1 + S1;
    char* pA3 = pA2 + S2;
    char* pA4 = pA3 + S3;
    char* pA5 = pA4 + S4;
    char* tail = pA5 + S5;

    ushortw* xnb    = (ushortw*)pA0;           // [NTOK][192]
    ushortw* xn2b   = (ushortw*)pA0;
    ushortw* qkvP   = (ushortw*)pA1;           // [NTOK][576]
    ushortw* y1b    = (ushortw*)pA1;           // [NTOK][96]
    ushortw* h1     = (ushortw*)pA1;           // [HALFTOK][720]
    ushortw* h3     = (ushortw*)pA1;           // [HALFTOK][768]
    ushortw* attnbb = (ushortw*)pA2;           // [NTOK][192]
    ushortw* y3b    = (ushortw*)pA2;           // [NTOK][192]
    float*   x1     = (float*)pA3;             // [NTOK][180]
    ushortw* y2b    = (ushortw*)pA4;           // [NTOK][128]
    ushortw* h2     = (ushortw*)pA4;           // [HALFTOK][768] spans S4+S5
    float*   y4     = (float*)pA5;             // [NTOK][180]

    // bf16 gemm weights (padded)
    ushortw* wqkv  = (ushortw*)tail;                        // 640 x 192
    ushortw* wproj = wqkv  + 640 * 192;                     // 256 x 192
    ushortw* wcab0 = wproj + 256 * 192;                     // 128 x 192
    ushortw* wcab2 = wcab0 + 128 * 192;                     // 256 x 128
    ushortw* wfc1  = wcab2 + 256 * 128;                     // 768 x 192
    ushortw* wpw   = wfc1  + 768 * 192;                     // 768 x 768
    ushortw* wfc2  = wpw   + 768 * 768;                     // 256 x 768
    char* tail2 = (char*)(wfc2 + 256 * 768);
    float* dwt1 = (float*)tail2;                 float* db1 = dwt1 + 9*128;   // [9][128]+[128]
    float* dwt2 = db1 + 128;                     float* db2 = dwt2 + 9*192;   // [9][192]+[192]
    float* dwt3 = db2 + 192;                     float* db3 = dwt3 + 9*768;   // [9][768]+[768]
    char* tail3 = (char*)(db3 + 768);
    float* biasN = (float*)tail3;                           // 6*256*256
    float* part  = (float*)(tail3 + 1572864);
    float* cabuf = (float*)(tail3 + 1572864 + 98304);
    float* mp    = (float*)(tail3 + 1572864 + 131072);                          // [HALFTOK]
    float* ap    = (float*)(tail3 + 1572864 + 131072 + (size_t)HALFTOK * 4);    // [HALFTOK]
    float* sab   = (float*)(tail3 + 1572864 + 131072 + 2*(size_t)HALFTOK * 4);  // [HALFTOK]

    auto wc = [&](const float* src, ushortw* dst, int N, int K, int Np, int Kp) {
        wconv_kernel<<<dim3((Np * Kp + 255) / 256), dim3(256), 0, stream>>>(src, dst, N, K, Np, Kp);
    };
    auto gemm = [&](const ushortw* A, const ushortw* Wt, const float* bi, void* Cp,
                    int M, int N, int Kp, int ldc, int outbf, int zfill, int act, int qm,
                    const float* rs, const float* resid) {
        dim3 g((N + 127) / 128, M / 128);
        mgemm_kernel<<<g, dim3(256), 0, stream>>>(A, Wt, bi, Cp, M, N, Kp, ldc, outbf, zfill, act, qm, rs, resid);
    };

    // 0) weight prep
    wc(qkv_w, wqkv, 540, 180, 640, 192);
    wc(proj_w, wproj, 180, 180, 256, 192);
    wc(cab_w0, wcab0, 90, 180, 128, 192);
    wc(cab_w2, wcab2, 180, 90, 256, 128);
    wc(fc1_w, wfc1, 720, 180, 768, 192);
    wc(pw_w, wpw, 720, 720, 768, 768);
    wc(fc2_w, wfc2, 180, 720, 256, 768);
    dwt_kernel<<<dim3((128*9 + 255)/256), dim3(256), 0, stream>>>(cab_w1, cab_b1, dwt1, db1, 90, 128);
    dwt_kernel<<<dim3((192*9 + 255)/256), dim3(256), 0, stream>>>(cab_w3, cab_b3, dwt2, db2, 180, 192);
    dwt_kernel<<<dim3((768*9 + 255)/256), dim3(256), 0, stream>>>(dw_w, dw_b, dwt3, db3, 720, 768);

    // 1) LN1 -> bf16 xnb ; bias table (natural orientation)
    ln_kernel<<<dim3(NTOK / 4), dim3(256), 0, stream>>>(x, n1g, n1b, xnb);
    bias_kernel<<<dim3((NTOKW * NTOKW) / 256), dim3(256), 0, stream>>>(rpi, rpb, biasN);
    // 2) full-batch qkv (padded layout) + MFMA attention
    gemm(xnb, wqkv, qkv_b, qkvP, NTOK, 540, 192, QKVSTR, 1, 0, 0, 1, nullptr, nullptr);
    attn_mfma_kernel<<<dim3(BB * 64 * NHEADS), dim3(256), 0, stream>>>(qkvP, biasN, attnbb);
    // 3) CAB part 1 (xnb consumed)
    gemm(xnb, wcab0, cab_b0, y1b, NTOK, 90, 192, 96, 1, 1, 0, 0, nullptr, nullptr);
    dwconv_kernel<96, 128, 128, 1, 1, 1><<<dim3(NTOK / 4, 2), dim3(256), 0, stream>>>(
        y1b, dwt1, db1, y2b);
    // 4) proj with residual x -> x1
    gemm(attnbb, wproj, proj_b, x1, NTOK, 180, 192, 180, 0, 0, 0, 0, nullptr, x);
    // 5) CAB part 2
    gemm(y2b, wcab2, cab_b2, y3b, NTOK, 180, 128, 192, 1, 1, 0, 0, nullptr, nullptr);
    dwconv_kernel<192, 192, 180, 2, 0, 0><<<dim3(NTOK / 4, 3), dim3(256), 0, stream>>>(
        y3b, dwt2, db2, y4);
    gap_kernel<<<dim3(BB * 32), dim3(192), 0, stream>>>(y4, part);
    ca_kernel<<<dim3(1), dim3(256), 0, stream>>>(part, ca_w1, ca_b1, ca_w2, ca_b2, cabuf);
    // 6) x1 += 0.01*y4*ca; LN2 -> bf16 xn2b
    resid_ln_kernel<<<dim3(NTOK / 4), dim3(256), 0, stream>>>(x1, y4, cabuf, n2g, n2b, xn2b);
    // 7) FFN in two half-batches (2 images each)
    for (int half = 0; half < 2; half++) {
        size_t toff = (size_t)half * HALFTOK;
        gemm(xn2b + toff * 192, wfc1, fc1_b, h1, HALFTOK, 720, 192, 720, 1, 0, 1, 0, nullptr, nullptr);
        dwconv_kernel<720, 768, 768, 1, 2, 1><<<dim3(HALFTOK / 4, 12), dim3(256), 0, stream>>>(
            h1, dwt3, db3, h2);
        gemm(h2, wpw, pw_b, h3, HALFTOK, 720, 768, 768, 1, 1, 2, 0, nullptr, nullptr);
        mpap_kernel<<<dim3(HALFTOK / 4), dim3(256), 0, stream>>>(h3, mp, ap);
        saconv_kernel<<<dim3(HALFTOK / 256), dim3(256), 0, stream>>>(mp, ap, sa_w, sab);
        gemm(h3, wfc2, fc2_b, outp + toff * 180, HALFTOK, 180, 768, 180, 0, 0, 0, 0,
             sab, x1 + toff * 180);
    }
}

// Round 8
// 912.630 us; speedup vs baseline: 3.8163x; 1.3584x over previous
//
#include <hip/hip_runtime.h>
#include <math.h>

#define HH 128
#define WW 128
#define CC 180
#define BB 4
#define IMG (HH*WW)          // 16384 tokens per image
#define NTOK (BB*IMG)        // 65536
#define HALFTOK (2*IMG)      // 32768
#define NHEADS 6
#define HD 30
#define WSZ 16
#define NTOKW (WSZ*WSZ)      // 256
#define HID 720
#define QKVSTR 576           // padded qkv row: 3 sections x 6 heads x 32

typedef __attribute__((ext_vector_type(8))) short short8v;
typedef __attribute__((ext_vector_type(4))) short short4v;
typedef __attribute__((ext_vector_type(4))) float f32x4;
typedef unsigned short ushortw;

__device__ __forceinline__ float warp_sum(float v) {
    #pragma unroll
    for (int o = 32; o > 0; o >>= 1) v += __shfl_xor(v, o);
    return v;
}
__device__ __forceinline__ float warp_max(float v) {
    #pragma unroll
    for (int o = 32; o > 0; o >>= 1) v = fmaxf(v, __shfl_xor(v, o));
    return v;
}
__device__ __forceinline__ float gelu_exact(float v) {
    return 0.5f * v * (1.f + erff(v * 0.70710678118654752f));
}
__device__ __forceinline__ ushortw f2bf(float f) {
    union { float f; unsigned int u; } c; c.f = f;
    unsigned int r = (c.u + 0x7FFFu + ((c.u >> 16) & 1u)) >> 16;
    return (ushortw)r;
}
__device__ __forceinline__ float bf2f(ushortw u) {
    union { unsigned int u; float f; } c; c.u = ((unsigned int)u) << 16; return c.f;
}

// ---------------- weight fp32 -> bf16 with N/K padding (zeros) ----------------
__global__ void wconv_kernel(const float* __restrict__ src, ushortw* __restrict__ dst,
                             int N, int K, int Npad, int Kpad)
{
    int idx = blockIdx.x * blockDim.x + threadIdx.x;
    if (idx >= Npad * Kpad) return;
    int r = idx / Kpad, k = idx % Kpad;
    float v = (r < N && k < K) ? src[r * K + k] : 0.f;
    dst[idx] = f2bf(v);
}

// ---------------- dw weight transpose [C][9] -> [9][COP] (+ padded bias) ----------------
__global__ void dwt_kernel(const float* __restrict__ src, const float* __restrict__ bsrc,
                           float* __restrict__ dst, float* __restrict__ bdst,
                           int C, int COP)
{
    int idx = blockIdx.x * blockDim.x + threadIdx.x;
    if (idx >= COP * 9) return;
    int c = idx / 9, k = idx - c * 9;
    dst[k * COP + c] = (c < C) ? src[c * 9 + k] : 0.f;
    if (k == 0) bdst[c] = (c < C) ? bsrc[c] : 0.f;
}

// ---------------- LayerNorm -> bf16 out, stride 192 (cols 180..191 zero) ----------------
__global__ __launch_bounds__(256) void ln_kernel(
    const float* __restrict__ x, const float* __restrict__ g,
    const float* __restrict__ b, ushortw* __restrict__ out)
{
    int wid = threadIdx.x >> 6, lane = threadIdx.x & 63;
    int t = blockIdx.x * 4 + wid;
    size_t off = (size_t)t * CC;
    size_t off2 = (size_t)t * 192;
    bool has2 = lane < (CC - 128);
    float v0 = x[off + lane];
    float v1 = x[off + lane + 64];
    float v2 = has2 ? x[off + lane + 128] : 0.f;
    float s = warp_sum(v0 + v1 + v2);
    float mu = s * (1.f / CC);
    float d0 = v0 - mu, d1 = v1 - mu, d2 = has2 ? v2 - mu : 0.f;
    float var = warp_sum(d0*d0 + d1*d1 + d2*d2) * (1.f / CC);
    float rs = rsqrtf(var + 1e-5f);
    out[off2 + lane]      = f2bf(d0 * rs * g[lane]      + b[lane]);
    out[off2 + lane + 64] = f2bf(d1 * rs * g[lane + 64] + b[lane + 64]);
    out[off2 + lane + 128] = has2 ? f2bf(d2 * rs * g[lane + 128] + b[lane + 128]) : (ushortw)0;
}

// ---------------- relative position bias, natural [h][i*256+j] ----------------
__global__ void bias_kernel(const int* __restrict__ rpi, const float* __restrict__ rpb,
                            float* __restrict__ biasN)
{
    int idx = blockIdx.x * blockDim.x + threadIdx.x;
    if (idx >= NTOKW * NTOKW) return;
    int r = rpi[idx];
    #pragma unroll
    for (int h = 0; h < NHEADS; h++)
        biasN[((size_t)h << 16) + idx] = rpb[r * NHEADS + h];
}

// ---------------- bf16 MFMA GEMM, m97 structure ----------------
// qkvmode: epilogue remaps col n (0..539) -> section(q/k/v)*192 + head*32 + d, bf16.
__global__ __launch_bounds__(256) void mgemm_kernel(
    const ushortw* __restrict__ A, const ushortw* __restrict__ Wt,
    const float* __restrict__ bias, void* __restrict__ Cout,
    int M, int N, int Kp, int ldc, int outbf, int zfill, int act, int qkvmode,
    const float* __restrict__ rowscale, const float* __restrict__ resid)
{
    __shared__ ushortw sA[128 * 64];
    __shared__ ushortw sB[128 * 64];
    int tid = threadIdx.x, lane = tid & 63, wid = tid >> 6;
    int m0 = blockIdx.y << 7, n0 = blockIdx.x << 7;
    int wm = (wid >> 1) << 6, wn = (wid & 1) << 6;
    int lrow = lane & 15, kgrp = lane >> 4;

    f32x4 acc[4][4];
    #pragma unroll
    for (int i = 0; i < 4; i++)
        #pragma unroll
        for (int j = 0; j < 4; j++)
            #pragma unroll
            for (int r = 0; r < 4; r++) acc[i][j][r] = 0.f;

    int nk = Kp >> 6;
    for (int t = 0; t < nk; t++) {
        int kk = t << 6;
        #pragma unroll
        for (int q = 0; q < 4; q++) {
            int seg = (wid << 2) + q;                 // 0..15
            int row = (seg << 3) + (lane >> 3);       // 0..127
            int cg = (lane & 7) ^ (row & 7);          // swizzled global chunk
            const ushortw* ga = A + (size_t)(m0 + row) * Kp + kk + (cg << 3);
            __builtin_amdgcn_global_load_lds(
                (const __attribute__((address_space(1))) void*)ga,
                (__attribute__((address_space(3))) void*)&sA[seg << 9], 16, 0, 0);
            const ushortw* gb = Wt + (size_t)(n0 + row) * Kp + kk + (cg << 3);
            __builtin_amdgcn_global_load_lds(
                (const __attribute__((address_space(1))) void*)gb,
                (__attribute__((address_space(3))) void*)&sB[seg << 9], 16, 0, 0);
        }
        __syncthreads();
        short8v a[4][2], b[4][2];
        #pragma unroll
        for (int i = 0; i < 4; i++) {
            int r = wm + (i << 4) + lrow;
            #pragma unroll
            for (int s = 0; s < 2; s++) {
                int slot = ((s << 2) + kgrp) ^ (r & 7);
                a[i][s] = *reinterpret_cast<const short8v*>(&sA[(r << 6) + (slot << 3)]);
            }
        }
        #pragma unroll
        for (int j = 0; j < 4; j++) {
            int r = wn + (j << 4) + lrow;
            #pragma unroll
            for (int s = 0; s < 2; s++) {
                int slot = ((s << 2) + kgrp) ^ (r & 7);
                b[j][s] = *reinterpret_cast<const short8v*>(&sB[(r << 6) + (slot << 3)]);
            }
        }
        #pragma unroll
        for (int i = 0; i < 4; i++)
            #pragma unroll
            for (int j = 0; j < 4; j++) {
                acc[i][j] = __builtin_amdgcn_mfma_f32_16x16x32_bf16(a[i][0], b[j][0], acc[i][j], 0, 0, 0);
                acc[i][j] = __builtin_amdgcn_mfma_f32_16x16x32_bf16(a[i][1], b[j][1], acc[i][j], 0, 0, 0);
            }
        __syncthreads();
    }
    #pragma unroll
    for (int i = 0; i < 4; i++) {
        int rowb = m0 + wm + (i << 4) + (kgrp << 2);
        #pragma unroll
        for (int j = 0; j < 4; j++) {
            int col = n0 + wn + (j << 4) + lrow;
            if (qkvmode) {
                if (col < N) {
                    int sub = (col >= 360) ? 2 : (col >= 180 ? 1 : 0);
                    int rem = col - sub * 180;
                    int hh = rem / 30;
                    int dd = rem - hh * 30;
                    int col2 = sub * 192 + hh * 32 + dd;
                    float bi = bias[col];
                    #pragma unroll
                    for (int r = 0; r < 4; r++) {
                        int row = rowb + r;
                        ((ushortw*)Cout)[(size_t)row * QKVSTR + col2] = f2bf(acc[i][j][r] + bi);
                    }
                }
                continue;
            }
            if (col < N) {
                float bi = bias[col];
                #pragma unroll
                for (int r = 0; r < 4; r++) {
                    int row = rowb + r;
                    float v = acc[i][j][r];
                    if (rowscale) v *= rowscale[row];
                    v += bi;
                    if (act == 1) v = gelu_exact(v);
                    else if (act == 2) v = fmaxf(v, 0.f);
                    if (resid) v += resid[(size_t)row * N + col];
                    if (outbf) ((ushortw*)Cout)[(size_t)row * ldc + col] = f2bf(v);
                    else       ((float*)Cout)[(size_t)row * ldc + col] = v;
                }
            } else if (zfill && col < ldc) {
                #pragma unroll
                for (int r = 0; r < 4; r++) {
                    int row = rowb + r;
                    if (outbf) ((ushortw*)Cout)[(size_t)row * ldc + col] = 0;
                    else       ((float*)Cout)[(size_t)row * ldc + col] = 0.f;
                }
            }
        }
    }
}

// ---------------- MFMA window attention (swapped QK^T): block = (img, win, head) ----------------
__global__ __launch_bounds__(256, 3) void attn_mfma_kernel(
    const ushortw* __restrict__ qkvP, const float* __restrict__ biasN,
    ushortw* __restrict__ out)
{
    __shared__ ushortw Vc[32 * 33 * 8];      // [kc][33 d-slots][8] : 16896 B
    __shared__ ushortw Kc[256 * 32];         // [k-row][32 d], chunk-XOR swizzled : 16384 B
    __shared__ ushortw Pl[4][2048];          // per-wave [16 q][128 k] bf16, XOR-swizzled : 16384 B
    const float SCALE = 0.18257418583505536f;   // 30^-0.5
    int blk = blockIdx.x;
    int img = blk / 384;
    int rem = blk - img * 384;
    int win = rem / NHEADS;
    int h = rem - win * NHEADS;
    int base = img * IMG + (win >> 3) * WSZ * WW + (win & 7) * WSZ;
    int tid = threadIdx.x;
    int lane = tid & 63, w = tid >> 6;
    int a15 = lane & 15, kg = lane >> 4;

    {
        int j = tid;
        int g = base + (j >> 4) * WW + (j & 15);
        const ushortw* vp = qkvP + (size_t)g * QKVSTR + 384 + h * 32;
        short8v c0 = *reinterpret_cast<const short8v*>(vp);
        short8v c1 = *reinterpret_cast<const short8v*>(vp + 8);
        short8v c2 = *reinterpret_cast<const short8v*>(vp + 16);
        short8v c3 = *reinterpret_cast<const short8v*>(vp + 24);
        int bo = (j >> 3) * 264 + (j & 7);
        #pragma unroll
        for (int e = 0; e < 8; e++)  Vc[bo + (e) * 8]      = (ushortw)c0[e];
        #pragma unroll
        for (int e = 0; e < 8; e++)  Vc[bo + (8 + e) * 8]  = (ushortw)c1[e];
        #pragma unroll
        for (int e = 0; e < 8; e++)  Vc[bo + (16 + e) * 8] = (ushortw)c2[e];
        #pragma unroll
        for (int e = 0; e < 6; e++)  Vc[bo + (24 + e) * 8] = (ushortw)c3[e];
        // K row j
        const ushortw* kp = qkvP + (size_t)g * QKVSTR + 192 + h * 32;
        short8v k0 = *reinterpret_cast<const short8v*>(kp);
        short8v k1 = *reinterpret_cast<const short8v*>(kp + 8);
        short8v k2 = *reinterpret_cast<const short8v*>(kp + 16);
        short8v k3 = *reinterpret_cast<const short8v*>(kp + 24);
        k3[6] = 0; k3[7] = 0;
        short8v* krow = reinterpret_cast<short8v*>(&Kc[j * 32]);
        int jsw = j & 3;
        krow[0 ^ jsw] = k0; krow[1 ^ jsw] = k1; krow[2 ^ jsw] = k2; krow[3 ^ jsw] = k3;
    }
    __syncthreads();

    ushortw* Pw = &Pl[w][0];
    int xsw = (a15 & 7) << 2;                // P dword-XOR per q-row
    f32x4 zf = {0.f, 0.f, 0.f, 0.f};
    #pragma unroll 1
    for (int si = 0; si < 4; si++) {
        int strip = (w << 2) + si;
        short8v qf = *reinterpret_cast<const short8v*>(
            qkvP + (size_t)(base + strip * WW + a15) * QKVSTR + h * 32 + (kg << 3));
        if (kg == 3) { qf[6] = 0; qf[7] = 0; }
        float psum = 0.f;
        f32x4 o0 = zf, o1 = zf;
        const float* brow = biasN + ((size_t)h << 16) + (size_t)((strip << 4) + a15) * 256;
        #pragma unroll 1
        for (int half = 0; half < 2; half++) {
            f32x4 s[8];
            #pragma unroll
            for (int j8 = 0; j8 < 8; j8++) {
                int jt = (half << 3) + j8;
                int row = (jt << 4) + a15;
                short8v ka = reinterpret_cast<const short8v*>(&Kc[row * 32])[kg ^ (row & 3)];
                s[j8] = __builtin_amdgcn_mfma_f32_16x16x32_bf16(ka, qf, zf, 0, 0, 0);
            }
            #pragma unroll
            for (int j8 = 0; j8 < 8; j8++) {
                int jt = (half << 3) + j8;
                float4 b4 = *reinterpret_cast<const float4*>(brow + (jt << 4) + (kg << 2));
                float p0 = __expf(fmaf(s[j8][0], SCALE, b4.x));
                float p1 = __expf(fmaf(s[j8][1], SCALE, b4.y));
                float p2 = __expf(fmaf(s[j8][2], SCALE, b4.z));
                float p3 = __expf(fmaf(s[j8][3], SCALE, b4.w));
                psum += (p0 + p1) + (p2 + p3);
                unsigned int u0, u1;
                asm("v_cvt_pk_bf16_f32 %0, %1, %2" : "=v"(u0) : "v"(p0), "v"(p1));
                asm("v_cvt_pk_bf16_f32 %0, %1, %2" : "=v"(u1) : "v"(p2), "v"(p3));
                int dw0 = ((j8 << 3) + (kg << 1)) ^ xsw;
                unsigned long long pk64 = (unsigned long long)u0 | ((unsigned long long)u1 << 32);
                *reinterpret_cast<unsigned long long*>(&Pw[(a15 << 7) + (dw0 << 1)]) = pk64;
            }
            __builtin_amdgcn_sched_barrier(0);
            #pragma unroll
            for (int ks4 = 0; ks4 < 4; ks4++) {
                int dwr = ((ks4 << 4) + (kg << 2)) ^ xsw;
                short8v pa = *reinterpret_cast<const short8v*>(&Pw[(a15 << 7) + (dwr << 1)]);
                int kc = (((half << 2) + ks4) << 2) + kg;
                short8v v0 = *reinterpret_cast<const short8v*>(&Vc[(kc * 33 + a15) * 8]);
                short8v v1 = *reinterpret_cast<const short8v*>(&Vc[(kc * 33 + 16 + a15) * 8]);
                o0 = __builtin_amdgcn_mfma_f32_16x16x32_bf16(pa, v0, o0, 0, 0, 0);
                o1 = __builtin_amdgcn_mfma_f32_16x16x32_bf16(pa, v1, o1, 0, 0, 0);
            }
            __builtin_amdgcn_sched_barrier(0);
        }
        psum += __shfl_xor(psum, 16);
        psum += __shfl_xor(psum, 32);
        #pragma unroll
        for (int r = 0; r < 4; r++) {
            float pt = __shfl(psum, (kg << 2) + r);
            float inv = 1.f / pt;
            int g = base + strip * WW + (kg << 2) + r;
            ushortw* orow = out + (size_t)g * 192 + h * HD;
            orow[a15] = f2bf(o0[r] * inv);
            if (a15 < 14) orow[16 + a15] = f2bf(o1[r] * inv);
        }
    }
    if (h == 0) {   // zero pad cols 180..191
        for (int idx2 = tid; idx2 < NTOKW * 12; idx2 += 256) {
            int j = idx2 / 12, d = idx2 - (idx2 / 12) * 12;
            int gj = base + (j >> 4) * WW + (j & 15);
            out[(size_t)gj * 192 + 180 + d] = 0;
        }
    }
}

// ---------------- register-tiled depthwise 3x3 conv: 4 pixels x 4 channels / thread ----------------
// wt [9][COP] zero-padded, bias [COP] zero-padded. Input stride CIN_S (reads beyond real
// channels hit zero weights). OSTR = output stride; COP may exceed OSTR (group skipped).
template<int CIN_S, int COP, int OSTR, int DIL, int ACT, int OUTBF>
__global__ __launch_bounds__(256) void dwconv4_kernel(
    const ushortw* __restrict__ in, const float* __restrict__ wt,
    const float* __restrict__ bias, void* __restrict__ out)
{
    constexpr int NC4 = COP >> 2;
    constexpr int NX = 4 + 2 * DIL;
    int idx = blockIdx.x * 256 + threadIdx.x;
    int c4 = idx % NC4;
    int quad = idx / NC4;
    int c = c4 << 2;
    int pix0 = quad << 2;
    int p = pix0 & (IMG - 1);
    int imgbase = pix0 - p;
    int px0 = p & (WW - 1), py = p >> 7;

    float4 w9[9];
    #pragma unroll
    for (int t = 0; t < 9; t++)
        w9[t] = *reinterpret_cast<const float4*>(wt + t * COP + c);
    float4 bi4 = *reinterpret_cast<const float4*>(bias + c);
    float acc[4][4];
    #pragma unroll
    for (int i = 0; i < 4; i++) {
        acc[i][0] = bi4.x; acc[i][1] = bi4.y; acc[i][2] = bi4.z; acc[i][3] = bi4.w;
    }
    #pragma unroll
    for (int ky = 0; ky < 3; ky++) {
        int iy = py + (ky - 1) * DIL;
        if (iy < 0 || iy >= HH) continue;
        const ushortw* rowp = in + (size_t)(imgbase + (iy << 7)) * CIN_S + c;
        #pragma unroll
        for (int xx = 0; xx < NX; xx++) {
            int ix = px0 + xx - DIL;
            if (ix < 0 || ix >= WW) continue;
            short4v v = *reinterpret_cast<const short4v*>(rowp + (size_t)ix * CIN_S);
            float f0 = bf2f((ushortw)v[0]);
            float f1 = bf2f((ushortw)v[1]);
            float f2 = bf2f((ushortw)v[2]);
            float f3 = bf2f((ushortw)v[3]);
            #pragma unroll
            for (int kx = 0; kx < 3; kx++) {
                int i = xx - DIL * kx;   // which pixel of the quad uses this column
                if (i < 0 || i > 3) continue;
                float4 wv = w9[ky * 3 + kx];
                acc[i][0] = fmaf(f0, wv.x, acc[i][0]);
                acc[i][1] = fmaf(f1, wv.y, acc[i][1]);
                acc[i][2] = fmaf(f2, wv.z, acc[i][2]);
                acc[i][3] = fmaf(f3, wv.w, acc[i][3]);
            }
        }
    }
    if (COP != OSTR && c >= OSTR) return;   // fully-out channel group (180 % 4 == 0)
    #pragma unroll
    for (int i = 0; i < 4; i++) {
        #pragma unroll
        for (int e = 0; e < 4; e++) {
            float v = acc[i][e];
            if (ACT == 1) v = gelu_exact(v);
            else if (ACT == 2) v = fmaxf(v, 0.f);
            acc[i][e] = v;
        }
        if (OUTBF) {
            short4v o;
            o[0] = (short)f2bf(acc[i][0]); o[1] = (short)f2bf(acc[i][1]);
            o[2] = (short)f2bf(acc[i][2]); o[3] = (short)f2bf(acc[i][3]);
            *reinterpret_cast<short4v*>((ushortw*)out + (size_t)(pix0 + i) * OSTR + c) = o;
        } else {
            float4 o = make_float4(acc[i][0], acc[i][1], acc[i][2], acc[i][3]);
            *reinterpret_cast<float4*>((float*)out + (size_t)(pix0 + i) * OSTR + c) = o;
        }
    }
}

// ---------------- GAP partial sums over fp32 y4 ----------------
__global__ void gap_kernel(const float* __restrict__ y, float* __restrict__ part)
{
    int blk = blockIdx.x;
    int b = blk >> 5, chunk = blk & 31;
    int c = threadIdx.x;
    if (c >= CC) return;
    size_t basep = ((size_t)b * IMG + (size_t)chunk * 512) * CC;
    float s = 0.f;
    for (int p = 0; p < 512; p++) s += y[basep + (size_t)p * CC + c];
    part[((size_t)b * 32 + chunk) * CC + c] = s;
}

// ---------------- channel attention (tiny) ----------------
__global__ void ca_kernel(const float* __restrict__ part,
                          const float* __restrict__ w1, const float* __restrict__ b1,
                          const float* __restrict__ w2, const float* __restrict__ b2,
                          float* __restrict__ ca)
{
    __shared__ float gap[BB * CC];
    __shared__ float s1[BB * 6];
    int tid = threadIdx.x;
    for (int idx = tid; idx < BB * CC; idx += 256) {
        int b = idx / CC, c = idx % CC;
        float s = 0.f;
        for (int ch = 0; ch < 32; ch++) s += part[((size_t)b * 32 + ch) * CC + c];
        gap[idx] = s * (1.f / IMG);
    }
    __syncthreads();
    if (tid < BB * 6) {
        int b = tid / 6, cs = tid % 6;
        float s = 0.f;
        for (int c = 0; c < CC; c++) s += w1[cs * CC + c] * gap[b * CC + c];
        s1[tid] = fmaxf(s + b1[cs], 0.f);
    }
    __syncthreads();
    for (int idx = tid; idx < BB * CC; idx += 256) {
        int b = idx / CC, c = idx % CC;
        float s = b2[c];
        #pragma unroll
        for (int cs = 0; cs < 6; cs++) s += w2[c * 6 + cs] * s1[b * 6 + cs];
        ca[idx] = 1.f / (1.f + __expf(-s));
    }
}

// ---------------- x1 += 0.01*y4*ca (fp32, in place); LN2 -> bf16 xn2 (stride 192) ----------------
__global__ __launch_bounds__(256) void resid_ln_kernel(
    float* __restrict__ x1, const float* __restrict__ y4, const float* __restrict__ ca,
    const float* __restrict__ g, const float* __restrict__ bb,
    ushortw* __restrict__ xn2)
{
    int wid = threadIdx.x >> 6, lane = threadIdx.x & 63;
    int t = blockIdx.x * 4 + wid;
    int b = t >> 14;
    size_t off = (size_t)t * CC;
    size_t off2 = (size_t)t * 192;
    bool has2 = lane < (CC - 128);
    float v0 = x1[off+lane]    + 0.01f * y4[off+lane]    * ca[b*CC + lane];
    float v1 = x1[off+lane+64] + 0.01f * y4[off+lane+64] * ca[b*CC + lane+64];
    float v2 = 0.f;
    if (has2) v2 = x1[off+lane+128] + 0.01f * y4[off+lane+128] * ca[b*CC + lane+128];
    x1[off+lane] = v0; x1[off+lane+64] = v1;
    if (has2) x1[off+lane+128] = v2;
    float s = warp_sum(v0 + v1 + v2);
    float mu = s * (1.f / CC);
    float d0 = v0-mu, d1 = v1-mu, d2 = has2 ? v2-mu : 0.f;
    float var = warp_sum(d0*d0 + d1*d1 + d2*d2) * (1.f / CC);
    float rs = rsqrtf(var + 1e-5f);
    xn2[off2+lane]      = f2bf(d0 * rs * g[lane]      + bb[lane]);
    xn2[off2+lane+64]   = f2bf(d1 * rs * g[lane+64]   + bb[lane+64]);
    xn2[off2+lane+128]  = has2 ? f2bf(d2 * rs * g[lane+128] + bb[lane+128]) : (ushortw)0;
}

// ---------------- max/mean over channels per pixel (bf16 h3, stride 768, 720 cols) ----------------
__global__ __launch_bounds__(256) void mpap_kernel(
    const ushortw* __restrict__ h, float* __restrict__ mp, float* __restrict__ ap)
{
    int wid = threadIdx.x >> 6, lane = threadIdx.x & 63;
    int p = blockIdx.x * 4 + wid;
    const ushortw* row = h + (size_t)p * 768;
    float mx = -1e30f, s = 0.f;
    for (int j = lane; j < HID; j += 64) { float v = bf2f(row[j]); mx = fmaxf(mx, v); s += v; }
    mx = warp_max(mx); s = warp_sum(s);
    if (lane == 0) { mp[p] = mx; ap[p] = s * (1.f / HID); }
}

// ---------------- 7x7 spatial-attention conv + sigmoid (half batch = 2 images) ----------------
__global__ void saconv_kernel(const float* __restrict__ mp, const float* __restrict__ ap,
                              const float* __restrict__ w, float* __restrict__ sa)
{
    int p = blockIdx.x * blockDim.x + threadIdx.x;   // 0..HALFTOK-1
    int lp = p & (IMG - 1);
    int base = p - lp;
    int px = lp & (WW - 1), py = lp >> 7;
    float acc = 0.f;
    for (int ky = 0; ky < 7; ky++) {
        int iy = py + ky - 3;
        if (iy < 0 || iy >= HH) continue;
        for (int kx = 0; kx < 7; kx++) {
            int ix = px + kx - 3;
            if (ix < 0 || ix >= WW) continue;
            int pid = base + iy * WW + ix;
            acc += mp[pid] * w[ky * 7 + kx] + ap[pid] * w[49 + ky * 7 + kx];
        }
    }
    sa[p] = 1.f / (1.f + __expf(-acc));
}

extern "C" void kernel_launch(void* const* d_in, const int* in_sizes, int n_in,
                              void* d_out, int out_size, void* d_ws, size_t ws_size,
                              hipStream_t stream)
{
    const float* x      = (const float*)d_in[0];
    const int*   rpi    = (const int*)d_in[3];
    const float* n1g    = (const float*)d_in[4];
    const float* n1b    = (const float*)d_in[5];
    const float* rpb    = (const float*)d_in[6];
    const float* qkv_w  = (const float*)d_in[7];
    const float* qkv_b  = (const float*)d_in[8];
    const float* proj_w = (const float*)d_in[9];
    const float* proj_b = (const float*)d_in[10];
    const float* cab_w0 = (const float*)d_in[11];
    const float* cab_b0 = (const float*)d_in[12];
    const float* cab_w1 = (const float*)d_in[13];
    const float* cab_b1 = (const float*)d_in[14];
    const float* cab_w2 = (const float*)d_in[15];
    const float* cab_b2 = (const float*)d_in[16];
    const float* cab_w3 = (const float*)d_in[17];
    const float* cab_b3 = (const float*)d_in[18];
    const float* ca_w1  = (const float*)d_in[19];
    const float* ca_b1  = (const float*)d_in[20];
    const float* ca_w2  = (const float*)d_in[21];
    const float* ca_b2  = (const float*)d_in[22];
    const float* n2g    = (const float*)d_in[23];
    const float* n2b    = (const float*)d_in[24];
    const float* fc1_w  = (const float*)d_in[25];
    const float* fc1_b  = (const float*)d_in[26];
    const float* dw_w   = (const float*)d_in[27];
    const float* dw_b   = (const float*)d_in[28];
    const float* pw_w   = (const float*)d_in[29];
    const float* pw_b   = (const float*)d_in[30];
    const float* sa_w   = (const float*)d_in[31];
    const float* fc2_w  = (const float*)d_in[32];
    const float* fc2_b  = (const float*)d_in[33];
    float* outp = (float*)d_out;
    (void)in_sizes; (void)n_in; (void)out_size; (void)ws_size;

    char* ws = (char*)d_ws;
    const size_t S0 = (size_t)NTOK * 192 * 2;      // xnb -> xn2b
    const size_t S1 = (size_t)NTOK * QKVSTR * 2;   // qkvP -> y1b -> h1(half) -> h3(half)
    const size_t S2 = (size_t)NTOK * 192 * 2;      // attnbb -> y3b
    const size_t S3 = (size_t)NTOK * 180 * 4;      // x1 fp32 persistent
    const size_t S4 = (size_t)NTOK * 128 * 2;      // y2b ; h2(half) spans S4+S5
    const size_t S5 = (size_t)NTOK * 180 * 4;      // y4 fp32
    char* pA0 = ws;
    char* pA1 = pA0 + S0;
    char* pA2 = pA1 + S1;
    char* pA3 = pA2 + S2;
    char* pA4 = pA3 + S3;
    char* pA5 = pA4 + S4;
    char* tail = pA5 + S5;

    ushortw* xnb    = (ushortw*)pA0;           // [NTOK][192]
    ushortw* xn2b   = (ushortw*)pA0;
    ushortw* qkvP   = (ushortw*)pA1;           // [NTOK][576]
    ushortw* y1b    = (ushortw*)pA1;           // [NTOK][96]
    ushortw* h1     = (ushortw*)pA1;           // [HALFTOK][720]
    ushortw* h3     = (ushortw*)pA1;           // [HALFTOK][768]
    ushortw* attnbb = (ushortw*)pA2;           // [NTOK][192]
    ushortw* y3b    = (ushortw*)pA2;           // [NTOK][192]
    float*   x1     = (float*)pA3;             // [NTOK][180]
    ushortw* y2b    = (ushortw*)pA4;           // [NTOK][128]
    ushortw* h2     = (ushortw*)pA4;           // [HALFTOK][768] spans S4+S5
    float*   y4     = (float*)pA5;             // [NTOK][180]

    // bf16 gemm weights (padded)
    ushortw* wqkv  = (ushortw*)tail;                        // 640 x 192
    ushortw* wproj = wqkv  + 640 * 192;                     // 256 x 192
    ushortw* wcab0 = wproj + 256 * 192;                     // 128 x 192
    ushortw* wcab2 = wcab0 + 128 * 192;                     // 256 x 128
    ushortw* wfc1  = wcab2 + 256 * 128;                     // 768 x 192
    ushortw* wpw   = wfc1  + 768 * 192;                     // 768 x 768
    ushortw* wfc2  = wpw   + 768 * 768;                     // 256 x 768
    char* tail2 = (char*)(wfc2 + 256 * 768);
    float* dwt1 = (float*)tail2;                 float* db1 = dwt1 + 9*128;   // [9][128]+[128]
    float* dwt2 = db1 + 128;                     float* db2 = dwt2 + 9*192;   // [9][192]+[192]
    float* dwt3 = db2 + 192;                     float* db3 = dwt3 + 9*768;   // [9][768]+[768]
    char* tail3 = (char*)(db3 + 768);
    float* biasN = (float*)tail3;                           // 6*256*256
    float* part  = (float*)(tail3 + 1572864);
    float* cabuf = (float*)(tail3 + 1572864 + 98304);
    float* mp    = (float*)(tail3 + 1572864 + 131072);                          // [HALFTOK]
    float* ap    = (float*)(tail3 + 1572864 + 131072 + (size_t)HALFTOK * 4);    // [HALFTOK]
    float* sab   = (float*)(tail3 + 1572864 + 131072 + 2*(size_t)HALFTOK * 4);  // [HALFTOK]

    auto wc = [&](const float* src, ushortw* dst, int N, int K, int Np, int Kp) {
        wconv_kernel<<<dim3((Np * Kp + 255) / 256), dim3(256), 0, stream>>>(src, dst, N, K, Np, Kp);
    };
    auto gemm = [&](const ushortw* A, const ushortw* Wt, const float* bi, void* Cp,
                    int M, int N, int Kp, int ldc, int outbf, int zfill, int act, int qm,
                    const float* rs, const float* resid) {
        dim3 g((N + 127) / 128, M / 128);
        mgemm_kernel<<<g, dim3(256), 0, stream>>>(A, Wt, bi, Cp, M, N, Kp, ldc, outbf, zfill, act, qm, rs, resid);
    };

    // 0) weight prep
    wc(qkv_w, wqkv, 540, 180, 640, 192);
    wc(proj_w, wproj, 180, 180, 256, 192);
    wc(cab_w0, wcab0, 90, 180, 128, 192);
    wc(cab_w2, wcab2, 180, 90, 256, 128);
    wc(fc1_w, wfc1, 720, 180, 768, 192);
    wc(pw_w, wpw, 720, 720, 768, 768);
    wc(fc2_w, wfc2, 180, 720, 256, 768);
    dwt_kernel<<<dim3((128*9 + 255)/256), dim3(256), 0, stream>>>(cab_w1, cab_b1, dwt1, db1, 90, 128);
    dwt_kernel<<<dim3((192*9 + 255)/256), dim3(256), 0, stream>>>(cab_w3, cab_b3, dwt2, db2, 180, 192);
    dwt_kernel<<<dim3((768*9 + 255)/256), dim3(256), 0, stream>>>(dw_w, dw_b, dwt3, db3, 720, 768);

    // 1) LN1 -> bf16 xnb ; bias table (natural orientation)
    ln_kernel<<<dim3(NTOK / 4), dim3(256), 0, stream>>>(x, n1g, n1b, xnb);
    bias_kernel<<<dim3((NTOKW * NTOKW) / 256), dim3(256), 0, stream>>>(rpi, rpb, biasN);
    // 2) full-batch qkv (padded layout) + MFMA attention
    gemm(xnb, wqkv, qkv_b, qkvP, NTOK, 540, 192, QKVSTR, 1, 0, 0, 1, nullptr, nullptr);
    attn_mfma_kernel<<<dim3(BB * 64 * NHEADS), dim3(256), 0, stream>>>(qkvP, biasN, attnbb);
    // 3) CAB part 1 (xnb consumed)
    gemm(xnb, wcab0, cab_b0, y1b, NTOK, 90, 192, 96, 1, 1, 0, 0, nullptr, nullptr);
    dwconv4_kernel<96, 128, 128, 1, 1, 1><<<dim3(NTOK / 4 * 32 / 256), dim3(256), 0, stream>>>(
        y1b, dwt1, db1, y2b);
    // 4) proj with residual x -> x1
    gemm(attnbb, wproj, proj_b, x1, NTOK, 180, 192, 180, 0, 0, 0, 0, nullptr, x);
    // 5) CAB part 2
    gemm(y2b, wcab2, cab_b2, y3b, NTOK, 180, 128, 192, 1, 1, 0, 0, nullptr, nullptr);
    dwconv4_kernel<192, 192, 180, 2, 0, 0><<<dim3(NTOK / 4 * 48 / 256), dim3(256), 0, stream>>>(
        y3b, dwt2, db2, y4);
    gap_kernel<<<dim3(BB * 32), dim3(192), 0, stream>>>(y4, part);
    ca_kernel<<<dim3(1), dim3(256), 0, stream>>>(part, ca_w1, ca_b1, ca_w2, ca_b2, cabuf);
    // 6) x1 += 0.01*y4*ca; LN2 -> bf16 xn2b
    resid_ln_kernel<<<dim3(NTOK / 4), dim3(256), 0, stream>>>(x1, y4, cabuf, n2g, n2b, xn2b);
    // 7) FFN in two half-batches (2 images each)
    for (int half = 0; half < 2; half++) {
        size_t toff = (size_t)half * HALFTOK;
        gemm(xn2b + toff * 192, wfc1, fc1_b, h1, HALFTOK, 720, 192, 720, 1, 0, 1, 0, nullptr, nullptr);
        dwconv4_kernel<720, 768, 768, 1, 2, 1><<<dim3(HALFTOK / 4 * 192 / 256), dim3(256), 0, stream>>>(
            h1, dwt3, db3, h2);
        gemm(h2, wpw, pw_b, h3, HALFTOK, 720, 768, 768, 1, 1, 2, 0, nullptr, nullptr);
        mpap_kernel<<<dim3(HALFTOK / 4), dim3(256), 0, stream>>>(h3, mp, ap);
        saconv_kernel<<<dim3(HALFTOK / 256), dim3(256), 0, stream>>>(mp, ap, sa_w, sab);
        gemm(h3, wfc2, fc2_b, outp + toff * 180, HALFTOK, 180, 768, 180, 0, 0, 0, 0,
             sab, x1 + toff * 180);
    }
}

// Round 9
// 855.746 us; speedup vs baseline: 4.0700x; 1.0665x over previous
//
#include <hip/hip_runtime.h>
#include <math.h>

#define HH 128
#define WW 128
#define CC 180
#define BB 4
#define IMG (HH*WW)          // 16384 tokens per image
#define NTOK (BB*IMG)        // 65536
#define HALFTOK (2*IMG)      // 32768
#define NHEADS 6
#define HD 30
#define WSZ 16
#define NTOKW (WSZ*WSZ)      // 256
#define HID 720
#define QKVSTR 576           // padded qkv row: 3 sections x 6 heads x 32

typedef __attribute__((ext_vector_type(8))) short short8v;
typedef __attribute__((ext_vector_type(4))) short short4v;
typedef __attribute__((ext_vector_type(4))) float f32x4;
typedef unsigned short ushortw;

__device__ __forceinline__ float warp_sum(float v) {
    #pragma unroll
    for (int o = 32; o > 0; o >>= 1) v += __shfl_xor(v, o);
    return v;
}
__device__ __forceinline__ float warp_max(float v) {
    #pragma unroll
    for (int o = 32; o > 0; o >>= 1) v = fmaxf(v, __shfl_xor(v, o));
    return v;
}
__device__ __forceinline__ float gelu_exact(float v) {
    return 0.5f * v * (1.f + erff(v * 0.70710678118654752f));
}
__device__ __forceinline__ ushortw f2bf(float f) {
    union { float f; unsigned int u; } c; c.f = f;
    unsigned int r = (c.u + 0x7FFFu + ((c.u >> 16) & 1u)) >> 16;
    return (ushortw)r;
}
__device__ __forceinline__ float bf2f(ushortw u) {
    union { unsigned int u; float f; } c; c.u = ((unsigned int)u) << 16; return c.f;
}

// ---------------- weight fp32 -> bf16 with N/K padding (zeros) ----------------
__global__ void wconv_kernel(const float* __restrict__ src, ushortw* __restrict__ dst,
                             int N, int K, int Npad, int Kpad)
{
    int idx = blockIdx.x * blockDim.x + threadIdx.x;
    if (idx >= Npad * Kpad) return;
    int r = idx / Kpad, k = idx % Kpad;
    float v = (r < N && k < K) ? src[r * K + k] : 0.f;
    dst[idx] = f2bf(v);
}

// ---------------- dw weight transpose [C][9] -> [9][COP] (+ padded bias) ----------------
__global__ void dwt_kernel(const float* __restrict__ src, const float* __restrict__ bsrc,
                           float* __restrict__ dst, float* __restrict__ bdst,
                           int C, int COP)
{
    int idx = blockIdx.x * blockDim.x + threadIdx.x;
    if (idx >= COP * 9) return;
    int c = idx / 9, k = idx - c * 9;
    dst[k * COP + c] = (c < C) ? src[c * 9 + k] : 0.f;
    if (k == 0) bdst[c] = (c < C) ? bsrc[c] : 0.f;
}

// ---------------- LayerNorm -> bf16 out, stride 192 (cols 180..191 zero) ----------------
__global__ __launch_bounds__(256) void ln_kernel(
    const float* __restrict__ x, const float* __restrict__ g,
    const float* __restrict__ b, ushortw* __restrict__ out)
{
    int wid = threadIdx.x >> 6, lane = threadIdx.x & 63;
    int t = blockIdx.x * 4 + wid;
    size_t off = (size_t)t * CC;
    size_t off2 = (size_t)t * 192;
    bool has2 = lane < (CC - 128);
    float v0 = x[off + lane];
    float v1 = x[off + lane + 64];
    float v2 = has2 ? x[off + lane + 128] : 0.f;
    float s = warp_sum(v0 + v1 + v2);
    float mu = s * (1.f / CC);
    float d0 = v0 - mu, d1 = v1 - mu, d2 = has2 ? v2 - mu : 0.f;
    float var = warp_sum(d0*d0 + d1*d1 + d2*d2) * (1.f / CC);
    float rs = rsqrtf(var + 1e-5f);
    out[off2 + lane]      = f2bf(d0 * rs * g[lane]      + b[lane]);
    out[off2 + lane + 64] = f2bf(d1 * rs * g[lane + 64] + b[lane + 64]);
    out[off2 + lane + 128] = has2 ? f2bf(d2 * rs * g[lane + 128] + b[lane + 128]) : (ushortw)0;
}

// ---------------- relative position bias, natural [h][i*256+j] ----------------
__global__ void bias_kernel(const int* __restrict__ rpi, const float* __restrict__ rpb,
                            float* __restrict__ biasN)
{
    int idx = blockIdx.x * blockDim.x + threadIdx.x;
    if (idx >= NTOKW * NTOKW) return;
    int r = rpi[idx];
    #pragma unroll
    for (int h = 0; h < NHEADS; h++)
        biasN[((size_t)h << 16) + idx] = rpb[r * NHEADS + h];
}

// ---------------- bf16 MFMA GEMM, m97 structure + XCD-aware bijective swizzle ----------------
// 1D grid of nM*nN blocks; each XCD gets a contiguous M-panel-major chunk (T1/m204).
__global__ __launch_bounds__(256) void mgemm_kernel(
    const ushortw* __restrict__ A, const ushortw* __restrict__ Wt,
    const float* __restrict__ bias, void* __restrict__ Cout,
    int M, int N, int Kp, int ldc, int outbf, int zfill, int act, int qkvmode, int nN,
    const float* __restrict__ rowscale, const float* __restrict__ resid)
{
    __shared__ ushortw sA[128 * 64];
    __shared__ ushortw sB[128 * 64];
    int tid = threadIdx.x, lane = tid & 63, wid = tid >> 6;
    // --- XCD-aware bijective remap (m204): contiguous wgid chunk per XCD ---
    int total = (int)gridDim.x;
    int orig = blockIdx.x;
    int q = total >> 3, r = total & 7;
    int xcd = orig & 7, slot = orig >> 3;
    int wgid = (xcd < r ? xcd * (q + 1) : r * (q + 1) + (xcd - r) * q) + slot;
    int mp = wgid / nN, np = wgid - mp * nN;
    int m0 = mp << 7, n0 = np << 7;
    int wm = (wid >> 1) << 6, wn = (wid & 1) << 6;
    int lrow = lane & 15, kgrp = lane >> 4;

    f32x4 acc[4][4];
    #pragma unroll
    for (int i = 0; i < 4; i++)
        #pragma unroll
        for (int j = 0; j < 4; j++)
            #pragma unroll
            for (int rr = 0; rr < 4; rr++) acc[i][j][rr] = 0.f;

    int nk = Kp >> 6;
    for (int t = 0; t < nk; t++) {
        int kk = t << 6;
        #pragma unroll
        for (int qq = 0; qq < 4; qq++) {
            int seg = (wid << 2) + qq;                // 0..15
            int row = (seg << 3) + (lane >> 3);       // 0..127
            int cg = (lane & 7) ^ (row & 7);          // swizzled global chunk
            const ushortw* ga = A + (size_t)(m0 + row) * Kp + kk + (cg << 3);
            __builtin_amdgcn_global_load_lds(
                (const __attribute__((address_space(1))) void*)ga,
                (__attribute__((address_space(3))) void*)&sA[seg << 9], 16, 0, 0);
            const ushortw* gb = Wt + (size_t)(n0 + row) * Kp + kk + (cg << 3);
            __builtin_amdgcn_global_load_lds(
                (const __attribute__((address_space(1))) void*)gb,
                (__attribute__((address_space(3))) void*)&sB[seg << 9], 16, 0, 0);
        }
        __syncthreads();
        short8v a[4][2], b[4][2];
        #pragma unroll
        for (int i = 0; i < 4; i++) {
            int rr = wm + (i << 4) + lrow;
            #pragma unroll
            for (int s = 0; s < 2; s++) {
                int slot2 = ((s << 2) + kgrp) ^ (rr & 7);
                a[i][s] = *reinterpret_cast<const short8v*>(&sA[(rr << 6) + (slot2 << 3)]);
            }
        }
        #pragma unroll
        for (int j = 0; j < 4; j++) {
            int rr = wn + (j << 4) + lrow;
            #pragma unroll
            for (int s = 0; s < 2; s++) {
                int slot2 = ((s << 2) + kgrp) ^ (rr & 7);
                b[j][s] = *reinterpret_cast<const short8v*>(&sB[(rr << 6) + (slot2 << 3)]);
            }
        }
        #pragma unroll
        for (int i = 0; i < 4; i++)
            #pragma unroll
            for (int j = 0; j < 4; j++) {
                acc[i][j] = __builtin_amdgcn_mfma_f32_16x16x32_bf16(a[i][0], b[j][0], acc[i][j], 0, 0, 0);
                acc[i][j] = __builtin_amdgcn_mfma_f32_16x16x32_bf16(a[i][1], b[j][1], acc[i][j], 0, 0, 0);
            }
        __syncthreads();
    }
    #pragma unroll
    for (int i = 0; i < 4; i++) {
        int rowb = m0 + wm + (i << 4) + (kgrp << 2);
        #pragma unroll
        for (int j = 0; j < 4; j++) {
            int col = n0 + wn + (j << 4) + lrow;
            if (qkvmode) {
                if (col < N) {
                    int sub = (col >= 360) ? 2 : (col >= 180 ? 1 : 0);
                    int rem = col - sub * 180;
                    int hh = rem / 30;
                    int dd = rem - hh * 30;
                    int col2 = sub * 192 + hh * 32 + dd;
                    float bi = bias[col];
                    #pragma unroll
                    for (int rr = 0; rr < 4; rr++) {
                        int row = rowb + rr;
                        ((ushortw*)Cout)[(size_t)row * QKVSTR + col2] = f2bf(acc[i][j][rr] + bi);
                    }
                }
                continue;
            }
            if (col < N) {
                float bi = bias[col];
                #pragma unroll
                for (int rr = 0; rr < 4; rr++) {
                    int row = rowb + rr;
                    float v = acc[i][j][rr];
                    if (rowscale) v *= rowscale[row];
                    v += bi;
                    if (act == 1) v = gelu_exact(v);
                    else if (act == 2) v = fmaxf(v, 0.f);
                    if (resid) v += resid[(size_t)row * N + col];
                    if (outbf) ((ushortw*)Cout)[(size_t)row * ldc + col] = f2bf(v);
                    else       ((float*)Cout)[(size_t)row * ldc + col] = v;
                }
            } else if (zfill && col < ldc) {
                #pragma unroll
                for (int rr = 0; rr < 4; rr++) {
                    int row = rowb + rr;
                    if (outbf) ((ushortw*)Cout)[(size_t)row * ldc + col] = 0;
                    else       ((float*)Cout)[(size_t)row * ldc + col] = 0.f;
                }
            }
        }
    }
}

// ---------------- MFMA window attention (swapped QK^T): block = (img, win, head) ----------------
__global__ __launch_bounds__(256, 3) void attn_mfma_kernel(
    const ushortw* __restrict__ qkvP, const float* __restrict__ biasN,
    ushortw* __restrict__ out)
{
    __shared__ ushortw Vc[32 * 33 * 8];      // [kc][33 d-slots][8] : 16896 B
    __shared__ ushortw Kc[256 * 32];         // [k-row][32 d], chunk-XOR swizzled : 16384 B
    __shared__ ushortw Pl[4][2048];          // per-wave [16 q][128 k] bf16, XOR-swizzled : 16384 B
    const float SCALE = 0.18257418583505536f;   // 30^-0.5
    int blk = blockIdx.x;
    int img = blk / 384;
    int rem = blk - img * 384;
    int win = rem / NHEADS;
    int h = rem - win * NHEADS;
    int base = img * IMG + (win >> 3) * WSZ * WW + (win & 7) * WSZ;
    int tid = threadIdx.x;
    int lane = tid & 63, w = tid >> 6;
    int a15 = lane & 15, kg = lane >> 4;

    {
        int j = tid;
        int g = base + (j >> 4) * WW + (j & 15);
        const ushortw* vp = qkvP + (size_t)g * QKVSTR + 384 + h * 32;
        short8v c0 = *reinterpret_cast<const short8v*>(vp);
        short8v c1 = *reinterpret_cast<const short8v*>(vp + 8);
        short8v c2 = *reinterpret_cast<const short8v*>(vp + 16);
        short8v c3 = *reinterpret_cast<const short8v*>(vp + 24);
        int bo = (j >> 3) * 264 + (j & 7);
        #pragma unroll
        for (int e = 0; e < 8; e++)  Vc[bo + (e) * 8]      = (ushortw)c0[e];
        #pragma unroll
        for (int e = 0; e < 8; e++)  Vc[bo + (8 + e) * 8]  = (ushortw)c1[e];
        #pragma unroll
        for (int e = 0; e < 8; e++)  Vc[bo + (16 + e) * 8] = (ushortw)c2[e];
        #pragma unroll
        for (int e = 0; e < 6; e++)  Vc[bo + (24 + e) * 8] = (ushortw)c3[e];
        // K row j
        const ushortw* kp = qkvP + (size_t)g * QKVSTR + 192 + h * 32;
        short8v k0 = *reinterpret_cast<const short8v*>(kp);
        short8v k1 = *reinterpret_cast<const short8v*>(kp + 8);
        short8v k2 = *reinterpret_cast<const short8v*>(kp + 16);
        short8v k3 = *reinterpret_cast<const short8v*>(kp + 24);
        k3[6] = 0; k3[7] = 0;
        short8v* krow = reinterpret_cast<short8v*>(&Kc[j * 32]);
        int jsw = j & 3;
        krow[0 ^ jsw] = k0; krow[1 ^ jsw] = k1; krow[2 ^ jsw] = k2; krow[3 ^ jsw] = k3;
    }
    __syncthreads();

    ushortw* Pw = &Pl[w][0];
    int xsw = (a15 & 7) << 2;                // P dword-XOR per q-row
    f32x4 zf = {0.f, 0.f, 0.f, 0.f};
    #pragma unroll 1
    for (int si = 0; si < 4; si++) {
        int strip = (w << 2) + si;
        short8v qf = *reinterpret_cast<const short8v*>(
            qkvP + (size_t)(base + strip * WW + a15) * QKVSTR + h * 32 + (kg << 3));
        if (kg == 3) { qf[6] = 0; qf[7] = 0; }
        float psum = 0.f;
        f32x4 o0 = zf, o1 = zf;
        const float* brow = biasN + ((size_t)h << 16) + (size_t)((strip << 4) + a15) * 256;
        #pragma unroll 1
        for (int half = 0; half < 2; half++) {
            f32x4 s[8];
            #pragma unroll
            for (int j8 = 0; j8 < 8; j8++) {
                int jt = (half << 3) + j8;
                int row = (jt << 4) + a15;
                short8v ka = reinterpret_cast<const short8v*>(&Kc[row * 32])[kg ^ (row & 3)];
                s[j8] = __builtin_amdgcn_mfma_f32_16x16x32_bf16(ka, qf, zf, 0, 0, 0);
            }
            #pragma unroll
            for (int j8 = 0; j8 < 8; j8++) {
                int jt = (half << 3) + j8;
                float4 b4 = *reinterpret_cast<const float4*>(brow + (jt << 4) + (kg << 2));
                float p0 = __expf(fmaf(s[j8][0], SCALE, b4.x));
                float p1 = __expf(fmaf(s[j8][1], SCALE, b4.y));
                float p2 = __expf(fmaf(s[j8][2], SCALE, b4.z));
                float p3 = __expf(fmaf(s[j8][3], SCALE, b4.w));
                psum += (p0 + p1) + (p2 + p3);
                unsigned int u0, u1;
                asm("v_cvt_pk_bf16_f32 %0, %1, %2" : "=v"(u0) : "v"(p0), "v"(p1));
                asm("v_cvt_pk_bf16_f32 %0, %1, %2" : "=v"(u1) : "v"(p2), "v"(p3));
                int dw0 = ((j8 << 3) + (kg << 1)) ^ xsw;
                unsigned long long pk64 = (unsigned long long)u0 | ((unsigned long long)u1 << 32);
                *reinterpret_cast<unsigned long long*>(&Pw[(a15 << 7) + (dw0 << 1)]) = pk64;
            }
            __builtin_amdgcn_sched_barrier(0);
            #pragma unroll
            for (int ks4 = 0; ks4 < 4; ks4++) {
                int dwr = ((ks4 << 4) + (kg << 2)) ^ xsw;
                short8v pa = *reinterpret_cast<const short8v*>(&Pw[(a15 << 7) + (dwr << 1)]);
                int kc = (((half << 2) + ks4) << 2) + kg;
                short8v v0 = *reinterpret_cast<const short8v*>(&Vc[(kc * 33 + a15) * 8]);
                short8v v1 = *reinterpret_cast<const short8v*>(&Vc[(kc * 33 + 16 + a15) * 8]);
                o0 = __builtin_amdgcn_mfma_f32_16x16x32_bf16(pa, v0, o0, 0, 0, 0);
                o1 = __builtin_amdgcn_mfma_f32_16x16x32_bf16(pa, v1, o1, 0, 0, 0);
            }
            __builtin_amdgcn_sched_barrier(0);
        }
        psum += __shfl_xor(psum, 16);
        psum += __shfl_xor(psum, 32);
        #pragma unroll
        for (int r = 0; r < 4; r++) {
            float pt = __shfl(psum, (kg << 2) + r);
            float inv = 1.f / pt;
            int g = base + strip * WW + (kg << 2) + r;
            ushortw* orow = out + (size_t)g * 192 + h * HD;
            orow[a15] = f2bf(o0[r] * inv);
            if (a15 < 14) orow[16 + a15] = f2bf(o1[r] * inv);
        }
    }
    if (h == 0) {   // zero pad cols 180..191
        for (int idx2 = tid; idx2 < NTOKW * 12; idx2 += 256) {
            int j = idx2 / 12, d = idx2 - (idx2 / 12) * 12;
            int gj = base + (j >> 4) * WW + (j & 15);
            out[(size_t)gj * 192 + 180 + d] = 0;
        }
    }
}

// ---------------- register-tiled depthwise 3x3 conv: 4 pixels x 4 channels / thread ----------------
template<int CIN_S, int COP, int OSTR, int DIL, int ACT, int OUTBF>
__global__ __launch_bounds__(256) void dwconv4_kernel(
    const ushortw* __restrict__ in, const float* __restrict__ wt,
    const float* __restrict__ bias, void* __restrict__ out)
{
    constexpr int NC4 = COP >> 2;
    constexpr int NX = 4 + 2 * DIL;
    int idx = blockIdx.x * 256 + threadIdx.x;
    int c4 = idx % NC4;
    int quad = idx / NC4;
    int c = c4 << 2;
    int pix0 = quad << 2;
    int p = pix0 & (IMG - 1);
    int imgbase = pix0 - p;
    int px0 = p & (WW - 1), py = p >> 7;

    float4 w9[9];
    #pragma unroll
    for (int t = 0; t < 9; t++)
        w9[t] = *reinterpret_cast<const float4*>(wt + t * COP + c);
    float4 bi4 = *reinterpret_cast<const float4*>(bias + c);
    float acc[4][4];
    #pragma unroll
    for (int i = 0; i < 4; i++) {
        acc[i][0] = bi4.x; acc[i][1] = bi4.y; acc[i][2] = bi4.z; acc[i][3] = bi4.w;
    }
    #pragma unroll
    for (int ky = 0; ky < 3; ky++) {
        int iy = py + (ky - 1) * DIL;
        if (iy < 0 || iy >= HH) continue;
        const ushortw* rowp = in + (size_t)(imgbase + (iy << 7)) * CIN_S + c;
        #pragma unroll
        for (int xx = 0; xx < NX; xx++) {
            int ix = px0 + xx - DIL;
            if (ix < 0 || ix >= WW) continue;
            short4v v = *reinterpret_cast<const short4v*>(rowp + (size_t)ix * CIN_S);
            float f0 = bf2f((ushortw)v[0]);
            float f1 = bf2f((ushortw)v[1]);
            float f2 = bf2f((ushortw)v[2]);
            float f3 = bf2f((ushortw)v[3]);
            #pragma unroll
            for (int kx = 0; kx < 3; kx++) {
                int i = xx - DIL * kx;   // which pixel of the quad uses this column
                if (i < 0 || i > 3) continue;
                float4 wv = w9[ky * 3 + kx];
                acc[i][0] = fmaf(f0, wv.x, acc[i][0]);
                acc[i][1] = fmaf(f1, wv.y, acc[i][1]);
                acc[i][2] = fmaf(f2, wv.z, acc[i][2]);
                acc[i][3] = fmaf(f3, wv.w, acc[i][3]);
            }
        }
    }
    if (COP != OSTR && c >= OSTR) return;   // fully-out channel group (180 % 4 == 0)
    #pragma unroll
    for (int i = 0; i < 4; i++) {
        #pragma unroll
        for (int e = 0; e < 4; e++) {
            float v = acc[i][e];
            if (ACT == 1) v = gelu_exact(v);
            else if (ACT == 2) v = fmaxf(v, 0.f);
            acc[i][e] = v;
        }
        if (OUTBF) {
            short4v o;
            o[0] = (short)f2bf(acc[i][0]); o[1] = (short)f2bf(acc[i][1]);
            o[2] = (short)f2bf(acc[i][2]); o[3] = (short)f2bf(acc[i][3]);
            *reinterpret_cast<short4v*>((ushortw*)out + (size_t)(pix0 + i) * OSTR + c) = o;
        } else {
            float4 o = make_float4(acc[i][0], acc[i][1], acc[i][2], acc[i][3]);
            *reinterpret_cast<float4*>((float*)out + (size_t)(pix0 + i) * OSTR + c) = o;
        }
    }
}

// ---------------- GAP partial sums over bf16 y4 ----------------
__global__ void gap_kernel(const ushortw* __restrict__ y, float* __restrict__ part)
{
    int blk = blockIdx.x;
    int b = blk >> 5, chunk = blk & 31;
    int c = threadIdx.x;
    if (c >= CC) return;
    size_t basep = ((size_t)b * IMG + (size_t)chunk * 512) * CC;
    float s = 0.f;
    for (int p = 0; p < 512; p++) s += bf2f(y[basep + (size_t)p * CC + c]);
    part[((size_t)b * 32 + chunk) * CC + c] = s;
}

// ---------------- channel attention (tiny) ----------------
__global__ void ca_kernel(const float* __restrict__ part,
                          const float* __restrict__ w1, const float* __restrict__ b1,
                          const float* __restrict__ w2, const float* __restrict__ b2,
                          float* __restrict__ ca)
{
    __shared__ float gap[BB * CC];
    __shared__ float s1[BB * 6];
    int tid = threadIdx.x;
    for (int idx = tid; idx < BB * CC; idx += 256) {
        int b = idx / CC, c = idx % CC;
        float s = 0.f;
        for (int ch = 0; ch < 32; ch++) s += part[((size_t)b * 32 + ch) * CC + c];
        gap[idx] = s * (1.f / IMG);
    }
    __syncthreads();
    if (tid < BB * 6) {
        int b = tid / 6, cs = tid % 6;
        float s = 0.f;
        for (int c = 0; c < CC; c++) s += w1[cs * CC + c] * gap[b * CC + c];
        s1[tid] = fmaxf(s + b1[cs], 0.f);
    }
    __syncthreads();
    for (int idx = tid; idx < BB * CC; idx += 256) {
        int b = idx / CC, c = idx % CC;
        float s = b2[c];
        #pragma unroll
        for (int cs = 0; cs < 6; cs++) s += w2[c * 6 + cs] * s1[b * 6 + cs];
        ca[idx] = 1.f / (1.f + __expf(-s));
    }
}

// ---------------- x1 += 0.01*y4*ca (y4 bf16); LN2 -> bf16 xn2 (stride 192) ----------------
__global__ __launch_bounds__(256) void resid_ln_kernel(
    float* __restrict__ x1, const ushortw* __restrict__ y4, const float* __restrict__ ca,
    const float* __restrict__ g, const float* __restrict__ bb,
    ushortw* __restrict__ xn2)
{
    int wid = threadIdx.x >> 6, lane = threadIdx.x & 63;
    int t = blockIdx.x * 4 + wid;
    int b = t >> 14;
    size_t off = (size_t)t * CC;
    size_t off2 = (size_t)t * 192;
    bool has2 = lane < (CC - 128);
    float v0 = x1[off+lane]    + 0.01f * bf2f(y4[off+lane])    * ca[b*CC + lane];
    float v1 = x1[off+lane+64] + 0.01f * bf2f(y4[off+lane+64]) * ca[b*CC + lane+64];
    float v2 = 0.f;
    if (has2) v2 = x1[off+lane+128] + 0.01f * bf2f(y4[off+lane+128]) * ca[b*CC + lane+128];
    x1[off+lane] = v0; x1[off+lane+64] = v1;
    if (has2) x1[off+lane+128] = v2;
    float s = warp_sum(v0 + v1 + v2);
    float mu = s * (1.f / CC);
    float d0 = v0-mu, d1 = v1-mu, d2 = has2 ? v2-mu : 0.f;
    float var = warp_sum(d0*d0 + d1*d1 + d2*d2) * (1.f / CC);
    float rs = rsqrtf(var + 1e-5f);
    xn2[off2+lane]      = f2bf(d0 * rs * g[lane]      + bb[lane]);
    xn2[off2+lane+64]   = f2bf(d1 * rs * g[lane+64]   + bb[lane+64]);
    xn2[off2+lane+128]  = has2 ? f2bf(d2 * rs * g[lane+128] + bb[lane+128]) : (ushortw)0;
}

// ---------------- max/mean over channels per pixel (bf16 h3, stride 768, 720 cols) ----------------
__global__ __launch_bounds__(256) void mpap_kernel(
    const ushortw* __restrict__ h, float* __restrict__ mp, float* __restrict__ ap)
{
    int wid = threadIdx.x >> 6, lane = threadIdx.x & 63;
    int p = blockIdx.x * 4 + wid;
    const ushortw* row = h + (size_t)p * 768;
    float mx = -1e30f, s = 0.f;
    for (int j = lane; j < HID; j += 64) { float v = bf2f(row[j]); mx = fmaxf(mx, v); s += v; }
    mx = warp_max(mx); s = warp_sum(s);
    if (lane == 0) { mp[p] = mx; ap[p] = s * (1.f / HID); }
}

// ---------------- 7x7 spatial-attention conv + sigmoid (half batch = 2 images) ----------------
__global__ void saconv_kernel(const float* __restrict__ mp, const float* __restrict__ ap,
                              const float* __restrict__ w, float* __restrict__ sa)
{
    int p = blockIdx.x * blockDim.x + threadIdx.x;   // 0..HALFTOK-1
    int lp = p & (IMG - 1);
    int base = p - lp;
    int px = lp & (WW - 1), py = lp >> 7;
    float acc = 0.f;
    for (int ky = 0; ky < 7; ky++) {
        int iy = py + ky - 3;
        if (iy < 0 || iy >= HH) continue;
        for (int kx = 0; kx < 7; kx++) {
            int ix = px + kx - 3;
            if (ix < 0 || ix >= WW) continue;
            int pid = base + iy * WW + ix;
            acc += mp[pid] * w[ky * 7 + kx] + ap[pid] * w[49 + ky * 7 + kx];
        }
    }
    sa[p] = 1.f / (1.f + __expf(-acc));
}

extern "C" void kernel_launch(void* const* d_in, const int* in_sizes, int n_in,
                              void* d_out, int out_size, void* d_ws, size_t ws_size,
                              hipStream_t stream)
{
    const float* x      = (const float*)d_in[0];
    const int*   rpi    = (const int*)d_in[3];
    const float* n1g    = (const float*)d_in[4];
    const float* n1b    = (const float*)d_in[5];
    const float* rpb    = (const float*)d_in[6];
    const float* qkv_w  = (const float*)d_in[7];
    const float* qkv_b  = (const float*)d_in[8];
    const float* proj_w = (const float*)d_in[9];
    const float* proj_b = (const float*)d_in[10];
    const float* cab_w0 = (const float*)d_in[11];
    const float* cab_b0 = (const float*)d_in[12];
    const float* cab_w1 = (const float*)d_in[13];
    const float* cab_b1 = (const float*)d_in[14];
    const float* cab_w2 = (const float*)d_in[15];
    const float* cab_b2 = (const float*)d_in[16];
    const float* cab_w3 = (const float*)d_in[17];
    const float* cab_b3 = (const float*)d_in[18];
    const float* ca_w1  = (const float*)d_in[19];
    const float* ca_b1  = (const float*)d_in[20];
    const float* ca_w2  = (const float*)d_in[21];
    const float* ca_b2  = (const float*)d_in[22];
    const float* n2g    = (const float*)d_in[23];
    const float* n2b    = (const float*)d_in[24];
    const float* fc1_w  = (const float*)d_in[25];
    const float* fc1_b  = (const float*)d_in[26];
    const float* dw_w   = (const float*)d_in[27];
    const float* dw_b   = (const float*)d_in[28];
    const float* pw_w   = (const float*)d_in[29];
    const float* pw_b   = (const float*)d_in[30];
    const float* sa_w   = (const float*)d_in[31];
    const float* fc2_w  = (const float*)d_in[32];
    const float* fc2_b  = (const float*)d_in[33];
    float* outp = (float*)d_out;
    (void)in_sizes; (void)n_in; (void)out_size; (void)ws_size;

    char* ws = (char*)d_ws;
    const size_t S0 = (size_t)NTOK * 192 * 2;      // xnb -> xn2b
    const size_t S1 = (size_t)NTOK * QKVSTR * 2;   // qkvP -> y1b -> h1(half) -> h3(half)
    const size_t S2 = (size_t)NTOK * 192 * 2;      // attnbb -> y3b
    const size_t S3 = (size_t)NTOK * 180 * 4;      // x1 fp32 persistent
    const size_t S4 = (size_t)NTOK * 128 * 2;      // y2b ; h2(half) spans S4+S5
    const size_t S5 = (size_t)NTOK * 180 * 4;      // y4 (bf16, region kept fp32-sized for h2 span)
    char* pA0 = ws;
    char* pA1 = pA0 + S0;
    char* pA2 = pA1 + S1;
    char* pA3 = pA2 + S2;
    char* pA4 = pA3 + S3;
    char* pA5 = pA4 + S4;
    char* tail = pA5 + S5;

    ushortw* xnb    = (ushortw*)pA0;           // [NTOK][192]
    ushortw* xn2b   = (ushortw*)pA0;
    ushortw* qkvP   = (ushortw*)pA1;           // [NTOK][576]
    ushortw* y1b    = (ushortw*)pA1;           // [NTOK][96]
    ushortw* h1     = (ushortw*)pA1;           // [HALFTOK][720]
    ushortw* h3     = (ushortw*)pA1;           // [HALFTOK][768]
    ushortw* attnbb = (ushortw*)pA2;           // [NTOK][192]
    ushortw* y3b    = (ushortw*)pA2;           // [NTOK][192]
    float*   x1     = (float*)pA3;             // [NTOK][180]
    ushortw* y2b    = (ushortw*)pA4;           // [NTOK][128]
    ushortw* h2     = (ushortw*)pA4;           // [HALFTOK][768] spans S4+S5
    ushortw* y4     = (ushortw*)pA5;           // [NTOK][180] bf16

    // bf16 gemm weights (padded)
    ushortw* wqkv  = (ushortw*)tail;                        // 640 x 192
    ushortw* wproj = wqkv  + 640 * 192;                     // 256 x 192
    ushortw* wcab0 = wproj + 256 * 192;                     // 128 x 192
    ushortw* wcab2 = wcab0 + 128 * 192;                     // 256 x 128
    ushortw* wfc1  = wcab2 + 256 * 128;                     // 768 x 192
    ushortw* wpw   = wfc1  + 768 * 192;                     // 768 x 768
    ushortw* wfc2  = wpw   + 768 * 768;                     // 256 x 768
    char* tail2 = (char*)(wfc2 + 256 * 768);
    float* dwt1 = (float*)tail2;                 float* db1 = dwt1 + 9*128;   // [9][128]+[128]
    float* dwt2 = db1 + 128;                     float* db2 = dwt2 + 9*192;   // [9][192]+[192]
    float* dwt3 = db2 + 192;                     float* db3 = dwt3 + 9*768;   // [9][768]+[768]
    char* tail3 = (char*)(db3 + 768);
    float* biasN = (float*)tail3;                           // 6*256*256
    float* part  = (float*)(tail3 + 1572864);
    float* cabuf = (float*)(tail3 + 1572864 + 98304);
    float* mp    = (float*)(tail3 + 1572864 + 131072);                          // [HALFTOK]
    float* ap    = (float*)(tail3 + 1572864 + 131072 + (size_t)HALFTOK * 4);    // [HALFTOK]
    float* sab   = (float*)(tail3 + 1572864 + 131072 + 2*(size_t)HALFTOK * 4);  // [HALFTOK]

    auto wc = [&](const float* src, ushortw* dst, int N, int K, int Np, int Kp) {
        wconv_kernel<<<dim3((Np * Kp + 255) / 256), dim3(256), 0, stream>>>(src, dst, N, K, Np, Kp);
    };
    auto gemm = [&](const ushortw* A, const ushortw* Wt, const float* bi, void* Cp,
                    int M, int N, int Kp, int ldc, int outbf, int zfill, int act, int qm,
                    const float* rs, const float* resid) {
        int nM = M >> 7, nN = (N + 127) >> 7;
        mgemm_kernel<<<dim3(nM * nN), dim3(256), 0, stream>>>(
            A, Wt, bi, Cp, M, N, Kp, ldc, outbf, zfill, act, qm, nN, rs, resid);
    };

    // 0) weight prep
    wc(qkv_w, wqkv, 540, 180, 640, 192);
    wc(proj_w, wproj, 180, 180, 256, 192);
    wc(cab_w0, wcab0, 90, 180, 128, 192);
    wc(cab_w2, wcab2, 180, 90, 256, 128);
    wc(fc1_w, wfc1, 720, 180, 768, 192);
    wc(pw_w, wpw, 720, 720, 768, 768);
    wc(fc2_w, wfc2, 180, 720, 256, 768);
    dwt_kernel<<<dim3((128*9 + 255)/256), dim3(256), 0, stream>>>(cab_w1, cab_b1, dwt1, db1, 90, 128);
    dwt_kernel<<<dim3((192*9 + 255)/256), dim3(256), 0, stream>>>(cab_w3, cab_b3, dwt2, db2, 180, 192);
    dwt_kernel<<<dim3((768*9 + 255)/256), dim3(256), 0, stream>>>(dw_w, dw_b, dwt3, db3, 720, 768);

    // 1) LN1 -> bf16 xnb ; bias table (natural orientation)
    ln_kernel<<<dim3(NTOK / 4), dim3(256), 0, stream>>>(x, n1g, n1b, xnb);
    bias_kernel<<<dim3((NTOKW * NTOKW) / 256), dim3(256), 0, stream>>>(rpi, rpb, biasN);
    // 2) full-batch qkv (padded layout) + MFMA attention
    gemm(xnb, wqkv, qkv_b, qkvP, NTOK, 540, 192, QKVSTR, 1, 0, 0, 1, nullptr, nullptr);
    attn_mfma_kernel<<<dim3(BB * 64 * NHEADS), dim3(256), 0, stream>>>(qkvP, biasN, attnbb);
    // 3) CAB part 1 (xnb consumed)
    gemm(xnb, wcab0, cab_b0, y1b, NTOK, 90, 192, 96, 1, 1, 0, 0, nullptr, nullptr);
    dwconv4_kernel<96, 128, 128, 1, 1, 1><<<dim3(NTOK / 4 * 32 / 256), dim3(256), 0, stream>>>(
        y1b, dwt1, db1, y2b);
    // 4) proj with residual x -> x1
    gemm(attnbb, wproj, proj_b, x1, NTOK, 180, 192, 180, 0, 0, 0, 0, nullptr, x);
    // 5) CAB part 2
    gemm(y2b, wcab2, cab_b2, y3b, NTOK, 180, 128, 192, 1, 1, 0, 0, nullptr, nullptr);
    dwconv4_kernel<192, 192, 180, 2, 0, 1><<<dim3(NTOK / 4 * 48 / 256), dim3(256), 0, stream>>>(
        y3b, dwt2, db2, y4);
    gap_kernel<<<dim3(BB * 32), dim3(192), 0, stream>>>(y4, part);
    ca_kernel<<<dim3(1), dim3(256), 0, stream>>>(part, ca_w1, ca_b1, ca_w2, ca_b2, cabuf);
    // 6) x1 += 0.01*y4*ca; LN2 -> bf16 xn2b
    resid_ln_kernel<<<dim3(NTOK / 4), dim3(256), 0, stream>>>(x1, y4, cabuf, n2g, n2b, xn2b);
    // 7) FFN in two half-batches (2 images each)
    for (int half = 0; half < 2; half++) {
        size_t toff = (size_t)half * HALFTOK;
        gemm(xn2b + toff * 192, wfc1, fc1_b, h1, HALFTOK, 720, 192, 720, 1, 0, 1, 0, nullptr, nullptr);
        dwconv4_kernel<720, 768, 768, 1, 2, 1><<<dim3(HALFTOK / 4 * 192 / 256), dim3(256), 0, stream>>>(
            h1, dwt3, db3, h2);
        gemm(h2, wpw, pw_b, h3, HALFTOK, 720, 768, 768, 1, 1, 2, 0, nullptr, nullptr);
        mpap_kernel<<<dim3(HALFTOK / 4), dim3(256), 0, stream>>>(h3, mp, ap);
        saconv_kernel<<<dim3(HALFTOK / 256), dim3(256), 0, stream>>>(mp, ap, sa_w, sab);
        gemm(h3, wfc2, fc2_b, outp + toff * 180, HALFTOK, 180, 768, 180, 0, 0, 0, 0,
             sab, x1 + toff * 180);
    }
}

// Round 10
// 812.177 us; speedup vs baseline: 4.2883x; 1.0536x over previous
//
#include <hip/hip_runtime.h>
#include <math.h>

#define HH 128
#define WW 128
#define CC 180
#define BB 4
#define IMG (HH*WW)          // 16384 tokens per image
#define NTOK (BB*IMG)        // 65536
#define HALFTOK (2*IMG)      // 32768
#define NHEADS 6
#define HD 30
#define WSZ 16
#define NTOKW (WSZ*WSZ)      // 256
#define HID 720
#define QKVSTR 576           // padded qkv row: 3 sections x 6 heads x 32

typedef __attribute__((ext_vector_type(8))) short short8v;
typedef __attribute__((ext_vector_type(4))) short short4v;
typedef __attribute__((ext_vector_type(4))) float f32x4;
typedef unsigned short ushortw;

__device__ __forceinline__ float warp_sum(float v) {
    #pragma unroll
    for (int o = 32; o > 0; o >>= 1) v += __shfl_xor(v, o);
    return v;
}
__device__ __forceinline__ float warp_max(float v) {
    #pragma unroll
    for (int o = 32; o > 0; o >>= 1) v = fmaxf(v, __shfl_xor(v, o));
    return v;
}
__device__ __forceinline__ float gelu_exact(float v) {
    return 0.5f * v * (1.f + erff(v * 0.70710678118654752f));
}
__device__ __forceinline__ ushortw f2bf(float f) {
    union { float f; unsigned int u; } c; c.f = f;
    unsigned int r = (c.u + 0x7FFFu + ((c.u >> 16) & 1u)) >> 16;
    return (ushortw)r;
}
__device__ __forceinline__ float bf2f(ushortw u) {
    union { unsigned int u; float f; } c; c.u = ((unsigned int)u) << 16; return c.f;
}

// ---------------- fused weight/bias prep: all conversions in ONE launch ----------------
// J0 wqkv permuted 576x192 | J1 wproj 256x192 | J2 wcab0 128x192 | J3 wcab2 256x128
// J4 wfc1 768x192 | J5 wpw 768x768 | J6 wfc2 256x768 | J7-9 dw transposes | J10 qb576 | J11 biasN
__global__ __launch_bounds__(256) void prep_kernel(
    const float* __restrict__ qkv_w, const float* __restrict__ proj_w,
    const float* __restrict__ cab_w0, const float* __restrict__ cab_w2,
    const float* __restrict__ fc1_w, const float* __restrict__ pw_w,
    const float* __restrict__ fc2_w,
    const float* __restrict__ cab_w1, const float* __restrict__ cab_b1,
    const float* __restrict__ cab_w3, const float* __restrict__ cab_b3,
    const float* __restrict__ dw_w, const float* __restrict__ dw_b,
    const float* __restrict__ qkv_b, const int* __restrict__ rpi,
    const float* __restrict__ rpb,
    ushortw* __restrict__ wqkv, ushortw* __restrict__ wproj,
    ushortw* __restrict__ wcab0, ushortw* __restrict__ wcab2,
    ushortw* __restrict__ wfc1, ushortw* __restrict__ wpw, ushortw* __restrict__ wfc2,
    float* __restrict__ dwt1, float* __restrict__ db1,
    float* __restrict__ dwt2, float* __restrict__ db2,
    float* __restrict__ dwt3, float* __restrict__ db3,
    float* __restrict__ qb576, float* __restrict__ biasN)
{
    int idx = blockIdx.x * 256 + threadIdx.x;
    if (idx < 110592) {                              // J0: wqkv permuted [576][192]
        int r = idx / 192, k = idx - r * 192;
        int sub = r / 192, rem = r - sub * 192;
        int hh = rem >> 5, dd = rem & 31;
        float v = (dd < 30 && k < 180) ? qkv_w[(sub * 180 + hh * 30 + dd) * 180 + k] : 0.f;
        wqkv[idx] = f2bf(v);
    } else if (idx < 159744) {                       // J1: wproj [256][192]
        int l = idx - 110592; int r = l / 192, k = l - r * 192;
        wproj[l] = f2bf((r < 180 && k < 180) ? proj_w[r * 180 + k] : 0.f);
    } else if (idx < 184320) {                       // J2: wcab0 [128][192]
        int l = idx - 159744; int r = l / 192, k = l - r * 192;
        wcab0[l] = f2bf((r < 90 && k < 180) ? cab_w0[r * 180 + k] : 0.f);
    } else if (idx < 217088) {                       // J3: wcab2 [256][128]
        int l = idx - 184320; int r = l / 128, k = l - r * 128;
        wcab2[l] = f2bf((r < 180 && k < 90) ? cab_w2[r * 90 + k] : 0.f);
    } else if (idx < 364544) {                       // J4: wfc1 [768][192]
        int l = idx - 217088; int r = l / 192, k = l - r * 192;
        wfc1[l] = f2bf((r < 720 && k < 180) ? fc1_w[r * 180 + k] : 0.f);
    } else if (idx < 954368) {                       // J5: wpw [768][768]
        int l = idx - 364544; int r = l / 768, k = l - r * 768;
        wpw[l] = f2bf((r < 720 && k < 720) ? pw_w[r * 720 + k] : 0.f);
    } else if (idx < 1150976) {                      // J6: wfc2 [256][768]
        int l = idx - 954368; int r = l / 768, k = l - r * 768;
        wfc2[l] = f2bf((r < 180 && k < 720) ? fc2_w[r * 720 + k] : 0.f);
    } else if (idx < 1152128) {                      // J7: dwt1 [9][128]
        int l = idx - 1150976; int c = l / 9, k = l - c * 9;
        dwt1[k * 128 + c] = (c < 90) ? cab_w1[c * 9 + k] : 0.f;
        if (k == 0) db1[c] = (c < 90) ? cab_b1[c] : 0.f;
    } else if (idx < 1153856) {                      // J8: dwt2 [9][192]
        int l = idx - 1152128; int c = l / 9, k = l - c * 9;
        dwt2[k * 192 + c] = (c < 180) ? cab_w3[c * 9 + k] : 0.f;
        if (k == 0) db2[c] = (c < 180) ? cab_b3[c] : 0.f;
    } else if (idx < 1160768) {                      // J9: dwt3 [9][768]
        int l = idx - 1153856; int c = l / 9, k = l - c * 9;
        dwt3[k * 768 + c] = (c < 720) ? dw_w[c * 9 + k] : 0.f;
        if (k == 0) db3[c] = (c < 720) ? dw_b[c] : 0.f;
    } else if (idx < 1161344) {                      // J10: qb576
        int l = idx - 1160768;
        int sub = l / 192, rem = l - sub * 192;
        int hh = rem >> 5, dd = rem & 31;
        qb576[l] = (dd < 30) ? qkv_b[sub * 180 + hh * 30 + dd] : 0.f;
    } else if (idx < 1226880) {                      // J11: biasN [6][65536]
        int l = idx - 1161344;
        int r = rpi[l];
        #pragma unroll
        for (int h = 0; h < NHEADS; h++)
            biasN[((size_t)h << 16) + l] = rpb[r * NHEADS + h];
    }
}

// ---------------- LayerNorm -> bf16 out, stride 192 (cols 180..191 zero) ----------------
__global__ __launch_bounds__(256) void ln_kernel(
    const float* __restrict__ x, const float* __restrict__ g,
    const float* __restrict__ b, ushortw* __restrict__ out)
{
    int wid = threadIdx.x >> 6, lane = threadIdx.x & 63;
    int t = blockIdx.x * 4 + wid;
    size_t off = (size_t)t * CC;
    size_t off2 = (size_t)t * 192;
    bool has2 = lane < (CC - 128);
    float v0 = x[off + lane];
    float v1 = x[off + lane + 64];
    float v2 = has2 ? x[off + lane + 128] : 0.f;
    float s = warp_sum(v0 + v1 + v2);
    float mu = s * (1.f / CC);
    float d0 = v0 - mu, d1 = v1 - mu, d2 = has2 ? v2 - mu : 0.f;
    float var = warp_sum(d0*d0 + d1*d1 + d2*d2) * (1.f / CC);
    float rs = rsqrtf(var + 1e-5f);
    out[off2 + lane]      = f2bf(d0 * rs * g[lane]      + b[lane]);
    out[off2 + lane + 64] = f2bf(d1 * rs * g[lane + 64] + b[lane + 64]);
    out[off2 + lane + 128] = has2 ? f2bf(d2 * rs * g[lane + 128] + b[lane + 128]) : (ushortw)0;
}

// ---------------- bf16 MFMA GEMM, m97 structure + XCD-aware bijective swizzle ----------------
__global__ __launch_bounds__(256) void mgemm_kernel(
    const ushortw* __restrict__ A, const ushortw* __restrict__ Wt,
    const float* __restrict__ bias, void* __restrict__ Cout,
    int M, int N, int Kp, int ldc, int outbf, int zfill, int act, int residbf, int nN,
    const float* __restrict__ rowscale, const void* __restrict__ residv)
{
    __shared__ ushortw sA[128 * 64];
    __shared__ ushortw sB[128 * 64];
    int tid = threadIdx.x, lane = tid & 63, wid = tid >> 6;
    int total = (int)gridDim.x;
    int orig = blockIdx.x;
    int q = total >> 3, r = total & 7;
    int xcd = orig & 7, slot = orig >> 3;
    int wgid = (xcd < r ? xcd * (q + 1) : r * (q + 1) + (xcd - r) * q) + slot;
    int mp = wgid / nN, np = wgid - mp * nN;
    int m0 = mp << 7, n0 = np << 7;
    int wm = (wid >> 1) << 6, wn = (wid & 1) << 6;
    int lrow = lane & 15, kgrp = lane >> 4;

    f32x4 acc[4][4];
    #pragma unroll
    for (int i = 0; i < 4; i++)
        #pragma unroll
        for (int j = 0; j < 4; j++)
            #pragma unroll
            for (int rr = 0; rr < 4; rr++) acc[i][j][rr] = 0.f;

    int nk = Kp >> 6;
    for (int t = 0; t < nk; t++) {
        int kk = t << 6;
        #pragma unroll
        for (int qq = 0; qq < 4; qq++) {
            int seg = (wid << 2) + qq;                // 0..15
            int row = (seg << 3) + (lane >> 3);       // 0..127
            int cg = (lane & 7) ^ (row & 7);          // swizzled global chunk
            const ushortw* ga = A + (size_t)(m0 + row) * Kp + kk + (cg << 3);
            __builtin_amdgcn_global_load_lds(
                (const __attribute__((address_space(1))) void*)ga,
                (__attribute__((address_space(3))) void*)&sA[seg << 9], 16, 0, 0);
            const ushortw* gb = Wt + (size_t)(n0 + row) * Kp + kk + (cg << 3);
            __builtin_amdgcn_global_load_lds(
                (const __attribute__((address_space(1))) void*)gb,
                (__attribute__((address_space(3))) void*)&sB[seg << 9], 16, 0, 0);
        }
        __syncthreads();
        short8v a[4][2], b[4][2];
        #pragma unroll
        for (int i = 0; i < 4; i++) {
            int rr = wm + (i << 4) + lrow;
            #pragma unroll
            for (int s = 0; s < 2; s++) {
                int slot2 = ((s << 2) + kgrp) ^ (rr & 7);
                a[i][s] = *reinterpret_cast<const short8v*>(&sA[(rr << 6) + (slot2 << 3)]);
            }
        }
        #pragma unroll
        for (int j = 0; j < 4; j++) {
            int rr = wn + (j << 4) + lrow;
            #pragma unroll
            for (int s = 0; s < 2; s++) {
                int slot2 = ((s << 2) + kgrp) ^ (rr & 7);
                b[j][s] = *reinterpret_cast<const short8v*>(&sB[(rr << 6) + (slot2 << 3)]);
            }
        }
        #pragma unroll
        for (int i = 0; i < 4; i++)
            #pragma unroll
            for (int j = 0; j < 4; j++) {
                acc[i][j] = __builtin_amdgcn_mfma_f32_16x16x32_bf16(a[i][0], b[j][0], acc[i][j], 0, 0, 0);
                acc[i][j] = __builtin_amdgcn_mfma_f32_16x16x32_bf16(a[i][1], b[j][1], acc[i][j], 0, 0, 0);
            }
        __syncthreads();
    }
    #pragma unroll
    for (int i = 0; i < 4; i++) {
        int rowb = m0 + wm + (i << 4) + (kgrp << 2);
        #pragma unroll
        for (int j = 0; j < 4; j++) {
            int col = n0 + wn + (j << 4) + lrow;
            if (col < N) {
                float bi = bias[col];
                #pragma unroll
                for (int rr = 0; rr < 4; rr++) {
                    int row = rowb + rr;
                    float v = acc[i][j][rr];
                    if (rowscale) v *= rowscale[row];
                    v += bi;
                    if (act == 1) v = gelu_exact(v);
                    else if (act == 2) v = fmaxf(v, 0.f);
                    if (residv) {
                        v += residbf ? bf2f(((const ushortw*)residv)[(size_t)row * N + col])
                                     : ((const float*)residv)[(size_t)row * N + col];
                    }
                    if (outbf) ((ushortw*)Cout)[(size_t)row * ldc + col] = f2bf(v);
                    else       ((float*)Cout)[(size_t)row * ldc + col] = v;
                }
            } else if (zfill && col < ldc) {
                #pragma unroll
                for (int rr = 0; rr < 4; rr++) {
                    int row = rowb + rr;
                    if (outbf) ((ushortw*)Cout)[(size_t)row * ldc + col] = 0;
                    else       ((float*)Cout)[(size_t)row * ldc + col] = 0.f;
                }
            }
        }
    }
}

// ---------------- MFMA window attention (swapped QK^T): block = (img, win, head) ----------------
__global__ __launch_bounds__(256, 3) void attn_mfma_kernel(
    const ushortw* __restrict__ qkvP, const float* __restrict__ biasN,
    ushortw* __restrict__ out)
{
    __shared__ ushortw Vc[32 * 33 * 8];      // [kc][33 d-slots][8] : 16896 B
    __shared__ ushortw Kc[256 * 32];         // [k-row][32 d], chunk-XOR swizzled : 16384 B
    __shared__ ushortw Pl[4][2048];          // per-wave [16 q][128 k] bf16, XOR-swizzled : 16384 B
    const float SCALE = 0.18257418583505536f;   // 30^-0.5
    int blk = blockIdx.x;
    int img = blk / 384;
    int rem = blk - img * 384;
    int win = rem / NHEADS;
    int h = rem - win * NHEADS;
    int base = img * IMG + (win >> 3) * WSZ * WW + (win & 7) * WSZ;
    int tid = threadIdx.x;
    int lane = tid & 63, w = tid >> 6;
    int a15 = lane & 15, kg = lane >> 4;

    {
        int j = tid;
        int g = base + (j >> 4) * WW + (j & 15);
        const ushortw* vp = qkvP + (size_t)g * QKVSTR + 384 + h * 32;
        short8v c0 = *reinterpret_cast<const short8v*>(vp);
        short8v c1 = *reinterpret_cast<const short8v*>(vp + 8);
        short8v c2 = *reinterpret_cast<const short8v*>(vp + 16);
        short8v c3 = *reinterpret_cast<const short8v*>(vp + 24);
        int bo = (j >> 3) * 264 + (j & 7);
        #pragma unroll
        for (int e = 0; e < 8; e++)  Vc[bo + (e) * 8]      = (ushortw)c0[e];
        #pragma unroll
        for (int e = 0; e < 8; e++)  Vc[bo + (8 + e) * 8]  = (ushortw)c1[e];
        #pragma unroll
        for (int e = 0; e < 8; e++)  Vc[bo + (16 + e) * 8] = (ushortw)c2[e];
        #pragma unroll
        for (int e = 0; e < 8; e++)  Vc[bo + (24 + e) * 8] = (ushortw)c3[e];
        // K row j (pads are true zeros from permuted-weight GEMM)
        const ushortw* kp = qkvP + (size_t)g * QKVSTR + 192 + h * 32;
        short8v k0 = *reinterpret_cast<const short8v*>(kp);
        short8v k1 = *reinterpret_cast<const short8v*>(kp + 8);
        short8v k2 = *reinterpret_cast<const short8v*>(kp + 16);
        short8v k3 = *reinterpret_cast<const short8v*>(kp + 24);
        short8v* krow = reinterpret_cast<short8v*>(&Kc[j * 32]);
        int jsw = j & 3;
        krow[0 ^ jsw] = k0; krow[1 ^ jsw] = k1; krow[2 ^ jsw] = k2; krow[3 ^ jsw] = k3;
    }
    __syncthreads();

    ushortw* Pw = &Pl[w][0];
    int xsw = (a15 & 7) << 2;                // P dword-XOR per q-row
    f32x4 zf = {0.f, 0.f, 0.f, 0.f};
    #pragma unroll 1
    for (int si = 0; si < 4; si++) {
        int strip = (w << 2) + si;
        short8v qf = *reinterpret_cast<const short8v*>(
            qkvP + (size_t)(base + strip * WW + a15) * QKVSTR + h * 32 + (kg << 3));
        float psum = 0.f;
        f32x4 o0 = zf, o1 = zf;
        const float* brow = biasN + ((size_t)h << 16) + (size_t)((strip << 4) + a15) * 256;
        #pragma unroll 1
        for (int half = 0; half < 2; half++) {
            f32x4 s[8];
            __builtin_amdgcn_s_setprio(1);
            #pragma unroll
            for (int j8 = 0; j8 < 8; j8++) {
                int jt = (half << 3) + j8;
                int row = (jt << 4) + a15;
                short8v ka = reinterpret_cast<const short8v*>(&Kc[row * 32])[kg ^ (row & 3)];
                s[j8] = __builtin_amdgcn_mfma_f32_16x16x32_bf16(ka, qf, zf, 0, 0, 0);
            }
            __builtin_amdgcn_s_setprio(0);
            #pragma unroll
            for (int j8 = 0; j8 < 8; j8++) {
                int jt = (half << 3) + j8;
                float4 b4 = *reinterpret_cast<const float4*>(brow + (jt << 4) + (kg << 2));
                float p0 = __expf(fmaf(s[j8][0], SCALE, b4.x));
                float p1 = __expf(fmaf(s[j8][1], SCALE, b4.y));
                float p2 = __expf(fmaf(s[j8][2], SCALE, b4.z));
                float p3 = __expf(fmaf(s[j8][3], SCALE, b4.w));
                psum += (p0 + p1) + (p2 + p3);
                unsigned int u0, u1;
                asm("v_cvt_pk_bf16_f32 %0, %1, %2" : "=v"(u0) : "v"(p0), "v"(p1));
                asm("v_cvt_pk_bf16_f32 %0, %1, %2" : "=v"(u1) : "v"(p2), "v"(p3));
                int dw0 = ((j8 << 3) + (kg << 1)) ^ xsw;
                unsigned long long pk64 = (unsigned long long)u0 | ((unsigned long long)u1 << 32);
                *reinterpret_cast<unsigned long long*>(&Pw[(a15 << 7) + (dw0 << 1)]) = pk64;
            }
            __builtin_amdgcn_sched_barrier(0);
            __builtin_amdgcn_s_setprio(1);
            #pragma unroll
            for (int ks4 = 0; ks4 < 4; ks4++) {
                int dwr = ((ks4 << 4) + (kg << 2)) ^ xsw;
                short8v pa = *reinterpret_cast<const short8v*>(&Pw[(a15 << 7) + (dwr << 1)]);
                int kc = (((half << 2) + ks4) << 2) + kg;
                short8v v0 = *reinterpret_cast<const short8v*>(&Vc[(kc * 33 + a15) * 8]);
                short8v v1 = *reinterpret_cast<const short8v*>(&Vc[(kc * 33 + 16 + a15) * 8]);
                o0 = __builtin_amdgcn_mfma_f32_16x16x32_bf16(pa, v0, o0, 0, 0, 0);
                o1 = __builtin_amdgcn_mfma_f32_16x16x32_bf16(pa, v1, o1, 0, 0, 0);
            }
            __builtin_amdgcn_s_setprio(0);
            __builtin_amdgcn_sched_barrier(0);
        }
        psum += __shfl_xor(psum, 16);
        psum += __shfl_xor(psum, 32);
        #pragma unroll
        for (int r = 0; r < 4; r++) {
            float pt = __shfl(psum, (kg << 2) + r);
            float inv = 1.f / pt;
            int g = base + strip * WW + (kg << 2) + r;
            ushortw* orow = out + (size_t)g * 192 + h * HD;
            orow[a15] = f2bf(o0[r] * inv);
            if (a15 < 14) orow[16 + a15] = f2bf(o1[r] * inv);
        }
    }
    if (h == 0) {   // zero pad cols 180..191
        for (int idx2 = tid; idx2 < NTOKW * 12; idx2 += 256) {
            int j = idx2 / 12, d = idx2 - (idx2 / 12) * 12;
            int gj = base + (j >> 4) * WW + (j & 15);
            out[(size_t)gj * 192 + 180 + d] = 0;
        }
    }
}

// ---------------- register-tiled depthwise 3x3 conv: 4 pixels x 4 channels / thread ----------------
template<int CIN_S, int COP, int OSTR, int DIL, int ACT, int OUTBF>
__global__ __launch_bounds__(256) void dwconv4_kernel(
    const ushortw* __restrict__ in, const float* __restrict__ wt,
    const float* __restrict__ bias, void* __restrict__ out)
{
    constexpr int NC4 = COP >> 2;
    constexpr int NX = 4 + 2 * DIL;
    int idx = blockIdx.x * 256 + threadIdx.x;
    int c4 = idx % NC4;
    int quad = idx / NC4;
    int c = c4 << 2;
    int pix0 = quad << 2;
    int p = pix0 & (IMG - 1);
    int imgbase = pix0 - p;
    int px0 = p & (WW - 1), py = p >> 7;

    float4 w9[9];
    #pragma unroll
    for (int t = 0; t < 9; t++)
        w9[t] = *reinterpret_cast<const float4*>(wt + t * COP + c);
    float4 bi4 = *reinterpret_cast<const float4*>(bias + c);
    float acc[4][4];
    #pragma unroll
    for (int i = 0; i < 4; i++) {
        acc[i][0] = bi4.x; acc[i][1] = bi4.y; acc[i][2] = bi4.z; acc[i][3] = bi4.w;
    }
    #pragma unroll
    for (int ky = 0; ky < 3; ky++) {
        int iy = py + (ky - 1) * DIL;
        if (iy < 0 || iy >= HH) continue;
        const ushortw* rowp = in + (size_t)(imgbase + (iy << 7)) * CIN_S + c;
        #pragma unroll
        for (int xx = 0; xx < NX; xx++) {
            int ix = px0 + xx - DIL;
            if (ix < 0 || ix >= WW) continue;
            short4v v = *reinterpret_cast<const short4v*>(rowp + (size_t)ix * CIN_S);
            float f0 = bf2f((ushortw)v[0]);
            float f1 = bf2f((ushortw)v[1]);
            float f2 = bf2f((ushortw)v[2]);
            float f3 = bf2f((ushortw)v[3]);
            #pragma unroll
            for (int kx = 0; kx < 3; kx++) {
                int i = xx - DIL * kx;
                if (i < 0 || i > 3) continue;
                float4 wv = w9[ky * 3 + kx];
                acc[i][0] = fmaf(f0, wv.x, acc[i][0]);
                acc[i][1] = fmaf(f1, wv.y, acc[i][1]);
                acc[i][2] = fmaf(f2, wv.z, acc[i][2]);
                acc[i][3] = fmaf(f3, wv.w, acc[i][3]);
            }
        }
    }
    if (COP != OSTR && c >= OSTR) return;
    #pragma unroll
    for (int i = 0; i < 4; i++) {
        #pragma unroll
        for (int e = 0; e < 4; e++) {
            float v = acc[i][e];
            if (ACT == 1) v = gelu_exact(v);
            else if (ACT == 2) v = fmaxf(v, 0.f);
            acc[i][e] = v;
        }
        if (OUTBF) {
            short4v o;
            o[0] = (short)f2bf(acc[i][0]); o[1] = (short)f2bf(acc[i][1]);
            o[2] = (short)f2bf(acc[i][2]); o[3] = (short)f2bf(acc[i][3]);
            *reinterpret_cast<short4v*>((ushortw*)out + (size_t)(pix0 + i) * OSTR + c) = o;
        } else {
            float4 o = make_float4(acc[i][0], acc[i][1], acc[i][2], acc[i][3]);
            *reinterpret_cast<float4*>((float*)out + (size_t)(pix0 + i) * OSTR + c) = o;
        }
    }
}

// ---------------- GAP partial sums over bf16 y4 ----------------
__global__ void gap_kernel(const ushortw* __restrict__ y, float* __restrict__ part)
{
    int blk = blockIdx.x;
    int b = blk >> 5, chunk = blk & 31;
    int c = threadIdx.x;
    if (c >= CC) return;
    size_t basep = ((size_t)b * IMG + (size_t)chunk * 512) * CC;
    float s = 0.f;
    for (int p = 0; p < 512; p++) s += bf2f(y[basep + (size_t)p * CC + c]);
    part[((size_t)b * 32 + chunk) * CC + c] = s;
}

// ---------------- channel attention (tiny) ----------------
__global__ void ca_kernel(const float* __restrict__ part,
                          const float* __restrict__ w1, const float* __restrict__ b1,
                          const float* __restrict__ w2, const float* __restrict__ b2,
                          float* __restrict__ ca)
{
    __shared__ float gap[BB * CC];
    __shared__ float s1[BB * 6];
    int tid = threadIdx.x;
    for (int idx = tid; idx < BB * CC; idx += 256) {
        int b = idx / CC, c = idx % CC;
        float s = 0.f;
        for (int ch = 0; ch < 32; ch++) s += part[((size_t)b * 32 + ch) * CC + c];
        gap[idx] = s * (1.f / IMG);
    }
    __syncthreads();
    if (tid < BB * 6) {
        int b = tid / 6, cs = tid % 6;
        float s = 0.f;
        for (int c = 0; c < CC; c++) s += w1[cs * CC + c] * gap[b * CC + c];
        s1[tid] = fmaxf(s + b1[cs], 0.f);
    }
    __syncthreads();
    for (int idx = tid; idx < BB * CC; idx += 256) {
        int b = idx / CC, c = idx % CC;
        float s = b2[c];
        #pragma unroll
        for (int cs = 0; cs < 6; cs++) s += w2[c * 6 + cs] * s1[b * 6 + cs];
        ca[idx] = 1.f / (1.f + __expf(-s));
    }
}

// ---------------- x1(bf16) += 0.01*y4*ca; LN2 -> bf16 xn2 (stride 192) ----------------
__global__ __launch_bounds__(256) void resid_ln_kernel(
    ushortw* __restrict__ x1, const ushortw* __restrict__ y4, const float* __restrict__ ca,
    const float* __restrict__ g, const float* __restrict__ bb,
    ushortw* __restrict__ xn2)
{
    int wid = threadIdx.x >> 6, lane = threadIdx.x & 63;
    int t = blockIdx.x * 4 + wid;
    int b = t >> 14;
    size_t off = (size_t)t * CC;
    size_t off2 = (size_t)t * 192;
    bool has2 = lane < (CC - 128);
    float v0 = bf2f(x1[off+lane])    + 0.01f * bf2f(y4[off+lane])    * ca[b*CC + lane];
    float v1 = bf2f(x1[off+lane+64]) + 0.01f * bf2f(y4[off+lane+64]) * ca[b*CC + lane+64];
    float v2 = 0.f;
    if (has2) v2 = bf2f(x1[off+lane+128]) + 0.01f * bf2f(y4[off+lane+128]) * ca[b*CC + lane+128];
    x1[off+lane] = f2bf(v0); x1[off+lane+64] = f2bf(v1);
    if (has2) x1[off+lane+128] = f2bf(v2);
    float s = warp_sum(v0 + v1 + v2);
    float mu = s * (1.f / CC);
    float d0 = v0-mu, d1 = v1-mu, d2 = has2 ? v2-mu : 0.f;
    float var = warp_sum(d0*d0 + d1*d1 + d2*d2) * (1.f / CC);
    float rs = rsqrtf(var + 1e-5f);
    xn2[off2+lane]      = f2bf(d0 * rs * g[lane]      + bb[lane]);
    xn2[off2+lane+64]   = f2bf(d1 * rs * g[lane+64]   + bb[lane+64]);
    xn2[off2+lane+128]  = has2 ? f2bf(d2 * rs * g[lane+128] + bb[lane+128]) : (ushortw)0;
}

// ---------------- max/mean over channels per pixel (bf16 h3, stride 768, 720 cols) ----------------
__global__ __launch_bounds__(256) void mpap_kernel(
    const ushortw* __restrict__ h, float* __restrict__ mp, float* __restrict__ ap)
{
    int wid = threadIdx.x >> 6, lane = threadIdx.x & 63;
    int p = blockIdx.x * 4 + wid;
    const ushortw* row = h + (size_t)p * 768;
    float mx = -1e30f, s = 0.f;
    for (int j = lane; j < HID; j += 64) { float v = bf2f(row[j]); mx = fmaxf(mx, v); s += v; }
    mx = warp_max(mx); s = warp_sum(s);
    if (lane == 0) { mp[p] = mx; ap[p] = s * (1.f / HID); }
}

// ---------------- 7x7 spatial-attention conv + sigmoid (half batch = 2 images) ----------------
__global__ void saconv_kernel(const float* __restrict__ mp, const float* __restrict__ ap,
                              const float* __restrict__ w, float* __restrict__ sa)
{
    int p = blockIdx.x * blockDim.x + threadIdx.x;   // 0..HALFTOK-1
    int lp = p & (IMG - 1);
    int base = p - lp;
    int px = lp & (WW - 1), py = lp >> 7;
    float acc = 0.f;
    for (int ky = 0; ky < 7; ky++) {
        int iy = py + ky - 3;
        if (iy < 0 || iy >= HH) continue;
        for (int kx = 0; kx < 7; kx++) {
            int ix = px + kx - 3;
            if (ix < 0 || ix >= WW) continue;
            int pid = base + iy * WW + ix;
            acc += mp[pid] * w[ky * 7 + kx] + ap[pid] * w[49 + ky * 7 + kx];
        }
    }
    sa[p] = 1.f / (1.f + __expf(-acc));
}

extern "C" void kernel_launch(void* const* d_in, const int* in_sizes, int n_in,
                              void* d_out, int out_size, void* d_ws, size_t ws_size,
                              hipStream_t stream)
{
    const float* x      = (const float*)d_in[0];
    const int*   rpi    = (const int*)d_in[3];
    const float* n1g    = (const float*)d_in[4];
    const float* n1b    = (const float*)d_in[5];
    const float* rpb    = (const float*)d_in[6];
    const float* qkv_w  = (const float*)d_in[7];
    const float* qkv_b  = (const float*)d_in[8];
    const float* proj_w = (const float*)d_in[9];
    const float* proj_b = (const float*)d_in[10];
    const float* cab_w0 = (const float*)d_in[11];
    const float* cab_b0 = (const float*)d_in[12];
    const float* cab_w1 = (const float*)d_in[13];
    const float* cab_b1 = (const float*)d_in[14];
    const float* cab_w2 = (const float*)d_in[15];
    const float* cab_b2 = (const float*)d_in[16];
    const float* cab_w3 = (const float*)d_in[17];
    const float* cab_b3 = (const float*)d_in[18];
    const float* ca_w1  = (const float*)d_in[19];
    const float* ca_b1  = (const float*)d_in[20];
    const float* ca_w2  = (const float*)d_in[21];
    const float* ca_b2  = (const float*)d_in[22];
    const float* n2g    = (const float*)d_in[23];
    const float* n2b    = (const float*)d_in[24];
    const float* fc1_w  = (const float*)d_in[25];
    const float* fc1_b  = (const float*)d_in[26];
    const float* dw_w   = (const float*)d_in[27];
    const float* dw_b   = (const float*)d_in[28];
    const float* pw_w   = (const float*)d_in[29];
    const float* pw_b   = (const float*)d_in[30];
    const float* sa_w   = (const float*)d_in[31];
    const float* fc2_w  = (const float*)d_in[32];
    const float* fc2_b  = (const float*)d_in[33];
    float* outp = (float*)d_out;
    (void)in_sizes; (void)n_in; (void)out_size; (void)ws_size;

    char* ws = (char*)d_ws;
    const size_t S0 = (size_t)NTOK * 192 * 2;      // xnb -> xn2b
    const size_t S1 = (size_t)NTOK * QKVSTR * 2;   // qkvP -> y1b -> h1(half) -> h3(half)
    const size_t S2 = (size_t)NTOK * 192 * 2;      // attnbb -> y3b
    const size_t S3 = (size_t)NTOK * 180 * 4;      // x1 (bf16, region oversize ok)
    const size_t S4 = (size_t)NTOK * 128 * 2;      // y2b ; h2(half) spans S4+S5
    const size_t S5 = (size_t)NTOK * 180 * 4;      // y4 (bf16, region kept for h2 span)
    char* pA0 = ws;
    char* pA1 = pA0 + S0;
    char* pA2 = pA1 + S1;
    char* pA3 = pA2 + S2;
    char* pA4 = pA3 + S3;
    char* pA5 = pA4 + S4;
    char* tail = pA5 + S5;

    ushortw* xnb    = (ushortw*)pA0;           // [NTOK][192]
    ushortw* xn2b   = (ushortw*)pA0;
    ushortw* qkvP   = (ushortw*)pA1;           // [NTOK][576]
    ushortw* y1b    = (ushortw*)pA1;           // [NTOK][96]
    ushortw* h1     = (ushortw*)pA1;           // [HALFTOK][720]
    ushortw* h3     = (ushortw*)pA1;           // [HALFTOK][768]
    ushortw* attnbb = (ushortw*)pA2;           // [NTOK][192]
    ushortw* y3b    = (ushortw*)pA2;           // [NTOK][192]
    ushortw* x1b    = (ushortw*)pA3;           // [NTOK][180] bf16
    ushortw* y2b    = (ushortw*)pA4;           // [NTOK][128]
    ushortw* h2     = (ushortw*)pA4;           // [HALFTOK][768] spans S4+S5
    ushortw* y4     = (ushortw*)pA5;           // [NTOK][180] bf16

    // bf16 gemm weights (padded)
    ushortw* wqkv  = (ushortw*)tail;                        // alloc 640x192, used 576x192
    ushortw* wproj = wqkv  + 640 * 192;                     // 256 x 192
    ushortw* wcab0 = wproj + 256 * 192;                     // 128 x 192
    ushortw* wcab2 = wcab0 + 128 * 192;                     // 256 x 128
    ushortw* wfc1  = wcab2 + 256 * 128;                     // 768 x 192
    ushortw* wpw   = wfc1  + 768 * 192;                     // 768 x 768
    ushortw* wfc2  = wpw   + 768 * 768;                     // 256 x 768
    char* tail2 = (char*)(wfc2 + 256 * 768);
    float* dwt1 = (float*)tail2;                 float* db1 = dwt1 + 9*128;
    float* dwt2 = db1 + 128;                     float* db2 = dwt2 + 9*192;
    float* dwt3 = db2 + 192;                     float* db3 = dwt3 + 9*768;
    float* qb576 = db3 + 768;
    char* tail3 = (char*)(qb576 + 576);
    float* biasN = (float*)tail3;                           // 6*65536
    float* part  = (float*)(tail3 + 1572864);
    float* cabuf = (float*)(tail3 + 1572864 + 98304);
    float* mp    = (float*)(tail3 + 1572864 + 131072);                          // [HALFTOK]
    float* ap    = (float*)(tail3 + 1572864 + 131072 + (size_t)HALFTOK * 4);    // [HALFTOK]
    float* sab   = (float*)(tail3 + 1572864 + 131072 + 2*(size_t)HALFTOK * 4);  // [HALFTOK]

    auto gemm = [&](const ushortw* A, const ushortw* Wt, const float* bi, void* Cp,
                    int M, int N, int Kp, int ldc, int outbf, int zfill, int act, int residbf,
                    const float* rs, const void* resid) {
        int nM = M >> 7, nN = (N + 127) >> 7;
        mgemm_kernel<<<dim3(nM * nN), dim3(256), 0, stream>>>(
            A, Wt, bi, Cp, M, N, Kp, ldc, outbf, zfill, act, residbf, nN, rs, resid);
    };

    // 0) all weight/bias prep in one launch
    prep_kernel<<<dim3((1226880 + 255) / 256), dim3(256), 0, stream>>>(
        qkv_w, proj_w, cab_w0, cab_w2, fc1_w, pw_w, fc2_w,
        cab_w1, cab_b1, cab_w3, cab_b3, dw_w, dw_b, qkv_b, rpi, rpb,
        wqkv, wproj, wcab0, wcab2, wfc1, wpw, wfc2,
        dwt1, db1, dwt2, db2, dwt3, db3, qb576, biasN);

    // 1) LN1 -> bf16 xnb
    ln_kernel<<<dim3(NTOK / 4), dim3(256), 0, stream>>>(x, n1g, n1b, xnb);
    // 2) full-batch qkv (permuted weights -> padded layout directly) + MFMA attention
    gemm(xnb, wqkv, qb576, qkvP, NTOK, 576, 192, QKVSTR, 1, 0, 0, 0, nullptr, nullptr);
    attn_mfma_kernel<<<dim3(BB * 64 * NHEADS), dim3(256), 0, stream>>>(qkvP, biasN, attnbb);
    // 3) CAB part 1 (xnb consumed)
    gemm(xnb, wcab0, cab_b0, y1b, NTOK, 90, 192, 96, 1, 1, 0, 0, nullptr, nullptr);
    dwconv4_kernel<96, 128, 128, 1, 1, 1><<<dim3(NTOK / 4 * 32 / 256), dim3(256), 0, stream>>>(
        y1b, dwt1, db1, y2b);
    // 4) proj with residual x -> x1 (bf16)
    gemm(attnbb, wproj, proj_b, x1b, NTOK, 180, 192, 180, 1, 0, 0, 0, nullptr, x);
    // 5) CAB part 2
    gemm(y2b, wcab2, cab_b2, y3b, NTOK, 180, 128, 192, 1, 1, 0, 0, nullptr, nullptr);
    dwconv4_kernel<192, 192, 180, 2, 0, 1><<<dim3(NTOK / 4 * 48 / 256), dim3(256), 0, stream>>>(
        y3b, dwt2, db2, y4);
    gap_kernel<<<dim3(BB * 32), dim3(192), 0, stream>>>(y4, part);
    ca_kernel<<<dim3(1), dim3(256), 0, stream>>>(part, ca_w1, ca_b1, ca_w2, ca_b2, cabuf);
    // 6) x1 += 0.01*y4*ca; LN2 -> bf16 xn2b
    resid_ln_kernel<<<dim3(NTOK / 4), dim3(256), 0, stream>>>(x1b, y4, cabuf, n2g, n2b, xn2b);
    // 7) FFN in two half-batches (2 images each)
    for (int half = 0; half < 2; half++) {
        size_t toff = (size_t)half * HALFTOK;
        gemm(xn2b + toff * 192, wfc1, fc1_b, h1, HALFTOK, 720, 192, 720, 1, 0, 1, 0, nullptr, nullptr);
        dwconv4_kernel<720, 768, 768, 1, 2, 1><<<dim3(HALFTOK / 4 * 192 / 256), dim3(256), 0, stream>>>(
            h1, dwt3, db3, h2);
        gemm(h2, wpw, pw_b, h3, HALFTOK, 720, 768, 768, 1, 1, 2, 0, nullptr, nullptr);
        mpap_kernel<<<dim3(HALFTOK / 4), dim3(256), 0, stream>>>(h3, mp, ap);
        saconv_kernel<<<dim3(HALFTOK / 256), dim3(256), 0, stream>>>(mp, ap, sa_w, sab);
        gemm(h3, wfc2, fc2_b, outp + toff * 180, HALFTOK, 180, 768, 180, 0, 0, 0, 1,
             sab, x1b + toff * 180);
    }
}

// Round 11
// 798.831 us; speedup vs baseline: 4.3600x; 1.0167x over previous
//
#include <hip/hip_runtime.h>
#include <math.h>

#define HH 128
#define WW 128
#define CC 180
#define BB 4
#define IMG (HH*WW)          // 16384 tokens per image
#define NTOK (BB*IMG)        // 65536
#define HALFTOK (2*IMG)      // 32768
#define NHEADS 6
#define HD 30
#define WSZ 16
#define NTOKW (WSZ*WSZ)      // 256
#define HID 720
#define QKVSTR 576           // padded qkv row: 3 sections x 6 heads x 32

typedef __attribute__((ext_vector_type(8))) short short8v;
typedef __attribute__((ext_vector_type(4))) short short4v;
typedef __attribute__((ext_vector_type(4))) float f32x4;
typedef unsigned short ushortw;

__device__ __forceinline__ float warp_sum(float v) {
    #pragma unroll
    for (int o = 32; o > 0; o >>= 1) v += __shfl_xor(v, o);
    return v;
}
__device__ __forceinline__ float warp_max(float v) {
    #pragma unroll
    for (int o = 32; o > 0; o >>= 1) v = fmaxf(v, __shfl_xor(v, o));
    return v;
}
__device__ __forceinline__ float gelu_exact(float v) {
    return 0.5f * v * (1.f + erff(v * 0.70710678118654752f));
}
__device__ __forceinline__ ushortw f2bf(float f) {
    union { float f; unsigned int u; } c; c.f = f;
    unsigned int r = (c.u + 0x7FFFu + ((c.u >> 16) & 1u)) >> 16;
    return (ushortw)r;
}
__device__ __forceinline__ float bf2f(ushortw u) {
    union { unsigned int u; float f; } c; c.u = ((unsigned int)u) << 16; return c.f;
}

// ---------------- fused weight/bias prep: all conversions in ONE launch ----------------
__global__ __launch_bounds__(256) void prep_kernel(
    const float* __restrict__ qkv_w, const float* __restrict__ proj_w,
    const float* __restrict__ cab_w0, const float* __restrict__ cab_w2,
    const float* __restrict__ fc1_w, const float* __restrict__ pw_w,
    const float* __restrict__ fc2_w,
    const float* __restrict__ cab_w1, const float* __restrict__ cab_b1,
    const float* __restrict__ cab_w3, const float* __restrict__ cab_b3,
    const float* __restrict__ dw_w, const float* __restrict__ dw_b,
    const float* __restrict__ qkv_b, const int* __restrict__ rpi,
    const float* __restrict__ rpb,
    ushortw* __restrict__ wqkv, ushortw* __restrict__ wproj,
    ushortw* __restrict__ wcab0, ushortw* __restrict__ wcab2,
    ushortw* __restrict__ wfc1, ushortw* __restrict__ wpw, ushortw* __restrict__ wfc2,
    float* __restrict__ dwt1, float* __restrict__ db1,
    float* __restrict__ dwt2, float* __restrict__ db2,
    float* __restrict__ dwt3, float* __restrict__ db3,
    float* __restrict__ qb576, float* __restrict__ biasN)
{
    int idx = blockIdx.x * 256 + threadIdx.x;
    if (idx < 110592) {                              // J0: wqkv permuted [576][192]
        int r = idx / 192, k = idx - r * 192;
        int sub = r / 192, rem = r - sub * 192;
        int hh = rem >> 5, dd = rem & 31;
        float v = (dd < 30 && k < 180) ? qkv_w[(sub * 180 + hh * 30 + dd) * 180 + k] : 0.f;
        wqkv[idx] = f2bf(v);
    } else if (idx < 159744) {                       // J1: wproj [256][192]
        int l = idx - 110592; int r = l / 192, k = l - r * 192;
        wproj[l] = f2bf((r < 180 && k < 180) ? proj_w[r * 180 + k] : 0.f);
    } else if (idx < 184320) {                       // J2: wcab0 [128][192]
        int l = idx - 159744; int r = l / 192, k = l - r * 192;
        wcab0[l] = f2bf((r < 90 && k < 180) ? cab_w0[r * 180 + k] : 0.f);
    } else if (idx < 217088) {                       // J3: wcab2 [256][128]
        int l = idx - 184320; int r = l / 128, k = l - r * 128;
        wcab2[l] = f2bf((r < 180 && k < 90) ? cab_w2[r * 90 + k] : 0.f);
    } else if (idx < 364544) {                       // J4: wfc1 [768][192]
        int l = idx - 217088; int r = l / 192, k = l - r * 192;
        wfc1[l] = f2bf((r < 720 && k < 180) ? fc1_w[r * 180 + k] : 0.f);
    } else if (idx < 954368) {                       // J5: wpw [768][768]
        int l = idx - 364544; int r = l / 768, k = l - r * 768;
        wpw[l] = f2bf((r < 720 && k < 720) ? pw_w[r * 720 + k] : 0.f);
    } else if (idx < 1150976) {                      // J6: wfc2 [256][768]
        int l = idx - 954368; int r = l / 768, k = l - r * 768;
        wfc2[l] = f2bf((r < 180 && k < 720) ? fc2_w[r * 720 + k] : 0.f);
    } else if (idx < 1152128) {                      // J7: dwt1 [9][128]
        int l = idx - 1150976; int c = l / 9, k = l - c * 9;
        dwt1[k * 128 + c] = (c < 90) ? cab_w1[c * 9 + k] : 0.f;
        if (k == 0) db1[c] = (c < 90) ? cab_b1[c] : 0.f;
    } else if (idx < 1153856) {                      // J8: dwt2 [9][192]
        int l = idx - 1152128; int c = l / 9, k = l - c * 9;
        dwt2[k * 192 + c] = (c < 180) ? cab_w3[c * 9 + k] : 0.f;
        if (k == 0) db2[c] = (c < 180) ? cab_b3[c] : 0.f;
    } else if (idx < 1160768) {                      // J9: dwt3 [9][768]
        int l = idx - 1153856; int c = l / 9, k = l - c * 9;
        dwt3[k * 768 + c] = (c < 720) ? dw_w[c * 9 + k] : 0.f;
        if (k == 0) db3[c] = (c < 720) ? dw_b[c] : 0.f;
    } else if (idx < 1161344) {                      // J10: qb576
        int l = idx - 1160768;
        int sub = l / 192, rem = l - sub * 192;
        int hh = rem >> 5, dd = rem & 31;
        qb576[l] = (dd < 30) ? qkv_b[sub * 180 + hh * 30 + dd] : 0.f;
    } else if (idx < 1226880) {                      // J11: biasN [6][65536]
        int l = idx - 1161344;
        int r = rpi[l];
        #pragma unroll
        for (int h = 0; h < NHEADS; h++)
            biasN[((size_t)h << 16) + l] = rpb[r * NHEADS + h];
    }
}

// ---------------- LayerNorm -> bf16 out, stride 192 (cols 180..191 zero) ----------------
__global__ __launch_bounds__(256) void ln_kernel(
    const float* __restrict__ x, const float* __restrict__ g,
    const float* __restrict__ b, ushortw* __restrict__ out)
{
    int wid = threadIdx.x >> 6, lane = threadIdx.x & 63;
    int t = blockIdx.x * 4 + wid;
    size_t off = (size_t)t * CC;
    size_t off2 = (size_t)t * 192;
    bool has2 = lane < (CC - 128);
    float v0 = x[off + lane];
    float v1 = x[off + lane + 64];
    float v2 = has2 ? x[off + lane + 128] : 0.f;
    float s = warp_sum(v0 + v1 + v2);
    float mu = s * (1.f / CC);
    float d0 = v0 - mu, d1 = v1 - mu, d2 = has2 ? v2 - mu : 0.f;
    float var = warp_sum(d0*d0 + d1*d1 + d2*d2) * (1.f / CC);
    float rs = rsqrtf(var + 1e-5f);
    out[off2 + lane]      = f2bf(d0 * rs * g[lane]      + b[lane]);
    out[off2 + lane + 64] = f2bf(d1 * rs * g[lane + 64] + b[lane + 64]);
    out[off2 + lane + 128] = has2 ? f2bf(d2 * rs * g[lane + 128] + b[lane + 128]) : (ushortw)0;
}

// ---------------- bf16 MFMA GEMM: m97 structure + XCD swizzle + 2-phase LDS double-buffer ----
__global__ __launch_bounds__(256) void mgemm_kernel(
    const ushortw* __restrict__ A, const ushortw* __restrict__ Wt,
    const float* __restrict__ bias, void* __restrict__ Cout,
    int M, int N, int Kp, int ldc, int outbf, int zfill, int act, int residbf, int nN,
    const float* __restrict__ rowscale, const void* __restrict__ residv)
{
    __shared__ ushortw sA[2][128 * 64];
    __shared__ ushortw sB[2][128 * 64];
    int tid = threadIdx.x, lane = tid & 63, wid = tid >> 6;
    int total = (int)gridDim.x;
    int orig = blockIdx.x;
    int q = total >> 3, r = total & 7;
    int xcd = orig & 7, slot = orig >> 3;
    int wgid = (xcd < r ? xcd * (q + 1) : r * (q + 1) + (xcd - r) * q) + slot;
    int mp = wgid / nN, np = wgid - mp * nN;
    int m0 = mp << 7, n0 = np << 7;
    int wm = (wid >> 1) << 6, wn = (wid & 1) << 6;
    int lrow = lane & 15, kgrp = lane >> 4;

    // staging address components (per-lane constants)
    int srow = ((wid << 2) << 3) + (lane >> 3);      // rows covered: seg = wid*4+qq
    int scg  = (lane & 7);

    f32x4 acc[4][4];
    #pragma unroll
    for (int i = 0; i < 4; i++)
        #pragma unroll
        for (int j = 0; j < 4; j++)
            #pragma unroll
            for (int rr = 0; rr < 4; rr++) acc[i][j][rr] = 0.f;

    int nk = Kp >> 6;
    // prologue: stage tile 0 into buffer 0
    #pragma unroll
    for (int qq = 0; qq < 4; qq++) {
        int seg = (wid << 2) + qq;
        int row = (seg << 3) + (lane >> 3);
        int cg = scg ^ (row & 7);
        const ushortw* ga = A + (size_t)(m0 + row) * Kp + (cg << 3);
        __builtin_amdgcn_global_load_lds(
            (const __attribute__((address_space(1))) void*)ga,
            (__attribute__((address_space(3))) void*)&sA[0][seg << 9], 16, 0, 0);
        const ushortw* gb = Wt + (size_t)(n0 + row) * Kp + (cg << 3);
        __builtin_amdgcn_global_load_lds(
            (const __attribute__((address_space(1))) void*)gb,
            (__attribute__((address_space(3))) void*)&sB[0][seg << 9], 16, 0, 0);
    }
    __syncthreads();

    int cur = 0;
    for (int t = 0; t < nk; t++) {
        // issue next tile's stage into the alternate buffer BEFORE compute
        if (t + 1 < nk) {
            int kk2 = (t + 1) << 6;
            #pragma unroll
            for (int qq = 0; qq < 4; qq++) {
                int seg = (wid << 2) + qq;
                int row = (seg << 3) + (lane >> 3);
                int cg = scg ^ (row & 7);
                const ushortw* ga = A + (size_t)(m0 + row) * Kp + kk2 + (cg << 3);
                __builtin_amdgcn_global_load_lds(
                    (const __attribute__((address_space(1))) void*)ga,
                    (__attribute__((address_space(3))) void*)&sA[cur ^ 1][seg << 9], 16, 0, 0);
                const ushortw* gb = Wt + (size_t)(n0 + row) * Kp + kk2 + (cg << 3);
                __builtin_amdgcn_global_load_lds(
                    (const __attribute__((address_space(1))) void*)gb,
                    (__attribute__((address_space(3))) void*)&sB[cur ^ 1][seg << 9], 16, 0, 0);
            }
        }
        // compute on current buffer
        short8v a[4][2], b[4][2];
        #pragma unroll
        for (int i = 0; i < 4; i++) {
            int rr = wm + (i << 4) + lrow;
            #pragma unroll
            for (int s = 0; s < 2; s++) {
                int slot2 = ((s << 2) + kgrp) ^ (rr & 7);
                a[i][s] = *reinterpret_cast<const short8v*>(&sA[cur][(rr << 6) + (slot2 << 3)]);
            }
        }
        #pragma unroll
        for (int j = 0; j < 4; j++) {
            int rr = wn + (j << 4) + lrow;
            #pragma unroll
            for (int s = 0; s < 2; s++) {
                int slot2 = ((s << 2) + kgrp) ^ (rr & 7);
                b[j][s] = *reinterpret_cast<const short8v*>(&sB[cur][(rr << 6) + (slot2 << 3)]);
            }
        }
        #pragma unroll
        for (int i = 0; i < 4; i++)
            #pragma unroll
            for (int j = 0; j < 4; j++) {
                acc[i][j] = __builtin_amdgcn_mfma_f32_16x16x32_bf16(a[i][0], b[j][0], acc[i][j], 0, 0, 0);
                acc[i][j] = __builtin_amdgcn_mfma_f32_16x16x32_bf16(a[i][1], b[j][1], acc[i][j], 0, 0, 0);
            }
        __syncthreads();   // drains next-tile stage (vmcnt 0) + all reads of cur done
        cur ^= 1;
    }
    (void)srow;
    #pragma unroll
    for (int i = 0; i < 4; i++) {
        int rowb = m0 + wm + (i << 4) + (kgrp << 2);
        #pragma unroll
        for (int j = 0; j < 4; j++) {
            int col = n0 + wn + (j << 4) + lrow;
            if (col < N) {
                float bi = bias[col];
                #pragma unroll
                for (int rr = 0; rr < 4; rr++) {
                    int row = rowb + rr;
                    float v = acc[i][j][rr];
                    if (rowscale) v *= rowscale[row];
                    v += bi;
                    if (act == 1) v = gelu_exact(v);
                    else if (act == 2) v = fmaxf(v, 0.f);
                    if (residv) {
                        v += residbf ? bf2f(((const ushortw*)residv)[(size_t)row * N + col])
                                     : ((const float*)residv)[(size_t)row * N + col];
                    }
                    if (outbf) ((ushortw*)Cout)[(size_t)row * ldc + col] = f2bf(v);
                    else       ((float*)Cout)[(size_t)row * ldc + col] = v;
                }
            } else if (zfill && col < ldc) {
                #pragma unroll
                for (int rr = 0; rr < 4; rr++) {
                    int row = rowb + rr;
                    if (outbf) ((ushortw*)Cout)[(size_t)row * ldc + col] = 0;
                    else       ((float*)Cout)[(size_t)row * ldc + col] = 0.f;
                }
            }
        }
    }
}

// ---------------- MFMA window attention (swapped QK^T): block = (img, win, head) ----------------
__global__ __launch_bounds__(256, 3) void attn_mfma_kernel(
    const ushortw* __restrict__ qkvP, const float* __restrict__ biasN,
    ushortw* __restrict__ out)
{
    __shared__ ushortw Vc[32 * 33 * 8];      // [kc][33 d-slots][8] : 16896 B
    __shared__ ushortw Kc[256 * 32];         // [k-row][32 d], chunk-XOR swizzled : 16384 B
    __shared__ ushortw Pl[4][2048];          // per-wave [16 q][128 k] bf16, XOR-swizzled : 16384 B
    const float SCALE = 0.18257418583505536f;   // 30^-0.5
    int blk = blockIdx.x;
    int img = blk / 384;
    int rem = blk - img * 384;
    int win = rem / NHEADS;
    int h = rem - win * NHEADS;
    int base = img * IMG + (win >> 3) * WSZ * WW + (win & 7) * WSZ;
    int tid = threadIdx.x;
    int lane = tid & 63, w = tid >> 6;
    int a15 = lane & 15, kg = lane >> 4;

    {
        int j = tid;
        int g = base + (j >> 4) * WW + (j & 15);
        const ushortw* vp = qkvP + (size_t)g * QKVSTR + 384 + h * 32;
        short8v c0 = *reinterpret_cast<const short8v*>(vp);
        short8v c1 = *reinterpret_cast<const short8v*>(vp + 8);
        short8v c2 = *reinterpret_cast<const short8v*>(vp + 16);
        short8v c3 = *reinterpret_cast<const short8v*>(vp + 24);
        int bo = (j >> 3) * 264 + (j & 7);
        #pragma unroll
        for (int e = 0; e < 8; e++)  Vc[bo + (e) * 8]      = (ushortw)c0[e];
        #pragma unroll
        for (int e = 0; e < 8; e++)  Vc[bo + (8 + e) * 8]  = (ushortw)c1[e];
        #pragma unroll
        for (int e = 0; e < 8; e++)  Vc[bo + (16 + e) * 8] = (ushortw)c2[e];
        #pragma unroll
        for (int e = 0; e < 8; e++)  Vc[bo + (24 + e) * 8] = (ushortw)c3[e];
        const ushortw* kp = qkvP + (size_t)g * QKVSTR + 192 + h * 32;
        short8v k0 = *reinterpret_cast<const short8v*>(kp);
        short8v k1 = *reinterpret_cast<const short8v*>(kp + 8);
        short8v k2 = *reinterpret_cast<const short8v*>(kp + 16);
        short8v k3 = *reinterpret_cast<const short8v*>(kp + 24);
        short8v* krow = reinterpret_cast<short8v*>(&Kc[j * 32]);
        int jsw = j & 3;
        krow[0 ^ jsw] = k0; krow[1 ^ jsw] = k1; krow[2 ^ jsw] = k2; krow[3 ^ jsw] = k3;
    }
    __syncthreads();

    ushortw* Pw = &Pl[w][0];
    int xsw = (a15 & 7) << 2;                // P dword-XOR per q-row
    f32x4 zf = {0.f, 0.f, 0.f, 0.f};
    #pragma unroll 1
    for (int si = 0; si < 4; si++) {
        int strip = (w << 2) + si;
        short8v qf = *reinterpret_cast<const short8v*>(
            qkvP + (size_t)(base + strip * WW + a15) * QKVSTR + h * 32 + (kg << 3));
        float psum = 0.f;
        f32x4 o0 = zf, o1 = zf;
        const float* brow = biasN + ((size_t)h << 16) + (size_t)((strip << 4) + a15) * 256;
        #pragma unroll 1
        for (int half = 0; half < 2; half++) {
            f32x4 s[8];
            __builtin_amdgcn_s_setprio(1);
            #pragma unroll
            for (int j8 = 0; j8 < 8; j8++) {
                int jt = (half << 3) + j8;
                int row = (jt << 4) + a15;
                short8v ka = reinterpret_cast<const short8v*>(&Kc[row * 32])[kg ^ (row & 3)];
                s[j8] = __builtin_amdgcn_mfma_f32_16x16x32_bf16(ka, qf, zf, 0, 0, 0);
            }
            __builtin_amdgcn_s_setprio(0);
            #pragma unroll
            for (int j8 = 0; j8 < 8; j8++) {
                int jt = (half << 3) + j8;
                float4 b4 = *reinterpret_cast<const float4*>(brow + (jt << 4) + (kg << 2));
                float p0 = __expf(fmaf(s[j8][0], SCALE, b4.x));
                float p1 = __expf(fmaf(s[j8][1], SCALE, b4.y));
                float p2 = __expf(fmaf(s[j8][2], SCALE, b4.z));
                float p3 = __expf(fmaf(s[j8][3], SCALE, b4.w));
                psum += (p0 + p1) + (p2 + p3);
                unsigned int u0, u1;
                asm("v_cvt_pk_bf16_f32 %0, %1, %2" : "=v"(u0) : "v"(p0), "v"(p1));
                asm("v_cvt_pk_bf16_f32 %0, %1, %2" : "=v"(u1) : "v"(p2), "v"(p3));
                int dw0 = ((j8 << 3) + (kg << 1)) ^ xsw;
                unsigned long long pk64 = (unsigned long long)u0 | ((unsigned long long)u1 << 32);
                *reinterpret_cast<unsigned long long*>(&Pw[(a15 << 7) + (dw0 << 1)]) = pk64;
            }
            __builtin_amdgcn_sched_barrier(0);
            __builtin_amdgcn_s_setprio(1);
            #pragma unroll
            for (int ks4 = 0; ks4 < 4; ks4++) {
                int dwr = ((ks4 << 4) + (kg << 2)) ^ xsw;
                short8v pa = *reinterpret_cast<const short8v*>(&Pw[(a15 << 7) + (dwr << 1)]);
                int kc = (((half << 2) + ks4) << 2) + kg;
                short8v v0 = *reinterpret_cast<const short8v*>(&Vc[(kc * 33 + a15) * 8]);
                short8v v1 = *reinterpret_cast<const short8v*>(&Vc[(kc * 33 + 16 + a15) * 8]);
                o0 = __builtin_amdgcn_mfma_f32_16x16x32_bf16(pa, v0, o0, 0, 0, 0);
                o1 = __builtin_amdgcn_mfma_f32_16x16x32_bf16(pa, v1, o1, 0, 0, 0);
            }
            __builtin_amdgcn_s_setprio(0);
            __builtin_amdgcn_sched_barrier(0);
        }
        psum += __shfl_xor(psum, 16);
        psum += __shfl_xor(psum, 32);
        #pragma unroll
        for (int r = 0; r < 4; r++) {
            float pt = __shfl(psum, (kg << 2) + r);
            float inv = 1.f / pt;
            int g = base + strip * WW + (kg << 2) + r;
            ushortw* orow = out + (size_t)g * 192 + h * HD;
            orow[a15] = f2bf(o0[r] * inv);
            if (a15 < 14) orow[16 + a15] = f2bf(o1[r] * inv);
        }
    }
    if (h == 0) {   // zero pad cols 180..191
        for (int idx2 = tid; idx2 < NTOKW * 12; idx2 += 256) {
            int j = idx2 / 12, d = idx2 - (idx2 / 12) * 12;
            int gj = base + (j >> 4) * WW + (j & 15);
            out[(size_t)gj * 192 + 180 + d] = 0;
        }
    }
}

// ---------------- register-tiled depthwise 3x3 conv: 4 pixels x 4 channels / thread ----------------
template<int CIN_S, int COP, int OSTR, int DIL, int ACT, int OUTBF>
__global__ __launch_bounds__(256) void dwconv4_kernel(
    const ushortw* __restrict__ in, const float* __restrict__ wt,
    const float* __restrict__ bias, void* __restrict__ out)
{
    constexpr int NC4 = COP >> 2;
    constexpr int NX = 4 + 2 * DIL;
    int idx = blockIdx.x * 256 + threadIdx.x;
    int c4 = idx % NC4;
    int quad = idx / NC4;
    int c = c4 << 2;
    int pix0 = quad << 2;
    int p = pix0 & (IMG - 1);
    int imgbase = pix0 - p;
    int px0 = p & (WW - 1), py = p >> 7;

    float4 w9[9];
    #pragma unroll
    for (int t = 0; t < 9; t++)
        w9[t] = *reinterpret_cast<const float4*>(wt + t * COP + c);
    float4 bi4 = *reinterpret_cast<const float4*>(bias + c);
    float acc[4][4];
    #pragma unroll
    for (int i = 0; i < 4; i++) {
        acc[i][0] = bi4.x; acc[i][1] = bi4.y; acc[i][2] = bi4.z; acc[i][3] = bi4.w;
    }
    #pragma unroll
    for (int ky = 0; ky < 3; ky++) {
        int iy = py + (ky - 1) * DIL;
        if (iy < 0 || iy >= HH) continue;
        const ushortw* rowp = in + (size_t)(imgbase + (iy << 7)) * CIN_S + c;
        #pragma unroll
        for (int xx = 0; xx < NX; xx++) {
            int ix = px0 + xx - DIL;
            if (ix < 0 || ix >= WW) continue;
            short4v v = *reinterpret_cast<const short4v*>(rowp + (size_t)ix * CIN_S);
            float f0 = bf2f((ushortw)v[0]);
            float f1 = bf2f((ushortw)v[1]);
            float f2 = bf2f((ushortw)v[2]);
            float f3 = bf2f((ushortw)v[3]);
            #pragma unroll
            for (int kx = 0; kx < 3; kx++) {
                int i = xx - DIL * kx;
                if (i < 0 || i > 3) continue;
                float4 wv = w9[ky * 3 + kx];
                acc[i][0] = fmaf(f0, wv.x, acc[i][0]);
                acc[i][1] = fmaf(f1, wv.y, acc[i][1]);
                acc[i][2] = fmaf(f2, wv.z, acc[i][2]);
                acc[i][3] = fmaf(f3, wv.w, acc[i][3]);
            }
        }
    }
    if (COP != OSTR && c >= OSTR) return;
    #pragma unroll
    for (int i = 0; i < 4; i++) {
        #pragma unroll
        for (int e = 0; e < 4; e++) {
            float v = acc[i][e];
            if (ACT == 1) v = gelu_exact(v);
            else if (ACT == 2) v = fmaxf(v, 0.f);
            acc[i][e] = v;
        }
        if (OUTBF) {
            short4v o;
            o[0] = (short)f2bf(acc[i][0]); o[1] = (short)f2bf(acc[i][1]);
            o[2] = (short)f2bf(acc[i][2]); o[3] = (short)f2bf(acc[i][3]);
            *reinterpret_cast<short4v*>((ushortw*)out + (size_t)(pix0 + i) * OSTR + c) = o;
        } else {
            float4 o = make_float4(acc[i][0], acc[i][1], acc[i][2], acc[i][3]);
            *reinterpret_cast<float4*>((float*)out + (size_t)(pix0 + i) * OSTR + c) = o;
        }
    }
}

// ---------------- GAP partial sums over bf16 y4 (128-pixel chunks, 512 blocks) ----------------
__global__ void gap_kernel(const ushortw* __restrict__ y, float* __restrict__ part)
{
    int blk = blockIdx.x;              // 0..511
    int b = blk >> 7, chunk = blk & 127;
    int c = threadIdx.x;
    if (c >= CC) return;
    size_t basep = ((size_t)b * IMG + (size_t)chunk * 128) * CC;
    float s = 0.f;
    for (int p = 0; p < 128; p++) s += bf2f(y[basep + (size_t)p * CC + c]);
    part[((size_t)b * 128 + chunk) * CC + c] = s;
}

// ---------------- channel attention (tiny) ----------------
__global__ void ca_kernel(const float* __restrict__ part,
                          const float* __restrict__ w1, const float* __restrict__ b1,
                          const float* __restrict__ w2, const float* __restrict__ b2,
                          float* __restrict__ ca)
{
    __shared__ float gap[BB * CC];
    __shared__ float s1[BB * 6];
    int tid = threadIdx.x;
    for (int idx = tid; idx < BB * CC; idx += 256) {
        int b = idx / CC, c = idx % CC;
        float s = 0.f;
        for (int ch = 0; ch < 128; ch++) s += part[((size_t)b * 128 + ch) * CC + c];
        gap[idx] = s * (1.f / IMG);
    }
    __syncthreads();
    if (tid < BB * 6) {
        int b = tid / 6, cs = tid % 6;
        float s = 0.f;
        for (int c = 0; c < CC; c++) s += w1[cs * CC + c] * gap[b * CC + c];
        s1[tid] = fmaxf(s + b1[cs], 0.f);
    }
    __syncthreads();
    for (int idx = tid; idx < BB * CC; idx += 256) {
        int b = idx / CC, c = idx % CC;
        float s = b2[c];
        #pragma unroll
        for (int cs = 0; cs < 6; cs++) s += w2[c * 6 + cs] * s1[b * 6 + cs];
        ca[idx] = 1.f / (1.f + __expf(-s));
    }
}

// ---------------- x1(bf16) += 0.01*y4*ca; LN2 -> bf16 xn2 (stride 192) ----------------
__global__ __launch_bounds__(256) void resid_ln_kernel(
    ushortw* __restrict__ x1, const ushortw* __restrict__ y4, const float* __restrict__ ca,
    const float* __restrict__ g, const float* __restrict__ bb,
    ushortw* __restrict__ xn2)
{
    int wid = threadIdx.x >> 6, lane = threadIdx.x & 63;
    int t = blockIdx.x * 4 + wid;
    int b = t >> 14;
    size_t off = (size_t)t * CC;
    size_t off2 = (size_t)t * 192;
    bool has2 = lane < (CC - 128);
    float v0 = bf2f(x1[off+lane])    + 0.01f * bf2f(y4[off+lane])    * ca[b*CC + lane];
    float v1 = bf2f(x1[off+lane+64]) + 0.01f * bf2f(y4[off+lane+64]) * ca[b*CC + lane+64];
    float v2 = 0.f;
    if (has2) v2 = bf2f(x1[off+lane+128]) + 0.01f * bf2f(y4[off+lane+128]) * ca[b*CC + lane+128];
    x1[off+lane] = f2bf(v0); x1[off+lane+64] = f2bf(v1);
    if (has2) x1[off+lane+128] = f2bf(v2);
    float s = warp_sum(v0 + v1 + v2);
    float mu = s * (1.f / CC);
    float d0 = v0-mu, d1 = v1-mu, d2 = has2 ? v2-mu : 0.f;
    float var = warp_sum(d0*d0 + d1*d1 + d2*d2) * (1.f / CC);
    float rs = rsqrtf(var + 1e-5f);
    xn2[off2+lane]      = f2bf(d0 * rs * g[lane]      + bb[lane]);
    xn2[off2+lane+64]   = f2bf(d1 * rs * g[lane+64]   + bb[lane+64]);
    xn2[off2+lane+128]  = has2 ? f2bf(d2 * rs * g[lane+128] + bb[lane+128]) : (ushortw)0;
}

// ---------------- max/mean over channels per pixel (bf16 h3, stride 768, 720 cols) ----------------
__global__ __launch_bounds__(256) void mpap_kernel(
    const ushortw* __restrict__ h, float* __restrict__ mp, float* __restrict__ ap)
{
    int wid = threadIdx.x >> 6, lane = threadIdx.x & 63;
    int p = blockIdx.x * 4 + wid;
    const ushortw* row = h + (size_t)p * 768;
    float mx = -1e30f, s = 0.f;
    for (int j = lane; j < HID; j += 64) { float v = bf2f(row[j]); mx = fmaxf(mx, v); s += v; }
    mx = warp_max(mx); s = warp_sum(s);
    if (lane == 0) { mp[p] = mx; ap[p] = s * (1.f / HID); }
}

// ---------------- 7x7 spatial-attention conv + sigmoid (half batch = 2 images) ----------------
__global__ void saconv_kernel(const float* __restrict__ mp, const float* __restrict__ ap,
                              const float* __restrict__ w, float* __restrict__ sa)
{
    int p = blockIdx.x * blockDim.x + threadIdx.x;   // 0..HALFTOK-1
    int lp = p & (IMG - 1);
    int base = p - lp;
    int px = lp & (WW - 1), py = lp >> 7;
    float acc = 0.f;
    for (int ky = 0; ky < 7; ky++) {
        int iy = py + ky - 3;
        if (iy < 0 || iy >= HH) continue;
        for (int kx = 0; kx < 7; kx++) {
            int ix = px + kx - 3;
            if (ix < 0 || ix >= WW) continue;
            int pid = base + iy * WW + ix;
            acc += mp[pid] * w[ky * 7 + kx] + ap[pid] * w[49 + ky * 7 + kx];
        }
    }
    sa[p] = 1.f / (1.f + __expf(-acc));
}

extern "C" void kernel_launch(void* const* d_in, const int* in_sizes, int n_in,
                              void* d_out, int out_size, void* d_ws, size_t ws_size,
                              hipStream_t stream)
{
    const float* x      = (const float*)d_in[0];
    const int*   rpi    = (const int*)d_in[3];
    const float* n1g    = (const float*)d_in[4];
    const float* n1b    = (const float*)d_in[5];
    const float* rpb    = (const float*)d_in[6];
    const float* qkv_w  = (const float*)d_in[7];
    const float* qkv_b  = (const float*)d_in[8];
    const float* proj_w = (const float*)d_in[9];
    const float* proj_b = (const float*)d_in[10];
    const float* cab_w0 = (const float*)d_in[11];
    const float* cab_b0 = (const float*)d_in[12];
    const float* cab_w1 = (const float*)d_in[13];
    const float* cab_b1 = (const float*)d_in[14];
    const float* cab_w2 = (const float*)d_in[15];
    const float* cab_b2 = (const float*)d_in[16];
    const float* cab_w3 = (const float*)d_in[17];
    const float* cab_b3 = (const float*)d_in[18];
    const float* ca_w1  = (const float*)d_in[19];
    const float* ca_b1  = (const float*)d_in[20];
    const float* ca_w2  = (const float*)d_in[21];
    const float* ca_b2  = (const float*)d_in[22];
    const float* n2g    = (const float*)d_in[23];
    const float* n2b    = (const float*)d_in[24];
    const float* fc1_w  = (const float*)d_in[25];
    const float* fc1_b  = (const float*)d_in[26];
    const float* dw_w   = (const float*)d_in[27];
    const float* dw_b   = (const float*)d_in[28];
    const float* pw_w   = (const float*)d_in[29];
    const float* pw_b   = (const float*)d_in[30];
    const float* sa_w   = (const float*)d_in[31];
    const float* fc2_w  = (const float*)d_in[32];
    const float* fc2_b  = (const float*)d_in[33];
    float* outp = (float*)d_out;
    (void)in_sizes; (void)n_in; (void)out_size; (void)ws_size;

    char* ws = (char*)d_ws;
    const size_t S0 = (size_t)NTOK * 192 * 2;      // xnb -> xn2b
    const size_t S1 = (size_t)NTOK * QKVSTR * 2;   // qkvP -> y1b -> h1(half) -> h3(half)
    const size_t S2 = (size_t)NTOK * 192 * 2;      // attnbb -> y3b
    const size_t S3 = (size_t)NTOK * 180 * 4;      // x1 (bf16, region oversize ok)
    const size_t S4 = (size_t)NTOK * 128 * 2;      // y2b ; h2(half) spans S4+S5
    const size_t S5 = (size_t)NTOK * 180 * 4;      // y4 (bf16, region kept for h2 span)
    char* pA0 = ws;
    char* pA1 = pA0 + S0;
    char* pA2 = pA1 + S1;
    char* pA3 = pA2 + S2;
    char* pA4 = pA3 + S3;
    char* pA5 = pA4 + S4;
    char* tail = pA5 + S5;

    ushortw* xnb    = (ushortw*)pA0;           // [NTOK][192]
    ushortw* xn2b   = (ushortw*)pA0;
    ushortw* qkvP   = (ushortw*)pA1;           // [NTOK][576]
    ushortw* y1b    = (ushortw*)pA1;           // [NTOK][96]
    ushortw* h1     = (ushortw*)pA1;           // [HALFTOK][720]
    ushortw* h3     = (ushortw*)pA1;           // [HALFTOK][768]
    ushortw* attnbb = (ushortw*)pA2;           // [NTOK][192]
    ushortw* y3b    = (ushortw*)pA2;           // [NTOK][192]
    ushortw* x1b    = (ushortw*)pA3;           // [NTOK][180] bf16
    ushortw* y2b    = (ushortw*)pA4;           // [NTOK][128]
    ushortw* h2     = (ushortw*)pA4;           // [HALFTOK][768] spans S4+S5
    ushortw* y4     = (ushortw*)pA5;           // [NTOK][180] bf16

    // bf16 gemm weights (padded)
    ushortw* wqkv  = (ushortw*)tail;                        // alloc 640x192, used 576x192
    ushortw* wproj = wqkv  + 640 * 192;                     // 256 x 192
    ushortw* wcab0 = wproj + 256 * 192;                     // 128 x 192
    ushortw* wcab2 = wcab0 + 128 * 192;                     // 256 x 128
    ushortw* wfc1  = wcab2 + 256 * 128;                     // 768 x 192
    ushortw* wpw   = wfc1  + 768 * 192;                     // 768 x 768
    ushortw* wfc2  = wpw   + 768 * 768;                     // 256 x 768
    char* tail2 = (char*)(wfc2 + 256 * 768);
    float* dwt1 = (float*)tail2;                 float* db1 = dwt1 + 9*128;
    float* dwt2 = db1 + 128;                     float* db2 = dwt2 + 9*192;
    float* dwt3 = db2 + 192;                     float* db3 = dwt3 + 9*768;
    float* qb576 = db3 + 768;
    char* tail3 = (char*)(qb576 + 576);
    float* biasN = (float*)tail3;                           // 6*65536 fp32
    float* part  = (float*)(tail3 + 1572864);               // 4*128*180 fp32
    float* cabuf = (float*)(tail3 + 1572864 + 393216);
    float* mp    = (float*)(tail3 + 1572864 + 393216 + 4096);
    float* ap    = (float*)(tail3 + 1572864 + 393216 + 4096 + (size_t)HALFTOK * 4);
    float* sab   = (float*)(tail3 + 1572864 + 393216 + 4096 + 2*(size_t)HALFTOK * 4);

    auto gemm = [&](const ushortw* A, const ushortw* Wt, const float* bi, void* Cp,
                    int M, int N, int Kp, int ldc, int outbf, int zfill, int act, int residbf,
                    const float* rs, const void* resid) {
        int nM = M >> 7, nN = (N + 127) >> 7;
        mgemm_kernel<<<dim3(nM * nN), dim3(256), 0, stream>>>(
            A, Wt, bi, Cp, M, N, Kp, ldc, outbf, zfill, act, residbf, nN, rs, resid);
    };

    // 0) all weight/bias prep in one launch
    prep_kernel<<<dim3((1226880 + 255) / 256), dim3(256), 0, stream>>>(
        qkv_w, proj_w, cab_w0, cab_w2, fc1_w, pw_w, fc2_w,
        cab_w1, cab_b1, cab_w3, cab_b3, dw_w, dw_b, qkv_b, rpi, rpb,
        wqkv, wproj, wcab0, wcab2, wfc1, wpw, wfc2,
        dwt1, db1, dwt2, db2, dwt3, db3, qb576, biasN);

    // 1) LN1 -> bf16 xnb
    ln_kernel<<<dim3(NTOK / 4), dim3(256), 0, stream>>>(x, n1g, n1b, xnb);
    // 2) full-batch qkv (permuted weights -> padded layout directly) + MFMA attention
    gemm(xnb, wqkv, qb576, qkvP, NTOK, 576, 192, QKVSTR, 1, 0, 0, 0, nullptr, nullptr);
    attn_mfma_kernel<<<dim3(BB * 64 * NHEADS), dim3(256), 0, stream>>>(qkvP, biasN, attnbb);
    // 3) CAB part 1 (xnb consumed)
    gemm(xnb, wcab0, cab_b0, y1b, NTOK, 90, 192, 96, 1, 1, 0, 0, nullptr, nullptr);
    dwconv4_kernel<96, 128, 128, 1, 1, 1><<<dim3(NTOK / 4 * 32 / 256), dim3(256), 0, stream>>>(
        y1b, dwt1, db1, y2b);
    // 4) proj with residual x -> x1 (bf16)
    gemm(attnbb, wproj, proj_b, x1b, NTOK, 180, 192, 180, 1, 0, 0, 0, nullptr, x);
    // 5) CAB part 2
    gemm(y2b, wcab2, cab_b2, y3b, NTOK, 180, 128, 192, 1, 1, 0, 0, nullptr, nullptr);
    dwconv4_kernel<192, 192, 180, 2, 0, 1><<<dim3(NTOK / 4 * 48 / 256), dim3(256), 0, stream>>>(
        y3b, dwt2, db2, y4);
    gap_kernel<<<dim3(BB * 128), dim3(192), 0, stream>>>(y4, part);
    ca_kernel<<<dim3(1), dim3(256), 0, stream>>>(part, ca_w1, ca_b1, ca_w2, ca_b2, cabuf);
    // 6) x1 += 0.01*y4*ca; LN2 -> bf16 xn2b
    resid_ln_kernel<<<dim3(NTOK / 4), dim3(256), 0, stream>>>(x1b, y4, cabuf, n2g, n2b, xn2b);
    // 7) FFN in two half-batches (2 images each)
    for (int half = 0; half < 2; half++) {
        size_t toff = (size_t)half * HALFTOK;
        gemm(xn2b + toff * 192, wfc1, fc1_b, h1, HALFTOK, 720, 192, 720, 1, 0, 1, 0, nullptr, nullptr);
        dwconv4_kernel<720, 768, 768, 1, 2, 1><<<dim3(HALFTOK / 4 * 192 / 256), dim3(256), 0, stream>>>(
            h1, dwt3, db3, h2);
        gemm(h2, wpw, pw_b, h3, HALFTOK, 720, 768, 768, 1, 1, 2, 0, nullptr, nullptr);
        mpap_kernel<<<dim3(HALFTOK / 4), dim3(256), 0, stream>>>(h3, mp, ap);
        saconv_kernel<<<dim3(HALFTOK / 256), dim3(256), 0, stream>>>(mp, ap, sa_w, sab);
        gemm(h3, wfc2, fc2_b, outp + toff * 180, HALFTOK, 180, 768, 180, 0, 0, 0, 1,
             sab, x1b + toff * 180);
    }
}

// Round 12
// 754.916 us; speedup vs baseline: 4.6136x; 1.0582x over previous
//
#include <hip/hip_runtime.h>
#include <math.h>

#define HH 128
#define WW 128
#define CC 180
#define BB 4
#define IMG (HH*WW)          // 16384 tokens per image
#define NTOK (BB*IMG)        // 65536
#define HALFTOK (2*IMG)      // 32768
#define NHEADS 6
#define HD 30
#define WSZ 16
#define NTOKW (WSZ*WSZ)      // 256
#define HID 720
#define QKVSTR 672           // merged row: q/k/v (3x192) + cab0 (96)

typedef __attribute__((ext_vector_type(8))) short short8v;
typedef __attribute__((ext_vector_type(4))) short short4v;
typedef __attribute__((ext_vector_type(4))) float f32x4;
typedef unsigned short ushortw;

__device__ __forceinline__ float warp_sum(float v) {
    #pragma unroll
    for (int o = 32; o > 0; o >>= 1) v += __shfl_xor(v, o);
    return v;
}
__device__ __forceinline__ float warp_max(float v) {
    #pragma unroll
    for (int o = 32; o > 0; o >>= 1) v = fmaxf(v, __shfl_xor(v, o));
    return v;
}
__device__ __forceinline__ float gelu_exact(float v) {
    return 0.5f * v * (1.f + erff(v * 0.70710678118654752f));
}
__device__ __forceinline__ ushortw f2bf(float f) {
    union { float f; unsigned int u; } c; c.f = f;
    unsigned int r = (c.u + 0x7FFFu + ((c.u >> 16) & 1u)) >> 16;
    return (ushortw)r;
}
__device__ __forceinline__ float bf2f(ushortw u) {
    union { unsigned int u; float f; } c; c.u = ((unsigned int)u) << 16; return c.f;
}

// ---------------- fused weight/bias prep (one launch) ----------------
// J0 wqkvc [672][192] (q/k/v permuted + cab0 rows 576..665) | J1 wproj 256x192 |
// J2 wcab2 256x128 | J3 wfc1 768x192 | J4 wpw 768x768 | J5 wfc2 256x768 |
// J6-8 dw transposes | J9 qb672 | J10 biasN
__global__ __launch_bounds__(256) void prep_kernel(
    const float* __restrict__ qkv_w, const float* __restrict__ proj_w,
    const float* __restrict__ cab_w0, const float* __restrict__ cab_b0,
    const float* __restrict__ cab_w2,
    const float* __restrict__ fc1_w, const float* __restrict__ pw_w,
    const float* __restrict__ fc2_w,
    const float* __restrict__ cab_w1, const float* __restrict__ cab_b1,
    const float* __restrict__ cab_w3, const float* __restrict__ cab_b3,
    const float* __restrict__ dw_w, const float* __restrict__ dw_b,
    const float* __restrict__ qkv_b, const int* __restrict__ rpi,
    const float* __restrict__ rpb,
    ushortw* __restrict__ wqkvc, ushortw* __restrict__ wproj,
    ushortw* __restrict__ wcab2,
    ushortw* __restrict__ wfc1, ushortw* __restrict__ wpw, ushortw* __restrict__ wfc2,
    float* __restrict__ dwt1, float* __restrict__ db1,
    float* __restrict__ dwt2, float* __restrict__ db2,
    float* __restrict__ dwt3, float* __restrict__ db3,
    float* __restrict__ qb672, float* __restrict__ biasN)
{
    int idx = blockIdx.x * 256 + threadIdx.x;
    if (idx < 129024) {                              // J0: wqkvc [672][192]
        int r = idx / 192, k = idx - r * 192;
        float v = 0.f;
        if (r < 576) {
            int sub = r / 192, rem = r - sub * 192;
            int hh = rem >> 5, dd = rem & 31;
            if (dd < 30 && k < 180) v = qkv_w[(sub * 180 + hh * 30 + dd) * 180 + k];
        } else if (r < 666) {
            if (k < 180) v = cab_w0[(r - 576) * 180 + k];
        }
        wqkvc[idx] = f2bf(v);
    } else if (idx < 178176) {                       // J1: wproj [256][192]
        int l = idx - 129024; int r = l / 192, k = l - r * 192;
        wproj[l] = f2bf((r < 180 && k < 180) ? proj_w[r * 180 + k] : 0.f);
    } else if (idx < 210944) {                       // J2: wcab2 [256][128]
        int l = idx - 178176; int r = l / 128, k = l - r * 128;
        wcab2[l] = f2bf((r < 180 && k < 90) ? cab_w2[r * 90 + k] : 0.f);
    } else if (idx < 358400) {                       // J3: wfc1 [768][192]
        int l = idx - 210944; int r = l / 192, k = l - r * 192;
        wfc1[l] = f2bf((r < 720 && k < 180) ? fc1_w[r * 180 + k] : 0.f);
    } else if (idx < 948224) {                       // J4: wpw [768][768]
        int l = idx - 358400; int r = l / 768, k = l - r * 768;
        wpw[l] = f2bf((r < 720 && k < 720) ? pw_w[r * 720 + k] : 0.f);
    } else if (idx < 1144832) {                      // J5: wfc2 [256][768]
        int l = idx - 948224; int r = l / 768, k = l - r * 768;
        wfc2[l] = f2bf((r < 180 && k < 720) ? fc2_w[r * 720 + k] : 0.f);
    } else if (idx < 1145984) {                      // J6: dwt1 [9][128]
        int l = idx - 1144832; int c = l / 9, k = l - c * 9;
        dwt1[k * 128 + c] = (c < 90) ? cab_w1[c * 9 + k] : 0.f;
        if (k == 0) db1[c] = (c < 90) ? cab_b1[c] : 0.f;
    } else if (idx < 1147712) {                      // J7: dwt2 [9][192]
        int l = idx - 1145984; int c = l / 9, k = l - c * 9;
        dwt2[k * 192 + c] = (c < 180) ? cab_w3[c * 9 + k] : 0.f;
        if (k == 0) db2[c] = (c < 180) ? cab_b3[c] : 0.f;
    } else if (idx < 1154624) {                      // J8: dwt3 [9][768]
        int l = idx - 1147712; int c = l / 9, k = l - c * 9;
        dwt3[k * 768 + c] = (c < 720) ? dw_w[c * 9 + k] : 0.f;
        if (k == 0) db3[c] = (c < 720) ? dw_b[c] : 0.f;
    } else if (idx < 1155296) {                      // J9: qb672
        int l = idx - 1154624;
        float v = 0.f;
        if (l < 576) {
            int sub = l / 192, rem = l - sub * 192;
            int hh = rem >> 5, dd = rem & 31;
            if (dd < 30) v = qkv_b[sub * 180 + hh * 30 + dd];
        } else if (l < 666) {
            v = cab_b0[l - 576];
        }
        qb672[l] = v;
    } else if (idx < 1220832) {                      // J10: biasN [6][65536]
        int l = idx - 1155296;
        int r = rpi[l];
        #pragma unroll
        for (int h = 0; h < NHEADS; h++)
            biasN[((size_t)h << 16) + l] = rpb[r * NHEADS + h];
    }
}

// ---------------- LayerNorm -> bf16 out, stride 192 (cols 180..191 zero) ----------------
__global__ __launch_bounds__(256) void ln_kernel(
    const float* __restrict__ x, const float* __restrict__ g,
    const float* __restrict__ b, ushortw* __restrict__ out)
{
    int wid = threadIdx.x >> 6, lane = threadIdx.x & 63;
    int t = blockIdx.x * 4 + wid;
    size_t off = (size_t)t * CC;
    size_t off2 = (size_t)t * 192;
    bool has2 = lane < (CC - 128);
    float v0 = x[off + lane];
    float v1 = x[off + lane + 64];
    float v2 = has2 ? x[off + lane + 128] : 0.f;
    float s = warp_sum(v0 + v1 + v2);
    float mu = s * (1.f / CC);
    float d0 = v0 - mu, d1 = v1 - mu, d2 = has2 ? v2 - mu : 0.f;
    float var = warp_sum(d0*d0 + d1*d1 + d2*d2) * (1.f / CC);
    float rs = rsqrtf(var + 1e-5f);
    out[off2 + lane]      = f2bf(d0 * rs * g[lane]      + b[lane]);
    out[off2 + lane + 64] = f2bf(d1 * rs * g[lane + 64] + b[lane + 64]);
    out[off2 + lane + 128] = has2 ? f2bf(d2 * rs * g[lane + 128] + b[lane + 128]) : (ushortw)0;
}

// ---------------- bf16 MFMA GEMM: BK=32 double-buffered, XCD swizzle ----------------
// LDS 32 KB total -> ~5 blocks/CU. Swizzle f(r)=(r&3)^((r>>2)&3) on source chunk + read slot.
__global__ __launch_bounds__(256) void mgemm_kernel(
    const ushortw* __restrict__ A, const ushortw* __restrict__ Wt,
    const float* __restrict__ bias, void* __restrict__ Cout,
    int M, int N, int Kp, int ldc, int outbf, int zfill, int act, int residbf, int nN,
    const float* __restrict__ rowscale, const void* __restrict__ residv)
{
    __shared__ ushortw sA[2][128 * 32];
    __shared__ ushortw sB[2][128 * 32];
    int tid = threadIdx.x, lane = tid & 63, wid = tid >> 6;
    int total = (int)gridDim.x;
    int orig = blockIdx.x;
    int q = total >> 3, r = total & 7;
    int xcd = orig & 7, slot = orig >> 3;
    int wgid = (xcd < r ? xcd * (q + 1) : r * (q + 1) + (xcd - r) * q) + slot;
    int mp = wgid / nN, np = wgid - mp * nN;
    int m0 = mp << 7, n0 = np << 7;
    int wm = (wid >> 1) << 6, wn = (wid & 1) << 6;
    int lrow = lane & 15, kgrp = lane >> 4;

    f32x4 acc[4][4];
    #pragma unroll
    for (int i = 0; i < 4; i++)
        #pragma unroll
        for (int j = 0; j < 4; j++)
            #pragma unroll
            for (int rr = 0; rr < 4; rr++) acc[i][j][rr] = 0.f;

    int nk = Kp >> 5;
    // prologue: stage tile 0 into buffer 0
    #pragma unroll
    for (int qq = 0; qq < 2; qq++) {
        int seg = (wid << 1) + qq;                 // 0..7
        int row = (seg << 4) + (lane >> 2);        // 0..127
        int cg = (lane & 3) ^ (row & 3) ^ ((row >> 2) & 3);
        const ushortw* ga = A + (size_t)(m0 + row) * Kp + (cg << 3);
        __builtin_amdgcn_global_load_lds(
            (const __attribute__((address_space(1))) void*)ga,
            (__attribute__((address_space(3))) void*)&sA[0][seg << 9], 16, 0, 0);
        const ushortw* gb = Wt + (size_t)(n0 + row) * Kp + (cg << 3);
        __builtin_amdgcn_global_load_lds(
            (const __attribute__((address_space(1))) void*)gb,
            (__attribute__((address_space(3))) void*)&sB[0][seg << 9], 16, 0, 0);
    }
    __syncthreads();

    int cur = 0;
    for (int t = 0; t < nk; t++) {
        if (t + 1 < nk) {
            int kk2 = (t + 1) << 5;
            #pragma unroll
            for (int qq = 0; qq < 2; qq++) {
                int seg = (wid << 1) + qq;
                int row = (seg << 4) + (lane >> 2);
                int cg = (lane & 3) ^ (row & 3) ^ ((row >> 2) & 3);
                const ushortw* ga = A + (size_t)(m0 + row) * Kp + kk2 + (cg << 3);
                __builtin_amdgcn_global_load_lds(
                    (const __attribute__((address_space(1))) void*)ga,
                    (__attribute__((address_space(3))) void*)&sA[cur ^ 1][seg << 9], 16, 0, 0);
                const ushortw* gb = Wt + (size_t)(n0 + row) * Kp + kk2 + (cg << 3);
                __builtin_amdgcn_global_load_lds(
                    (const __attribute__((address_space(1))) void*)gb,
                    (__attribute__((address_space(3))) void*)&sB[cur ^ 1][seg << 9], 16, 0, 0);
            }
        }
        short8v a[4], b[4];
        #pragma unroll
        for (int i = 0; i < 4; i++) {
            int rr = wm + (i << 4) + lrow;
            int slot2 = kgrp ^ (rr & 3) ^ ((rr >> 2) & 3);
            a[i] = *reinterpret_cast<const short8v*>(&sA[cur][(rr << 5) + (slot2 << 3)]);
        }
        #pragma unroll
        for (int j = 0; j < 4; j++) {
            int rr = wn + (j << 4) + lrow;
            int slot2 = kgrp ^ (rr & 3) ^ ((rr >> 2) & 3);
            b[j] = *reinterpret_cast<const short8v*>(&sB[cur][(rr << 5) + (slot2 << 3)]);
        }
        #pragma unroll
        for (int i = 0; i < 4; i++)
            #pragma unroll
            for (int j = 0; j < 4; j++)
                acc[i][j] = __builtin_amdgcn_mfma_f32_16x16x32_bf16(a[i], b[j], acc[i][j], 0, 0, 0);
        __syncthreads();   // drains next-tile stage + all reads of cur done
        cur ^= 1;
    }
    #pragma unroll
    for (int i = 0; i < 4; i++) {
        int rowb = m0 + wm + (i << 4) + (kgrp << 2);
        #pragma unroll
        for (int j = 0; j < 4; j++) {
            int col = n0 + wn + (j << 4) + lrow;
            if (col < N) {
                float bi = bias[col];
                #pragma unroll
                for (int rr = 0; rr < 4; rr++) {
                    int row = rowb + rr;
                    float v = acc[i][j][rr];
                    if (rowscale) v *= rowscale[row];
                    v += bi;
                    if (act == 1) v = gelu_exact(v);
                    else if (act == 2) v = fmaxf(v, 0.f);
                    if (residv) {
                        v += residbf ? bf2f(((const ushortw*)residv)[(size_t)row * N + col])
                                     : ((const float*)residv)[(size_t)row * N + col];
                    }
                    if (outbf) ((ushortw*)Cout)[(size_t)row * ldc + col] = f2bf(v);
                    else       ((float*)Cout)[(size_t)row * ldc + col] = v;
                }
            } else if (zfill && col < ldc) {
                #pragma unroll
                for (int rr = 0; rr < 4; rr++) {
                    int row = rowb + rr;
                    if (outbf) ((ushortw*)Cout)[(size_t)row * ldc + col] = 0;
                    else       ((float*)Cout)[(size_t)row * ldc + col] = 0.f;
                }
            }
        }
    }
}

// ---------------- MFMA window attention (swapped QK^T): block = (img, win, head) ----------------
__global__ __launch_bounds__(256, 3) void attn_mfma_kernel(
    const ushortw* __restrict__ qkvP, const float* __restrict__ biasN,
    ushortw* __restrict__ out)
{
    __shared__ ushortw Vc[32 * 33 * 8];      // 16896 B
    __shared__ ushortw Kc[256 * 32];         // 16384 B
    __shared__ ushortw Pl[4][2048];          // 16384 B
    const float SCALE = 0.18257418583505536f;   // 30^-0.5
    int blk = blockIdx.x;
    int img = blk / 384;
    int rem = blk - img * 384;
    int win = rem / NHEADS;
    int h = rem - win * NHEADS;
    int base = img * IMG + (win >> 3) * WSZ * WW + (win & 7) * WSZ;
    int tid = threadIdx.x;
    int lane = tid & 63, w = tid >> 6;
    int a15 = lane & 15, kg = lane >> 4;

    {
        int j = tid;
        int g = base + (j >> 4) * WW + (j & 15);
        const ushortw* vp = qkvP + (size_t)g * QKVSTR + 384 + h * 32;
        short8v c0 = *reinterpret_cast<const short8v*>(vp);
        short8v c1 = *reinterpret_cast<const short8v*>(vp + 8);
        short8v c2 = *reinterpret_cast<const short8v*>(vp + 16);
        short8v c3 = *reinterpret_cast<const short8v*>(vp + 24);
        int bo = (j >> 3) * 264 + (j & 7);
        #pragma unroll
        for (int e = 0; e < 8; e++)  Vc[bo + (e) * 8]      = (ushortw)c0[e];
        #pragma unroll
        for (int e = 0; e < 8; e++)  Vc[bo + (8 + e) * 8]  = (ushortw)c1[e];
        #pragma unroll
        for (int e = 0; e < 8; e++)  Vc[bo + (16 + e) * 8] = (ushortw)c2[e];
        #pragma unroll
        for (int e = 0; e < 8; e++)  Vc[bo + (24 + e) * 8] = (ushortw)c3[e];
        const ushortw* kp = qkvP + (size_t)g * QKVSTR + 192 + h * 32;
        short8v k0 = *reinterpret_cast<const short8v*>(kp);
        short8v k1 = *reinterpret_cast<const short8v*>(kp + 8);
        short8v k2 = *reinterpret_cast<const short8v*>(kp + 16);
        short8v k3 = *reinterpret_cast<const short8v*>(kp + 24);
        short8v* krow = reinterpret_cast<short8v*>(&Kc[j * 32]);
        int jsw = j & 3;
        krow[0 ^ jsw] = k0; krow[1 ^ jsw] = k1; krow[2 ^ jsw] = k2; krow[3 ^ jsw] = k3;
    }
    __syncthreads();

    ushortw* Pw = &Pl[w][0];
    int xsw = (a15 & 7) << 2;                // P dword-XOR per q-row
    f32x4 zf = {0.f, 0.f, 0.f, 0.f};
    #pragma unroll 1
    for (int si = 0; si < 4; si++) {
        int strip = (w << 2) + si;
        short8v qf = *reinterpret_cast<const short8v*>(
            qkvP + (size_t)(base + strip * WW + a15) * QKVSTR + h * 32 + (kg << 3));
        float psum = 0.f;
        f32x4 o0 = zf, o1 = zf;
        const float* brow = biasN + ((size_t)h << 16) + (size_t)((strip << 4) + a15) * 256;
        #pragma unroll 1
        for (int half = 0; half < 2; half++) {
            f32x4 s[8];
            __builtin_amdgcn_s_setprio(1);
            #pragma unroll
            for (int j8 = 0; j8 < 8; j8++) {
                int jt = (half << 3) + j8;
                int row = (jt << 4) + a15;
                short8v ka = reinterpret_cast<const short8v*>(&Kc[row * 32])[kg ^ (row & 3)];
                s[j8] = __builtin_amdgcn_mfma_f32_16x16x32_bf16(ka, qf, zf, 0, 0, 0);
            }
            __builtin_amdgcn_s_setprio(0);
            #pragma unroll
            for (int j8 = 0; j8 < 8; j8++) {
                int jt = (half << 3) + j8;
                float4 b4 = *reinterpret_cast<const float4*>(brow + (jt << 4) + (kg << 2));
                float p0 = __expf(fmaf(s[j8][0], SCALE, b4.x));
                float p1 = __expf(fmaf(s[j8][1], SCALE, b4.y));
                float p2 = __expf(fmaf(s[j8][2], SCALE, b4.z));
                float p3 = __expf(fmaf(s[j8][3], SCALE, b4.w));
                psum += (p0 + p1) + (p2 + p3);
                unsigned int u0, u1;
                asm("v_cvt_pk_bf16_f32 %0, %1, %2" : "=v"(u0) : "v"(p0), "v"(p1));
                asm("v_cvt_pk_bf16_f32 %0, %1, %2" : "=v"(u1) : "v"(p2), "v"(p3));
                int dw0 = ((j8 << 3) + (kg << 1)) ^ xsw;
                unsigned long long pk64 = (unsigned long long)u0 | ((unsigned long long)u1 << 32);
                *reinterpret_cast<unsigned long long*>(&Pw[(a15 << 7) + (dw0 << 1)]) = pk64;
            }
            __builtin_amdgcn_sched_barrier(0);
            __builtin_amdgcn_s_setprio(1);
            #pragma unroll
            for (int ks4 = 0; ks4 < 4; ks4++) {
                int dwr = ((ks4 << 4) + (kg << 2)) ^ xsw;
                short8v pa = *reinterpret_cast<const short8v*>(&Pw[(a15 << 7) + (dwr << 1)]);
                int kc = (((half << 2) + ks4) << 2) + kg;
                short8v v0 = *reinterpret_cast<const short8v*>(&Vc[(kc * 33 + a15) * 8]);
                short8v v1 = *reinterpret_cast<const short8v*>(&Vc[(kc * 33 + 16 + a15) * 8]);
                o0 = __builtin_amdgcn_mfma_f32_16x16x32_bf16(pa, v0, o0, 0, 0, 0);
                o1 = __builtin_amdgcn_mfma_f32_16x16x32_bf16(pa, v1, o1, 0, 0, 0);
            }
            __builtin_amdgcn_s_setprio(0);
            __builtin_amdgcn_sched_barrier(0);
        }
        psum += __shfl_xor(psum, 16);
        psum += __shfl_xor(psum, 32);
        #pragma unroll
        for (int r = 0; r < 4; r++) {
            float pt = __shfl(psum, (kg << 2) + r);
            float inv = 1.f / pt;
            int g = base + strip * WW + (kg << 2) + r;
            ushortw* orow = out + (size_t)g * 192 + h * HD;
            orow[a15] = f2bf(o0[r] * inv);
            if (a15 < 14) orow[16 + a15] = f2bf(o1[r] * inv);
        }
    }
    if (h == 0) {   // zero pad cols 180..191
        for (int idx2 = tid; idx2 < NTOKW * 12; idx2 += 256) {
            int j = idx2 / 12, d = idx2 - (idx2 / 12) * 12;
            int gj = base + (j >> 4) * WW + (j & 15);
            out[(size_t)gj * 192 + 180 + d] = 0;
        }
    }
}

// ---------------- register-tiled depthwise 3x3 conv: 4 pixels x 4 channels / thread ----------------
template<int CIN_S, int COP, int OSTR, int DIL, int ACT, int OUTBF>
__global__ __launch_bounds__(256) void dwconv4_kernel(
    const ushortw* __restrict__ in, const float* __restrict__ wt,
    const float* __restrict__ bias, void* __restrict__ out)
{
    constexpr int NC4 = COP >> 2;
    constexpr int NX = 4 + 2 * DIL;
    int idx = blockIdx.x * 256 + threadIdx.x;
    int c4 = idx % NC4;
    int quad = idx / NC4;
    int c = c4 << 2;
    int pix0 = quad << 2;
    int p = pix0 & (IMG - 1);
    int imgbase = pix0 - p;
    int px0 = p & (WW - 1), py = p >> 7;

    float4 w9[9];
    #pragma unroll
    for (int t = 0; t < 9; t++)
        w9[t] = *reinterpret_cast<const float4*>(wt + t * COP + c);
    float4 bi4 = *reinterpret_cast<const float4*>(bias + c);
    float acc[4][4];
    #pragma unroll
    for (int i = 0; i < 4; i++) {
        acc[i][0] = bi4.x; acc[i][1] = bi4.y; acc[i][2] = bi4.z; acc[i][3] = bi4.w;
    }
    #pragma unroll
    for (int ky = 0; ky < 3; ky++) {
        int iy = py + (ky - 1) * DIL;
        if (iy < 0 || iy >= HH) continue;
        const ushortw* rowp = in + (size_t)(imgbase + (iy << 7)) * CIN_S + c;
        #pragma unroll
        for (int xx = 0; xx < NX; xx++) {
            int ix = px0 + xx - DIL;
            if (ix < 0 || ix >= WW) continue;
            short4v v = *reinterpret_cast<const short4v*>(rowp + (size_t)ix * CIN_S);
            float f0 = bf2f((ushortw)v[0]);
            float f1 = bf2f((ushortw)v[1]);
            float f2 = bf2f((ushortw)v[2]);
            float f3 = bf2f((ushortw)v[3]);
            #pragma unroll
            for (int kx = 0; kx < 3; kx++) {
                int i = xx - DIL * kx;
                if (i < 0 || i > 3) continue;
                float4 wv = w9[ky * 3 + kx];
                acc[i][0] = fmaf(f0, wv.x, acc[i][0]);
                acc[i][1] = fmaf(f1, wv.y, acc[i][1]);
                acc[i][2] = fmaf(f2, wv.z, acc[i][2]);
                acc[i][3] = fmaf(f3, wv.w, acc[i][3]);
            }
        }
    }
    if (COP != OSTR && c >= OSTR) return;
    #pragma unroll
    for (int i = 0; i < 4; i++) {
        #pragma unroll
        for (int e = 0; e < 4; e++) {
            float v = acc[i][e];
            if (ACT == 1) v = gelu_exact(v);
            else if (ACT == 2) v = fmaxf(v, 0.f);
            acc[i][e] = v;
        }
        if (OUTBF) {
            short4v o;
            o[0] = (short)f2bf(acc[i][0]); o[1] = (short)f2bf(acc[i][1]);
            o[2] = (short)f2bf(acc[i][2]); o[3] = (short)f2bf(acc[i][3]);
            *reinterpret_cast<short4v*>((ushortw*)out + (size_t)(pix0 + i) * OSTR + c) = o;
        } else {
            float4 o = make_float4(acc[i][0], acc[i][1], acc[i][2], acc[i][3]);
            *reinterpret_cast<float4*>((float*)out + (size_t)(pix0 + i) * OSTR + c) = o;
        }
    }
}

// ---------------- GAP partial sums over bf16 y4 (128-pixel chunks, 512 blocks) ----------------
__global__ void gap_kernel(const ushortw* __restrict__ y, float* __restrict__ part)
{
    int blk = blockIdx.x;              // 0..511
    int b = blk >> 7, chunk = blk & 127;
    int c = threadIdx.x;
    if (c >= CC) return;
    size_t basep = ((size_t)b * IMG + (size_t)chunk * 128) * CC;
    float s = 0.f;
    for (int p = 0; p < 128; p++) s += bf2f(y[basep + (size_t)p * CC + c]);
    part[((size_t)b * 128 + chunk) * CC + c] = s;
}

// ---------------- channel attention (tiny) ----------------
__global__ void ca_kernel(const float* __restrict__ part,
                          const float* __restrict__ w1, const float* __restrict__ b1,
                          const float* __restrict__ w2, const float* __restrict__ b2,
                          float* __restrict__ ca)
{
    __shared__ float gap[BB * CC];
    __shared__ float s1[BB * 6];
    int tid = threadIdx.x;
    for (int idx = tid; idx < BB * CC; idx += 256) {
        int b = idx / CC, c = idx % CC;
        float s = 0.f;
        for (int ch = 0; ch < 128; ch++) s += part[((size_t)b * 128 + ch) * CC + c];
        gap[idx] = s * (1.f / IMG);
    }
    __syncthreads();
    if (tid < BB * 6) {
        int b = tid / 6, cs = tid % 6;
        float s = 0.f;
        for (int c = 0; c < CC; c++) s += w1[cs * CC + c] * gap[b * CC + c];
        s1[tid] = fmaxf(s + b1[cs], 0.f);
    }
    __syncthreads();
    for (int idx = tid; idx < BB * CC; idx += 256) {
        int b = idx / CC, c = idx % CC;
        float s = b2[c];
        #pragma unroll
        for (int cs = 0; cs < 6; cs++) s += w2[c * 6 + cs] * s1[b * 6 + cs];
        ca[idx] = 1.f / (1.f + __expf(-s));
    }
}

// ---------------- x1(bf16) += 0.01*y4*ca; LN2 -> bf16 xn2 (stride 192) ----------------
__global__ __launch_bounds__(256) void resid_ln_kernel(
    ushortw* __restrict__ x1, const ushortw* __restrict__ y4, const float* __restrict__ ca,
    const float* __restrict__ g, const float* __restrict__ bb,
    ushortw* __restrict__ xn2)
{
    int wid = threadIdx.x >> 6, lane = threadIdx.x & 63;
    int t = blockIdx.x * 4 + wid;
    int b = t >> 14;
    size_t off = (size_t)t * CC;
    size_t off2 = (size_t)t * 192;
    bool has2 = lane < (CC - 128);
    float v0 = bf2f(x1[off+lane])    + 0.01f * bf2f(y4[off+lane])    * ca[b*CC + lane];
    float v1 = bf2f(x1[off+lane+64]) + 0.01f * bf2f(y4[off+lane+64]) * ca[b*CC + lane+64];
    float v2 = 0.f;
    if (has2) v2 = bf2f(x1[off+lane+128]) + 0.01f * bf2f(y4[off+lane+128]) * ca[b*CC + lane+128];
    x1[off+lane] = f2bf(v0); x1[off+lane+64] = f2bf(v1);
    if (has2) x1[off+lane+128] = f2bf(v2);
    float s = warp_sum(v0 + v1 + v2);
    float mu = s * (1.f / CC);
    float d0 = v0-mu, d1 = v1-mu, d2 = has2 ? v2-mu : 0.f;
    float var = warp_sum(d0*d0 + d1*d1 + d2*d2) * (1.f / CC);
    float rs = rsqrtf(var + 1e-5f);
    xn2[off2+lane]      = f2bf(d0 * rs * g[lane]      + bb[lane]);
    xn2[off2+lane+64]   = f2bf(d1 * rs * g[lane+64]   + bb[lane+64]);
    xn2[off2+lane+128]  = has2 ? f2bf(d2 * rs * g[lane+128] + bb[lane+128]) : (ushortw)0;
}

// ---------------- max/mean over channels per pixel (bf16 h3, stride 768, 720 cols) ----------------
__global__ __launch_bounds__(256) void mpap_kernel(
    const ushortw* __restrict__ h, float* __restrict__ mp, float* __restrict__ ap)
{
    int wid = threadIdx.x >> 6, lane = threadIdx.x & 63;
    int p = blockIdx.x * 4 + wid;
    const ushortw* row = h + (size_t)p * 768;
    float mx = -1e30f, s = 0.f;
    for (int j = lane; j < HID; j += 64) { float v = bf2f(row[j]); mx = fmaxf(mx, v); s += v; }
    mx = warp_max(mx); s = warp_sum(s);
    if (lane == 0) { mp[p] = mx; ap[p] = s * (1.f / HID); }
}

// ---------------- 7x7 spatial-attention conv + sigmoid (half batch = 2 images) ----------------
__global__ void saconv_kernel(const float* __restrict__ mp, const float* __restrict__ ap,
                              const float* __restrict__ w, float* __restrict__ sa)
{
    int p = blockIdx.x * blockDim.x + threadIdx.x;   // 0..HALFTOK-1
    int lp = p & (IMG - 1);
    int base = p - lp;
    int px = lp & (WW - 1), py = lp >> 7;
    float acc = 0.f;
    for (int ky = 0; ky < 7; ky++) {
        int iy = py + ky - 3;
        if (iy < 0 || iy >= HH) continue;
        for (int kx = 0; kx < 7; kx++) {
            int ix = px + kx - 3;
            if (ix < 0 || ix >= WW) continue;
            int pid = base + iy * WW + ix;
            acc += mp[pid] * w[ky * 7 + kx] + ap[pid] * w[49 + ky * 7 + kx];
        }
    }
    sa[p] = 1.f / (1.f + __expf(-acc));
}

extern "C" void kernel_launch(void* const* d_in, const int* in_sizes, int n_in,
                              void* d_out, int out_size, void* d_ws, size_t ws_size,
                              hipStream_t stream)
{
    const float* x      = (const float*)d_in[0];
    const int*   rpi    = (const int*)d_in[3];
    const float* n1g    = (const float*)d_in[4];
    const float* n1b    = (const float*)d_in[5];
    const float* rpb    = (const float*)d_in[6];
    const float* qkv_w  = (const float*)d_in[7];
    const float* qkv_b  = (const float*)d_in[8];
    const float* proj_w = (const float*)d_in[9];
    const float* proj_b = (const float*)d_in[10];
    const float* cab_w0 = (const float*)d_in[11];
    const float* cab_b0 = (const float*)d_in[12];
    const float* cab_w1 = (const float*)d_in[13];
    const float* cab_b1 = (const float*)d_in[14];
    const float* cab_w2 = (const float*)d_in[15];
    const float* cab_b2 = (const float*)d_in[16];
    const float* cab_w3 = (const float*)d_in[17];
    const float* cab_b3 = (const float*)d_in[18];
    const float* ca_w1  = (const float*)d_in[19];
    const float* ca_b1  = (const float*)d_in[20];
    const float* ca_w2  = (const float*)d_in[21];
    const float* ca_b2  = (const float*)d_in[22];
    const float* n2g    = (const float*)d_in[23];
    const float* n2b    = (const float*)d_in[24];
    const float* fc1_w  = (const float*)d_in[25];
    const float* fc1_b  = (const float*)d_in[26];
    const float* dw_w   = (const float*)d_in[27];
    const float* dw_b   = (const float*)d_in[28];
    const float* pw_w   = (const float*)d_in[29];
    const float* pw_b   = (const float*)d_in[30];
    const float* sa_w   = (const float*)d_in[31];
    const float* fc2_w  = (const float*)d_in[32];
    const float* fc2_b  = (const float*)d_in[33];
    float* outp = (float*)d_out;
    (void)in_sizes; (void)n_in; (void)out_size; (void)ws_size;

    char* ws = (char*)d_ws;
    const size_t S0 = (size_t)NTOK * 192 * 2;            // xnb -> xn2b
    const size_t S1 = (size_t)NTOK * QKVSTR * 2 + 256;   // qkvP(+y1) -> h1(half) -> h3(half)
    const size_t S2 = (size_t)NTOK * 192 * 2;            // attnbb -> y3b
    const size_t S3 = (size_t)NTOK * 180 * 2;            // x1b bf16
    const size_t S4 = (size_t)NTOK * 128 * 2;            // y2b ; h2(half) spans S4+S5
    const size_t S5 = (size_t)NTOK * 180 * 4;            // y4 bf16 (region kept for h2 span)
    char* pA0 = ws;
    char* pA1 = pA0 + S0;
    char* pA2 = pA1 + S1;
    char* pA3 = pA2 + S2;
    char* pA4 = pA3 + S3;
    char* pA5 = pA4 + S4;
    char* tail = pA5 + S5;

    ushortw* xnb    = (ushortw*)pA0;           // [NTOK][192]
    ushortw* xn2b   = (ushortw*)pA0;
    ushortw* qkvP   = (ushortw*)pA1;           // [NTOK][672] (cols 576.. = cab0 out)
    ushortw* h1     = (ushortw*)pA1;           // [HALFTOK][720]
    ushortw* h3     = (ushortw*)pA1;           // [HALFTOK][768]
    ushortw* attnbb = (ushortw*)pA2;           // [NTOK][192]
    ushortw* y3b    = (ushortw*)pA2;           // [NTOK][192]
    ushortw* x1b    = (ushortw*)pA3;           // [NTOK][180] bf16
    ushortw* y2b    = (ushortw*)pA4;           // [NTOK][128]
    ushortw* h2     = (ushortw*)pA4;           // [HALFTOK][768] spans S4+S5
    ushortw* y4     = (ushortw*)pA5;           // [NTOK][180] bf16

    // bf16 gemm weights
    ushortw* wqkvc = (ushortw*)tail;                        // 672 x 192 (+tile-overread slack ok)
    ushortw* wproj = wqkvc + 672 * 192;                     // 256 x 192
    ushortw* wcab2 = wproj + 256 * 192;                     // 256 x 128
    ushortw* wfc1  = wcab2 + 256 * 128;                     // 768 x 192
    ushortw* wpw   = wfc1  + 768 * 192;                     // 768 x 768
    ushortw* wfc2  = wpw   + 768 * 768;                     // 256 x 768
    char* tail2 = (char*)(wfc2 + 256 * 768);
    float* dwt1 = (float*)tail2;                 float* db1 = dwt1 + 9*128;
    float* dwt2 = db1 + 128;                     float* db2 = dwt2 + 9*192;
    float* dwt3 = db2 + 192;                     float* db3 = dwt3 + 9*768;
    float* qb672 = db3 + 768;
    char* tail3 = (char*)(qb672 + 672);
    float* biasN = (float*)tail3;                           // 6*65536 fp32
    float* part  = (float*)(tail3 + 1572864);               // 4*128*180 fp32
    float* cabuf = (float*)(tail3 + 1572864 + 393216);
    float* mp    = (float*)(tail3 + 1572864 + 393216 + 4096);
    float* ap    = (float*)(tail3 + 1572864 + 393216 + 4096 + (size_t)HALFTOK * 4);
    float* sab   = (float*)(tail3 + 1572864 + 393216 + 4096 + 2*(size_t)HALFTOK * 4);

    auto gemm = [&](const ushortw* A, const ushortw* Wt, const float* bi, void* Cp,
                    int M, int N, int Kp, int ldc, int outbf, int zfill, int act, int residbf,
                    const float* rs, const void* resid) {
        int nM = M >> 7, nN = (N + 127) >> 7;
        mgemm_kernel<<<dim3(nM * nN), dim3(256), 0, stream>>>(
            A, Wt, bi, Cp, M, N, Kp, ldc, outbf, zfill, act, residbf, nN, rs, resid);
    };

    // 0) all weight/bias prep in one launch
    prep_kernel<<<dim3((1220832 + 255) / 256), dim3(256), 0, stream>>>(
        qkv_w, proj_w, cab_w0, cab_b0, cab_w2, fc1_w, pw_w, fc2_w,
        cab_w1, cab_b1, cab_w3, cab_b3, dw_w, dw_b, qkv_b, rpi, rpb,
        wqkvc, wproj, wcab2, wfc1, wpw, wfc2,
        dwt1, db1, dwt2, db2, dwt3, db3, qb672, biasN);

    // 1) LN1 -> bf16 xnb
    ln_kernel<<<dim3(NTOK / 4), dim3(256), 0, stream>>>(x, n1g, n1b, xnb);
    // 2) merged qkv+cab0 GEMM -> qkvP[NTOK][672]; then attention + CAB dwconv1
    gemm(xnb, wqkvc, qb672, qkvP, NTOK, 672, 192, QKVSTR, 1, 0, 0, 0, nullptr, nullptr);
    attn_mfma_kernel<<<dim3(BB * 64 * NHEADS), dim3(256), 0, stream>>>(qkvP, biasN, attnbb);
    dwconv4_kernel<672, 128, 128, 1, 1, 1><<<dim3(NTOK / 4 * 32 / 256), dim3(256), 0, stream>>>(
        qkvP + 576, dwt1, db1, y2b);
    // 3) proj with residual x -> x1 (bf16)
    gemm(attnbb, wproj, proj_b, x1b, NTOK, 180, 192, 180, 1, 0, 0, 0, nullptr, x);
    // 4) CAB part 2
    gemm(y2b, wcab2, cab_b2, y3b, NTOK, 180, 128, 192, 1, 1, 0, 0, nullptr, nullptr);
    dwconv4_kernel<192, 192, 180, 2, 0, 1><<<dim3(NTOK / 4 * 48 / 256), dim3(256), 0, stream>>>(
        y3b, dwt2, db2, y4);
    gap_kernel<<<dim3(BB * 128), dim3(192), 0, stream>>>(y4, part);
    ca_kernel<<<dim3(1), dim3(256), 0, stream>>>(part, ca_w1, ca_b1, ca_w2, ca_b2, cabuf);
    // 5) x1 += 0.01*y4*ca; LN2 -> bf16 xn2b
    resid_ln_kernel<<<dim3(NTOK / 4), dim3(256), 0, stream>>>(x1b, y4, cabuf, n2g, n2b, xn2b);
    // 6) FFN in two half-batches (2 images each)
    for (int half = 0; half < 2; half++) {
        size_t toff = (size_t)half * HALFTOK;
        gemm(xn2b + toff * 192, wfc1, fc1_b, h1, HALFTOK, 720, 192, 720, 1, 0, 1, 0, nullptr, nullptr);
        dwconv4_kernel<720, 768, 768, 1, 2, 1><<<dim3(HALFTOK / 4 * 192 / 256), dim3(256), 0, stream>>>(
            h1, dwt3, db3, h2);
        gemm(h2, wpw, pw_b, h3, HALFTOK, 720, 768, 768, 1, 1, 2, 0, nullptr, nullptr);
        mpap_kernel<<<dim3(HALFTOK / 4), dim3(256), 0, stream>>>(h3, mp, ap);
        saconv_kernel<<<dim3(HALFTOK / 256), dim3(256), 0, stream>>>(mp, ap, sa_w, sab);
        gemm(h3, wfc2, fc2_b, outp + toff * 180, HALFTOK, 180, 768, 180, 0, 0, 0, 1,
             sab, x1b + toff * 180);
    }
}